// Round 1
// baseline (5673.010 us; speedup 1.0000x reference)
//
#include <hip/hip_runtime.h>
#include <math.h>

// ---------------- problem constants ----------------
constexpr int Bn = 1024, Jn = 17, Dn = 512, Mn = 34, Kcb = 2048, DTn = 512;
constexpr int RJ = Bn * Jn;                 // 17408 rows [B,J]
constexpr int RM = Bn * Mn;                 // 34816 rows [B,M]
constexpr size_t SZX = (size_t)RJ * Dn;     // 8,912,896 floats
constexpr size_t SZM = (size_t)RM * DTn;    // 17,825,792 floats

__device__ __forceinline__ float gelu_f(float x) {
  // exact gelu (approximate=False): 0.5*x*(1+erf(x/sqrt(2)))
  return 0.5f * x * (1.0f + erff(x * 0.7071067811865475f));
}

// ---------------- embed: x = joints[:,:,:2]@start_w + start_b; vis mask ----------------
__global__ __launch_bounds__(256) void embed_kernel(
    const float* __restrict__ joints, const float* __restrict__ inv,
    const float* __restrict__ sw, const float* __restrict__ sb,
    float* __restrict__ out) {
  int tid = blockIdx.x * 256 + threadIdx.x;   // < RJ*512
  int row = tid >> 9, d = tid & 511;
  float j0 = joints[row * 3 + 0];
  float j1 = joints[row * 3 + 1];
  float j2 = joints[row * 3 + 2];
  float x = fmaf(j0, sw[d], fmaf(j1, sw[512 + d], sb[d]));
  float v = (j2 != 0.0f) ? 1.0f : 0.0f;
  out[tid] = x * v + inv[d] * (1.0f - v);
}

// ---------------- LayerNorm: wave per row ----------------
template <int NV>
__global__ __launch_bounds__(256) void ln_kernel(
    const float* __restrict__ src, float* __restrict__ dst,
    const float* __restrict__ g, const float* __restrict__ b,
    int rows, int D) {
  int wave = threadIdx.x >> 6;
  int lane = threadIdx.x & 63;
  int row = blockIdx.x * 4 + wave;
  if (row >= rows) return;
  const float* p = src + (size_t)row * D;
  float v[NV];
  float s = 0.0f;
#pragma unroll
  for (int i = 0; i < NV; i++) {
    int d = lane + 64 * i;
    v[i] = (d < D) ? p[d] : 0.0f;
    s += v[i];
  }
#pragma unroll
  for (int m = 32; m; m >>= 1) s += __shfl_xor(s, m);
  float mean = s / (float)D;
  float s2 = 0.0f;
#pragma unroll
  for (int i = 0; i < NV; i++) {
    int d = lane + 64 * i;
    float t = (d < D) ? (v[i] - mean) : 0.0f;
    s2 += t * t;
  }
#pragma unroll
  for (int m = 32; m; m >>= 1) s2 += __shfl_xor(s2, m);
  float rs = 1.0f / sqrtf(s2 / (float)D + 1e-5f);
  float* q = dst + (size_t)row * D;
#pragma unroll
  for (int i = 0; i < NV; i++) {
    int d = lane + 64 * i;
    if (d < D) q[d] = (v[i] - mean) * rs * g[d] + b[d];
  }
}

// ---------------- token mixing (joints MLP 17->64->17), fused residual ----------------
// out[b,j,d] = xin[b,j,d] + tokenMLP(ln[b,:,d])[j]
__global__ __launch_bounds__(256) void tokenmix_kernel(
    const float* __restrict__ ln, const float* __restrict__ xin,
    float* __restrict__ out, const float* __restrict__ tw1,
    const float* __restrict__ tb1, const float* __restrict__ tw2,
    const float* __restrict__ tb2, int B, int H) {
  __shared__ float sw1[17 * 64], sw2[64 * 17], sb1[64], sb2[17];
  for (int i = threadIdx.x; i < 17 * 64; i += 256) {
    sw1[i] = tw1[i];
    sw2[i] = tw2[i];
  }
  if (threadIdx.x < 64) sb1[threadIdx.x] = tb1[threadIdx.x];
  if (threadIdx.x < 17) sb2[threadIdx.x] = tb2[threadIdx.x];
  __syncthreads();
  int tid = blockIdx.x * 256 + threadIdx.x;
  if (tid >= B * H) return;
  int b = tid / H, d = tid % H;
  const float* pl = ln + (size_t)b * 17 * H + d;
  float t[17], acc[17];
#pragma unroll
  for (int j = 0; j < 17; j++) {
    t[j] = pl[j * H];
    acc[j] = 0.0f;
  }
  for (int k = 0; k < 64; k++) {
    float h = sb1[k];
#pragma unroll
    for (int j = 0; j < 17; j++) h = fmaf(t[j], sw1[j * 64 + k], h);
    h = gelu_f(h);
#pragma unroll
    for (int j = 0; j < 17; j++) acc[j] = fmaf(h, sw2[k * 17 + j], acc[j]);
  }
  const float* px = xin + (size_t)b * 17 * H + d;
  float* po = out + (size_t)b * 17 * H + d;
#pragma unroll
  for (int j = 0; j < 17; j++) po[j * H] = px[j * H] + acc[j] + sb2[j];
}

// ---------------- linear mix over joint/token axis: out[b,m,d] = sum_j in[b,j,d]*w[j,m] + bias[m] ----------------
template <int JIN, int JOUT>
__global__ __launch_bounds__(256) void linmix_kernel(
    const float* __restrict__ in, float* __restrict__ out,
    const float* __restrict__ w, const float* __restrict__ bias,
    int B, int H) {
  __shared__ float sw[JIN * JOUT], sb[JOUT];
  for (int i = threadIdx.x; i < JIN * JOUT; i += 256) sw[i] = w[i];
  if (threadIdx.x < JOUT) sb[threadIdx.x] = bias[threadIdx.x];
  __syncthreads();
  int tid = blockIdx.x * 256 + threadIdx.x;
  if (tid >= B * H) return;
  int b = tid / H, d = tid % H;
  const float* pi = in + (size_t)b * JIN * H + d;
  float t[JIN];
#pragma unroll
  for (int j = 0; j < JIN; j++) t[j] = pi[(size_t)j * H];
  float* po = out + (size_t)b * JOUT * H + d;
#pragma unroll
  for (int m = 0; m < JOUT; m++) {
    float s = sb[m];
#pragma unroll
    for (int j = 0; j < JIN; j++) s = fmaf(t[j], sw[j * JOUT + m], s);
    po[(size_t)m * H] = s;
  }
}

// ---------------- big fp32 GEMM: C = act(A@W + bias) (+ R). 128x128 tile, 8x8/thread ----------------
// Requires M%128==0, N%128==0, K%16==0.
template <int GELU_FLAG, int RES_FLAG>
__global__ __launch_bounds__(256) void gemm128(
    const float* __restrict__ A, const float* __restrict__ W,
    const float* __restrict__ bias, const float* __restrict__ R,
    float* __restrict__ C, int Mdim, int K, int N) {
  __shared__ float sA[16][132];
  __shared__ float sW[16][132];
  const int tid = threadIdx.x;
  const int tx = tid & 15, ty = tid >> 4;
  const int m0 = blockIdx.x * 128, n0 = blockIdx.y * 128;
  const int lr = tid >> 2;
  const int lc4 = (tid & 3) * 4;
  float acc[8][8] = {};
  for (int k0 = 0; k0 < K; k0 += 16) {
    float4 a0 = *(const float4*)(A + (size_t)(m0 + lr) * K + k0 + lc4);
    float4 a1 = *(const float4*)(A + (size_t)(m0 + lr + 64) * K + k0 + lc4);
    sA[lc4 + 0][lr] = a0.x; sA[lc4 + 1][lr] = a0.y;
    sA[lc4 + 2][lr] = a0.z; sA[lc4 + 3][lr] = a0.w;
    sA[lc4 + 0][lr + 64] = a1.x; sA[lc4 + 1][lr + 64] = a1.y;
    sA[lc4 + 2][lr + 64] = a1.z; sA[lc4 + 3][lr + 64] = a1.w;
    {
      const int wk = tid >> 5;          // 0..7
      const int wc = (tid & 31) * 4;    // 0..124
      float4 w0 = *(const float4*)(W + (size_t)(k0 + wk) * N + n0 + wc);
      float4 w1 = *(const float4*)(W + (size_t)(k0 + wk + 8) * N + n0 + wc);
      *(float4*)&sW[wk][wc] = w0;
      *(float4*)&sW[wk + 8][wc] = w1;
    }
    __syncthreads();
#pragma unroll
    for (int kk = 0; kk < 16; kk++) {
      float4 av0 = *(const float4*)&sA[kk][tx * 4];
      float4 av1 = *(const float4*)&sA[kk][64 + tx * 4];
      float4 wv0 = *(const float4*)&sW[kk][ty * 4];
      float4 wv1 = *(const float4*)&sW[kk][64 + ty * 4];
      float a[8] = {av0.x, av0.y, av0.z, av0.w, av1.x, av1.y, av1.z, av1.w};
      float w[8] = {wv0.x, wv0.y, wv0.z, wv0.w, wv1.x, wv1.y, wv1.z, wv1.w};
#pragma unroll
      for (int i = 0; i < 8; i++)
#pragma unroll
        for (int j = 0; j < 8; j++) acc[i][j] = fmaf(a[i], w[j], acc[i][j]);
    }
    __syncthreads();
  }
#pragma unroll
  for (int gi = 0; gi < 2; gi++)
#pragma unroll
    for (int u = 0; u < 4; u++) {
      int r = m0 + gi * 64 + tx * 4 + u;
      int ai = gi * 4 + u;
#pragma unroll
      for (int gj = 0; gj < 2; gj++) {
        int cb = n0 + gj * 64 + ty * 4;
        float4 bv = *(const float4*)(bias + cb);
        float4 o;
        o.x = acc[ai][gj * 4 + 0] + bv.x;
        o.y = acc[ai][gj * 4 + 1] + bv.y;
        o.z = acc[ai][gj * 4 + 2] + bv.z;
        o.w = acc[ai][gj * 4 + 3] + bv.w;
        if (GELU_FLAG) {
          o.x = gelu_f(o.x); o.y = gelu_f(o.y);
          o.z = gelu_f(o.z); o.w = gelu_f(o.w);
        }
        if (RES_FLAG) {
          float4 rv = *(const float4*)(R + (size_t)r * N + cb);
          o.x += rv.x; o.y += rv.y; o.z += rv.z; o.w += rv.w;
        }
        *(float4*)(C + (size_t)r * N + cb) = o;
      }
    }
}

// ---------------- codebook L2 norms ----------------
__global__ __launch_bounds__(256) void cnorm_kernel(
    const float* __restrict__ CBm, float* __restrict__ cnorm) {
  int wave = threadIdx.x >> 6, lane = threadIdx.x & 63;
  int k = blockIdx.x * 4 + wave;
  const float* p = CBm + (size_t)k * 512;
  float s = 0.0f;
#pragma unroll
  for (int i = 0; i < 8; i++) {
    float v = p[lane + 64 * i];
    s = fmaf(v, v, s);
  }
#pragma unroll
  for (int m = 32; m; m >>= 1) s += __shfl_xor(s, m);
  if (lane == 0) cnorm[k] = s;
}

// ---------------- distance GEMM (B transposed = codebook [N,K]) + fused per-block argmin ----------------
__global__ __launch_bounds__(256) void dist_gemm(
    const float* __restrict__ A, const float* __restrict__ CBm,
    const float* __restrict__ cnorm, float* __restrict__ pval,
    int* __restrict__ pidx, int K) {
  __shared__ float sA[16][132];
  __shared__ float sW[16][132];
  __shared__ float rv[128][17];
  __shared__ int ri[128][17];
  const int tid = threadIdx.x;
  const int tx = tid & 15, ty = tid >> 4;
  const int m0 = blockIdx.x * 128, n0 = blockIdx.y * 128;
  const int lr = tid >> 2;
  const int lc4 = (tid & 3) * 4;
  float acc[8][8] = {};
  for (int k0 = 0; k0 < K; k0 += 16) {
    float4 a0 = *(const float4*)(A + (size_t)(m0 + lr) * K + k0 + lc4);
    float4 a1 = *(const float4*)(A + (size_t)(m0 + lr + 64) * K + k0 + lc4);
    float4 w0 = *(const float4*)(CBm + (size_t)(n0 + lr) * K + k0 + lc4);
    float4 w1 = *(const float4*)(CBm + (size_t)(n0 + lr + 64) * K + k0 + lc4);
    sA[lc4 + 0][lr] = a0.x; sA[lc4 + 1][lr] = a0.y;
    sA[lc4 + 2][lr] = a0.z; sA[lc4 + 3][lr] = a0.w;
    sA[lc4 + 0][lr + 64] = a1.x; sA[lc4 + 1][lr + 64] = a1.y;
    sA[lc4 + 2][lr + 64] = a1.z; sA[lc4 + 3][lr + 64] = a1.w;
    sW[lc4 + 0][lr] = w0.x; sW[lc4 + 1][lr] = w0.y;
    sW[lc4 + 2][lr] = w0.z; sW[lc4 + 3][lr] = w0.w;
    sW[lc4 + 0][lr + 64] = w1.x; sW[lc4 + 1][lr + 64] = w1.y;
    sW[lc4 + 2][lr + 64] = w1.z; sW[lc4 + 3][lr + 64] = w1.w;
    __syncthreads();
#pragma unroll
    for (int kk = 0; kk < 16; kk++) {
      float4 av0 = *(const float4*)&sA[kk][tx * 4];
      float4 av1 = *(const float4*)&sA[kk][64 + tx * 4];
      float4 wv0 = *(const float4*)&sW[kk][ty * 4];
      float4 wv1 = *(const float4*)&sW[kk][64 + ty * 4];
      float a[8] = {av0.x, av0.y, av0.z, av0.w, av1.x, av1.y, av1.z, av1.w};
      float w[8] = {wv0.x, wv0.y, wv0.z, wv0.w, wv1.x, wv1.y, wv1.z, wv1.w};
#pragma unroll
      for (int i = 0; i < 8; i++)
#pragma unroll
        for (int j = 0; j < 8; j++) acc[i][j] = fmaf(a[i], w[j], acc[i][j]);
    }
    __syncthreads();
  }
  // per-thread argmin over its 8 columns for each of its 8 rows
#pragma unroll
  for (int gi = 0; gi < 2; gi++)
#pragma unroll
    for (int u = 0; u < 4; u++) {
      const int ai = gi * 4 + u;
      float bv = 3.0e38f;
      int bi = 0x7fffffff;
#pragma unroll
      for (int gj = 0; gj < 2; gj++)
#pragma unroll
        for (int v = 0; v < 4; v++) {
          int c = n0 + gj * 64 + ty * 4 + v;
          float d = cnorm[c] - 2.0f * acc[ai][gj * 4 + v];
          if (d < bv || (d == bv && c < bi)) { bv = d; bi = c; }
        }
      int rl = gi * 64 + tx * 4 + u;
      rv[rl][ty] = bv;
      ri[rl][ty] = bi;
    }
  __syncthreads();
  if (tid < 128) {
    float bv = rv[tid][0];
    int bi = ri[tid][0];
#pragma unroll
    for (int t = 1; t < 16; t++) {
      float v = rv[tid][t];
      int i2 = ri[tid][t];
      if (v < bv || (v == bv && i2 < bi)) { bv = v; bi = i2; }
    }
    int row = m0 + tid;
    pval[row * 16 + blockIdx.y] = bv;
    pidx[row * 16 + blockIdx.y] = bi;
  }
}

// ---------------- argmin across the 16 N-block partials ----------------
__global__ __launch_bounds__(256) void argmin_reduce(
    const float* __restrict__ pval, const int* __restrict__ pidx,
    int* __restrict__ idxi, float* __restrict__ idxf, int rows) {
  int r = blockIdx.x * 256 + threadIdx.x;
  if (r >= rows) return;
  float bv = pval[r * 16];
  int bi = pidx[r * 16];
#pragma unroll
  for (int t = 1; t < 16; t++) {
    float v = pval[r * 16 + t];
    int i2 = pidx[r * 16 + t];
    if (v < bv || (v == bv && i2 < bi)) { bv = v; bi = i2; }
  }
  idxi[r] = bi;
  idxf[r] = (float)bi;
}

// ---------------- quant gather + EMA scatter + latent loss ----------------
__global__ __launch_bounds__(128) void quant_scatter(
    const float* __restrict__ feat, const float* __restrict__ CBm,
    const int* __restrict__ idxi, float* __restrict__ ptf_out,
    float* __restrict__ dw, float* __restrict__ counts,
    float* __restrict__ loss_acc) {
  int row = blockIdx.x;
  int k = idxi[row];
  int t = threadIdx.x;  // 0..127, 4 floats each
  const float4* f4 = (const float4*)(feat + (size_t)row * 512);
  const float4* c4 = (const float4*)(CBm + (size_t)k * 512);
  float4 f = f4[t];
  float4 c = c4[t];
  float* po = ptf_out + (size_t)row * 512 + 4 * t;  // base may be 4B-misaligned region -> scalar stores
  po[0] = c.x; po[1] = c.y; po[2] = c.z; po[3] = c.w;
  float dx = c.x - f.x, dy = c.y - f.y, dz = c.z - f.z, dwv = c.w - f.w;
  float ls = dx * dx + dy * dy + dz * dz + dwv * dwv;
  float* pdw = dw + (size_t)k * 512 + 4 * t;
  atomicAdd(pdw + 0, f.x);
  atomicAdd(pdw + 1, f.y);
  atomicAdd(pdw + 2, f.z);
  atomicAdd(pdw + 3, f.w);
#pragma unroll
  for (int m = 32; m; m >>= 1) ls += __shfl_xor(ls, m);
  if ((t & 63) == 0) atomicAdd(loss_acc, ls);
  if (t == 0) atomicAdd(&counts[k], 1.0f);
}

// ---------------- cs sum (n) + loss finalize ----------------
__global__ __launch_bounds__(256) void cs_n_kernel(
    const float* __restrict__ counts, const float* __restrict__ ema_cs,
    float* __restrict__ nbuf, const float* __restrict__ loss_acc,
    float* __restrict__ loss_out) {
  __shared__ float red[256];
  float s = 0.0f;
  for (int k = threadIdx.x; k < 2048; k += 256)
    s += ema_cs[k] * 0.9f + 0.1f * counts[k];
  red[threadIdx.x] = s;
  __syncthreads();
  for (int o = 128; o; o >>= 1) {
    if (threadIdx.x < o) red[threadIdx.x] += red[threadIdx.x + o];
    __syncthreads();
  }
  if (threadIdx.x == 0) {
    nbuf[0] = red[0];
    loss_out[0] = loss_acc[0] / (float)((size_t)34816 * 512);
  }
}

// ---------------- codebook_new ----------------
__global__ __launch_bounds__(256) void cbnew_kernel(
    const float* __restrict__ ema_w, const float* __restrict__ dw,
    const float* __restrict__ ema_cs, const float* __restrict__ counts,
    const float* __restrict__ nbuf, float* __restrict__ outp) {
  int tid = blockIdx.x * 256 + threadIdx.x;  // < 2048*512
  int k = tid >> 9;
  float n = nbuf[0];
  float cs = ema_cs[k] * 0.9f + 0.1f * counts[k];
  cs = (cs + 1e-5f) / (n + 0.02048f) * n;
  outp[tid] = (ema_w[tid] * 0.9f + 0.1f * dw[tid]) / cs;
}

// ---------------- small-N GEMM: out = act(A@W + bias) (+R). N divides 256 ----------------
template <int GELU_FLAG, int RES_FLAG>
__global__ __launch_bounds__(256) void small_gemm(
    const float* __restrict__ A, const float* __restrict__ W,
    const float* __restrict__ bias, const float* __restrict__ R,
    float* __restrict__ out, int Mrows, int K, int N) {
  int tid = blockIdx.x * 256 + threadIdx.x;
  int r = tid / N, c = tid % N;
  if (r >= Mrows) return;
  float s = bias[c];
  const float4* pa = (const float4*)(A + (size_t)r * K);
  const float* pw = W + c;
  int k4 = K >> 2;
  for (int kk = 0; kk < k4; kk++) {
    float4 a = pa[kk];
    s = fmaf(a.x, pw[(4 * kk + 0) * N], s);
    s = fmaf(a.y, pw[(4 * kk + 1) * N], s);
    s = fmaf(a.z, pw[(4 * kk + 2) * N], s);
    s = fmaf(a.w, pw[(4 * kk + 3) * N], s);
  }
  if (GELU_FLAG) s = gelu_f(s);
  if (RES_FLAG) s += R[(size_t)r * N + c];
  out[(size_t)r * N + c] = s;
}

// ================================================================
extern "C" void kernel_launch(void* const* d_in, const int* in_sizes, int n_in,
                              void* d_out, int out_size, void* d_ws, size_t ws_size,
                              hipStream_t stream) {
  // -------- inputs (setup_inputs dict order) --------
  const float* joints   = (const float*)d_in[0];
  const float* inv_tok  = (const float*)d_in[3];
  const float* start_w  = (const float*)d_in[4];
  const float* start_b  = (const float*)d_in[5];
  const float* e_ln1g = (const float*)d_in[6];
  const float* e_ln1b = (const float*)d_in[7];
  const float* e_tw1  = (const float*)d_in[8];
  const float* e_tb1  = (const float*)d_in[9];
  const float* e_tw2  = (const float*)d_in[10];
  const float* e_tb2  = (const float*)d_in[11];
  const float* e_ln2g = (const float*)d_in[12];
  const float* e_ln2b = (const float*)d_in[13];
  const float* e_cw1  = (const float*)d_in[14];
  const float* e_cb1  = (const float*)d_in[15];
  const float* e_cw2  = (const float*)d_in[16];
  const float* e_cb2  = (const float*)d_in[17];
  const float* d_ln1g = (const float*)d_in[18];
  const float* d_ln1b = (const float*)d_in[19];
  const float* d_tw1  = (const float*)d_in[20];
  const float* d_tb1  = (const float*)d_in[21];
  const float* d_tw2  = (const float*)d_in[22];
  const float* d_tb2  = (const float*)d_in[23];
  const float* d_ln2g = (const float*)d_in[24];
  const float* d_ln2b = (const float*)d_in[25];
  const float* d_cw1  = (const float*)d_in[26];
  const float* d_cb1  = (const float*)d_in[27];
  const float* d_cw2  = (const float*)d_in[28];
  const float* d_cb2  = (const float*)d_in[29];
  const float* enc_lng = (const float*)d_in[30];
  const float* enc_lnb = (const float*)d_in[31];
  const float* tok_w   = (const float*)d_in[32];
  const float* tok_b   = (const float*)d_in[33];
  const float* feat_w  = (const float*)d_in[34];
  const float* feat_b  = (const float*)d_in[35];
  const float* codebook = (const float*)d_in[36];
  const float* ema_cs   = (const float*)d_in[37];
  const float* ema_w    = (const float*)d_in[38];
  const float* dtok_w   = (const float*)d_in[39];
  const float* dtok_b   = (const float*)d_in[40];
  const float* dstart_w = (const float*)d_in[41];
  const float* dstart_b = (const float*)d_in[42];
  const float* dec_lng  = (const float*)d_in[43];
  const float* dec_lnb  = (const float*)d_in[44];
  const float* rec_w    = (const float*)d_in[45];
  const float* rec_b    = (const float*)d_in[46];

  // -------- workspace layout (floats) --------
  float* ws = (float*)d_ws;
  float* Ab = ws;                 // [RJ,512]; later feat spans Ab..Ab+SZM
  float* Bb = ws + SZX;           // [RJ,512]
  float* Cc = ws + 2 * SZX;       // [RJ,512]
  float* Mm = ws + 3 * SZX;       // [RM,512] xm; also h-buffer in encoder; dec bufs later
  float* feat = Ab;               // [RM,512] = Ab+Bb regions
  float* tail = ws + 3 * SZX + SZM;
  float* cnorm = tail;                          // 2048
  float* pval = cnorm + 2048;                   // RM*16
  int* pidx = (int*)(pval + (size_t)RM * 16);   // RM*16
  int* idxi = pidx + (size_t)RM * 16;           // RM
  float* counts = (float*)(idxi + RM);          // 2048
  float* dw = counts + 2048;                    // 2048*512
  float* nbuf = dw + (size_t)2048 * 512;        // 1
  float* lossb = nbuf + 1;                      // 1
  // decoder small buffers carved from Mm region
  float* dy  = Mm;                              // [RJ,32]
  float* dx2 = Mm + (size_t)RJ * 32;            // [RJ,32]
  float* dh  = Mm + (size_t)2 * RJ * 32;        // [RJ,64]
  float* dln = Mm + (size_t)2 * RJ * 32 + (size_t)RJ * 64;  // [RJ,32]

  // -------- outputs --------
  float* outp = (float*)d_out;
  float* o_rec = outp;                       // [RJ,2]
  float* o_idx = outp + (size_t)RJ * 2;      // [RM]
  float* o_loss = o_idx + RM;                // [1]
  float* o_ptf = o_loss + 1;                 // [RM,512]
  float* o_cb = o_ptf + SZM;                 // [2048,512]

  // zero the accumulators (counts + dw + nbuf + lossb are contiguous)
  hipMemsetAsync(counts, 0, (size_t)(2048 + 2048 * 512 + 2) * sizeof(float), stream);

  // -------- encoder --------
  embed_kernel<<<(RJ * 512) / 256, 256, 0, stream>>>(joints, inv_tok, start_w, start_b, Ab);
  for (int i = 0; i < 4; i++) {
    ln_kernel<8><<<RJ / 4, 256, 0, stream>>>(Ab, Cc, e_ln1g + i * 512, e_ln1b + i * 512, RJ, 512);
    tokenmix_kernel<<<(Bn * 512) / 256, 256, 0, stream>>>(
        Cc, Ab, Bb, e_tw1 + i * 17 * 64, e_tb1 + i * 64, e_tw2 + i * 64 * 17, e_tb2 + i * 17, Bn, 512);
    ln_kernel<8><<<RJ / 4, 256, 0, stream>>>(Bb, Cc, e_ln2g + i * 512, e_ln2b + i * 512, RJ, 512);
    gemm128<1, 0><<<dim3(RJ / 128, 4), 256, 0, stream>>>(
        Cc, e_cw1 + (size_t)i * 512 * 512, e_cb1 + i * 512, nullptr, Mm, RJ, 512, 512);
    gemm128<0, 1><<<dim3(RJ / 128, 4), 256, 0, stream>>>(
        Mm, e_cw2 + (size_t)i * 512 * 512, e_cb2 + i * 512, Bb, Ab, RJ, 512, 512);
  }
  ln_kernel<8><<<RJ / 4, 256, 0, stream>>>(Ab, Cc, enc_lng, enc_lnb, RJ, 512);
  linmix_kernel<17, 34><<<(Bn * 512) / 256, 256, 0, stream>>>(Cc, Mm, tok_w, tok_b, Bn, 512);
  gemm128<0, 0><<<dim3(RM / 128, 4), 256, 0, stream>>>(Mm, feat_w, feat_b, nullptr, feat, RM, 512, 512);

  // -------- VQ: distances + argmin --------
  cnorm_kernel<<<2048 / 4, 256, 0, stream>>>(codebook, cnorm);
  dist_gemm<<<dim3(RM / 128, 2048 / 128), 256, 0, stream>>>(feat, codebook, cnorm, pval, pidx, 512);
  argmin_reduce<<<RM / 256, 256, 0, stream>>>(pval, pidx, idxi, o_idx, RM);
  quant_scatter<<<RM, 128, 0, stream>>>(feat, codebook, idxi, o_ptf, dw, counts, lossb);
  cs_n_kernel<<<1, 256, 0, stream>>>(counts, ema_cs, nbuf, lossb, o_loss);
  cbnew_kernel<<<(2048 * 512) / 256, 256, 0, stream>>>(ema_w, dw, ema_cs, counts, nbuf, o_cb);

  // -------- decoder --------
  linmix_kernel<34, 17><<<(Bn * 512) / 256, 256, 0, stream>>>(o_ptf, Cc, dtok_w, dtok_b, Bn, 512);
  small_gemm<0, 0><<<(RJ * 32) / 256, 256, 0, stream>>>(Cc, dstart_w, dstart_b, nullptr, dy, RJ, 512, 32);
  ln_kernel<1><<<RJ / 4, 256, 0, stream>>>(dy, dln, d_ln1g, d_ln1b, RJ, 32);
  tokenmix_kernel<<<(Bn * 32) / 256, 256, 0, stream>>>(dln, dy, dx2, d_tw1, d_tb1, d_tw2, d_tb2, Bn, 32);
  ln_kernel<1><<<RJ / 4, 256, 0, stream>>>(dx2, dln, d_ln2g, d_ln2b, RJ, 32);
  small_gemm<1, 0><<<(RJ * 64) / 256, 256, 0, stream>>>(dln, d_cw1, d_cb1, nullptr, dh, RJ, 32, 64);
  small_gemm<0, 1><<<(RJ * 32) / 256, 256, 0, stream>>>(dh, d_cw2, d_cb2, dx2, dy, RJ, 64, 32);
  ln_kernel<1><<<RJ / 4, 256, 0, stream>>>(dy, dln, dec_lng, dec_lnb, RJ, 32);
  small_gemm<0, 0><<<(RJ * 2) / 256, 256, 0, stream>>>(dln, rec_w, rec_b, nullptr, o_rec, RJ, 32, 2);
}

// Round 2
// 5320.982 us; speedup vs baseline: 1.0662x; 1.0662x over previous
//
#include <hip/hip_runtime.h>
#include <math.h>

// ---------------- problem constants ----------------
constexpr int Bn = 1024, Jn = 17, Dn = 512, Mn = 34, Kcb = 2048, DTn = 512;
constexpr int RJ = Bn * Jn;                 // 17408 rows [B,J]
constexpr int RM = Bn * Mn;                 // 34816 rows [B,M]
constexpr size_t SZX = (size_t)RJ * Dn;     // 8,912,896 floats
constexpr size_t SZM = (size_t)RM * DTn;    // 17,825,792 floats

__device__ __forceinline__ float gelu_f(float x) {
  return 0.5f * x * (1.0f + erff(x * 0.7071067811865475f));
}

// ---------------- embed ----------------
__global__ __launch_bounds__(256) void embed_kernel(
    const float* __restrict__ joints, const float* __restrict__ inv,
    const float* __restrict__ sw, const float* __restrict__ sb,
    float* __restrict__ out) {
  int tid = blockIdx.x * 256 + threadIdx.x;
  int row = tid >> 9, d = tid & 511;
  float j0 = joints[row * 3 + 0];
  float j1 = joints[row * 3 + 1];
  float j2 = joints[row * 3 + 2];
  float x = fmaf(j0, sw[d], fmaf(j1, sw[512 + d], sb[d]));
  float v = (j2 != 0.0f) ? 1.0f : 0.0f;
  out[tid] = x * v + inv[d] * (1.0f - v);
}

// ---------------- LayerNorm: wave per row ----------------
template <int NV>
__global__ __launch_bounds__(256) void ln_kernel(
    const float* __restrict__ src, float* __restrict__ dst,
    const float* __restrict__ g, const float* __restrict__ b,
    int rows, int D) {
  int wave = threadIdx.x >> 6;
  int lane = threadIdx.x & 63;
  int row = blockIdx.x * 4 + wave;
  if (row >= rows) return;
  const float* p = src + (size_t)row * D;
  float v[NV];
  float s = 0.0f;
#pragma unroll
  for (int i = 0; i < NV; i++) {
    int d = lane + 64 * i;
    v[i] = (d < D) ? p[d] : 0.0f;
    s += v[i];
  }
#pragma unroll
  for (int m = 32; m; m >>= 1) s += __shfl_xor(s, m);
  float mean = s / (float)D;
  float s2 = 0.0f;
#pragma unroll
  for (int i = 0; i < NV; i++) {
    int d = lane + 64 * i;
    float t = (d < D) ? (v[i] - mean) : 0.0f;
    s2 += t * t;
  }
#pragma unroll
  for (int m = 32; m; m >>= 1) s2 += __shfl_xor(s2, m);
  float rs = 1.0f / sqrtf(s2 / (float)D + 1e-5f);
  float* q = dst + (size_t)row * D;
#pragma unroll
  for (int i = 0; i < NV; i++) {
    int d = lane + 64 * i;
    if (d < D) q[d] = (v[i] - mean) * rs * g[d] + b[d];
  }
}

// ---------------- token mixing (17->64->17) fused residual ----------------
__global__ __launch_bounds__(256) void tokenmix_kernel(
    const float* __restrict__ ln, const float* __restrict__ xin,
    float* __restrict__ out, const float* __restrict__ tw1,
    const float* __restrict__ tb1, const float* __restrict__ tw2,
    const float* __restrict__ tb2, int B, int H) {
  __shared__ float sw1[17 * 64], sw2[64 * 17], sb1[64], sb2[17];
  for (int i = threadIdx.x; i < 17 * 64; i += 256) {
    sw1[i] = tw1[i];
    sw2[i] = tw2[i];
  }
  if (threadIdx.x < 64) sb1[threadIdx.x] = tb1[threadIdx.x];
  if (threadIdx.x < 17) sb2[threadIdx.x] = tb2[threadIdx.x];
  __syncthreads();
  int tid = blockIdx.x * 256 + threadIdx.x;
  if (tid >= B * H) return;
  int b = tid / H, d = tid % H;
  const float* pl = ln + (size_t)b * 17 * H + d;
  float t[17], acc[17];
#pragma unroll
  for (int j = 0; j < 17; j++) {
    t[j] = pl[j * H];
    acc[j] = 0.0f;
  }
  for (int k = 0; k < 64; k++) {
    float h = sb1[k];
#pragma unroll
    for (int j = 0; j < 17; j++) h = fmaf(t[j], sw1[j * 64 + k], h);
    h = gelu_f(h);
#pragma unroll
    for (int j = 0; j < 17; j++) acc[j] = fmaf(h, sw2[k * 17 + j], acc[j]);
  }
  const float* px = xin + (size_t)b * 17 * H + d;
  float* po = out + (size_t)b * 17 * H + d;
#pragma unroll
  for (int j = 0; j < 17; j++) po[j * H] = px[j * H] + acc[j] + sb2[j];
}

// ---------------- linear mix over joint/token axis ----------------
template <int JIN, int JOUT>
__global__ __launch_bounds__(256) void linmix_kernel(
    const float* __restrict__ in, float* __restrict__ out,
    const float* __restrict__ w, const float* __restrict__ bias,
    int B, int H) {
  __shared__ float sw[JIN * JOUT], sb[JOUT];
  for (int i = threadIdx.x; i < JIN * JOUT; i += 256) sw[i] = w[i];
  if (threadIdx.x < JOUT) sb[threadIdx.x] = bias[threadIdx.x];
  __syncthreads();
  int tid = blockIdx.x * 256 + threadIdx.x;
  if (tid >= B * H) return;
  int b = tid / H, d = tid % H;
  const float* pi = in + (size_t)b * JIN * H + d;
  float t[JIN];
#pragma unroll
  for (int j = 0; j < JIN; j++) t[j] = pi[(size_t)j * H];
  float* po = out + (size_t)b * JOUT * H + d;
#pragma unroll
  for (int m = 0; m < JOUT; m++) {
    float s = sb[m];
#pragma unroll
    for (int j = 0; j < JIN; j++) s = fmaf(t[j], sw[j * JOUT + m], s);
    po[(size_t)m * H] = s;
  }
}

// ---------------- big fp32 GEMM: 128x128 tile, 8x8/thread ----------------
template <int GELU_FLAG, int RES_FLAG>
__global__ __launch_bounds__(256) void gemm128(
    const float* __restrict__ A, const float* __restrict__ W,
    const float* __restrict__ bias, const float* __restrict__ R,
    float* __restrict__ C, int Mdim, int K, int N) {
  __shared__ float sA[16][132];
  __shared__ float sW[16][132];
  const int tid = threadIdx.x;
  const int tx = tid & 15, ty = tid >> 4;
  const int m0 = blockIdx.x * 128, n0 = blockIdx.y * 128;
  const int lr = tid >> 2;
  const int lc4 = (tid & 3) * 4;
  float acc[8][8] = {};
  for (int k0 = 0; k0 < K; k0 += 16) {
    float4 a0 = *(const float4*)(A + (size_t)(m0 + lr) * K + k0 + lc4);
    float4 a1 = *(const float4*)(A + (size_t)(m0 + lr + 64) * K + k0 + lc4);
    sA[lc4 + 0][lr] = a0.x; sA[lc4 + 1][lr] = a0.y;
    sA[lc4 + 2][lr] = a0.z; sA[lc4 + 3][lr] = a0.w;
    sA[lc4 + 0][lr + 64] = a1.x; sA[lc4 + 1][lr + 64] = a1.y;
    sA[lc4 + 2][lr + 64] = a1.z; sA[lc4 + 3][lr + 64] = a1.w;
    {
      const int wk = tid >> 5;
      const int wc = (tid & 31) * 4;
      float4 w0 = *(const float4*)(W + (size_t)(k0 + wk) * N + n0 + wc);
      float4 w1 = *(const float4*)(W + (size_t)(k0 + wk + 8) * N + n0 + wc);
      *(float4*)&sW[wk][wc] = w0;
      *(float4*)&sW[wk + 8][wc] = w1;
    }
    __syncthreads();
#pragma unroll
    for (int kk = 0; kk < 16; kk++) {
      float4 av0 = *(const float4*)&sA[kk][tx * 4];
      float4 av1 = *(const float4*)&sA[kk][64 + tx * 4];
      float4 wv0 = *(const float4*)&sW[kk][ty * 4];
      float4 wv1 = *(const float4*)&sW[kk][64 + ty * 4];
      float a[8] = {av0.x, av0.y, av0.z, av0.w, av1.x, av1.y, av1.z, av1.w};
      float w[8] = {wv0.x, wv0.y, wv0.z, wv0.w, wv1.x, wv1.y, wv1.z, wv1.w};
#pragma unroll
      for (int i = 0; i < 8; i++)
#pragma unroll
        for (int j = 0; j < 8; j++) acc[i][j] = fmaf(a[i], w[j], acc[i][j]);
    }
    __syncthreads();
  }
#pragma unroll
  for (int gi = 0; gi < 2; gi++)
#pragma unroll
    for (int u = 0; u < 4; u++) {
      int r = m0 + gi * 64 + tx * 4 + u;
      int ai = gi * 4 + u;
#pragma unroll
      for (int gj = 0; gj < 2; gj++) {
        int cb = n0 + gj * 64 + ty * 4;
        float4 bv = *(const float4*)(bias + cb);
        float4 o;
        o.x = acc[ai][gj * 4 + 0] + bv.x;
        o.y = acc[ai][gj * 4 + 1] + bv.y;
        o.z = acc[ai][gj * 4 + 2] + bv.z;
        o.w = acc[ai][gj * 4 + 3] + bv.w;
        if (GELU_FLAG) {
          o.x = gelu_f(o.x); o.y = gelu_f(o.y);
          o.z = gelu_f(o.z); o.w = gelu_f(o.w);
        }
        if (RES_FLAG) {
          float4 rv = *(const float4*)(R + (size_t)r * N + cb);
          o.x += rv.x; o.y += rv.y; o.z += rv.z; o.w += rv.w;
        }
        *(float4*)(C + (size_t)r * N + cb) = o;
      }
    }
}

// ---------------- codebook L2 norms ----------------
__global__ __launch_bounds__(256) void cnorm_kernel(
    const float* __restrict__ CBm, float* __restrict__ cnorm) {
  int wave = threadIdx.x >> 6, lane = threadIdx.x & 63;
  int k = blockIdx.x * 4 + wave;
  const float* p = CBm + (size_t)k * 512;
  float s = 0.0f;
#pragma unroll
  for (int i = 0; i < 8; i++) {
    float v = p[lane + 64 * i];
    s = fmaf(v, v, s);
  }
#pragma unroll
  for (int m = 32; m; m >>= 1) s += __shfl_xor(s, m);
  if (lane == 0) cnorm[k] = s;
}

// ---------------- distance GEMM + fused per-block argmin ----------------
__global__ __launch_bounds__(256) void dist_gemm(
    const float* __restrict__ A, const float* __restrict__ CBm,
    const float* __restrict__ cnorm, float* __restrict__ pval,
    int* __restrict__ pidx, int K) {
  __shared__ float sA[16][132];
  __shared__ float sW[16][132];
  __shared__ float rv[128][17];
  __shared__ int ri[128][17];
  const int tid = threadIdx.x;
  const int tx = tid & 15, ty = tid >> 4;
  const int m0 = blockIdx.x * 128, n0 = blockIdx.y * 128;
  const int lr = tid >> 2;
  const int lc4 = (tid & 3) * 4;
  float acc[8][8] = {};
  for (int k0 = 0; k0 < K; k0 += 16) {
    float4 a0 = *(const float4*)(A + (size_t)(m0 + lr) * K + k0 + lc4);
    float4 a1 = *(const float4*)(A + (size_t)(m0 + lr + 64) * K + k0 + lc4);
    float4 w0 = *(const float4*)(CBm + (size_t)(n0 + lr) * K + k0 + lc4);
    float4 w1 = *(const float4*)(CBm + (size_t)(n0 + lr + 64) * K + k0 + lc4);
    sA[lc4 + 0][lr] = a0.x; sA[lc4 + 1][lr] = a0.y;
    sA[lc4 + 2][lr] = a0.z; sA[lc4 + 3][lr] = a0.w;
    sA[lc4 + 0][lr + 64] = a1.x; sA[lc4 + 1][lr + 64] = a1.y;
    sA[lc4 + 2][lr + 64] = a1.z; sA[lc4 + 3][lr + 64] = a1.w;
    sW[lc4 + 0][lr] = w0.x; sW[lc4 + 1][lr] = w0.y;
    sW[lc4 + 2][lr] = w0.z; sW[lc4 + 3][lr] = w0.w;
    sW[lc4 + 0][lr + 64] = w1.x; sW[lc4 + 1][lr + 64] = w1.y;
    sW[lc4 + 2][lr + 64] = w1.z; sW[lc4 + 3][lr + 64] = w1.w;
    __syncthreads();
#pragma unroll
    for (int kk = 0; kk < 16; kk++) {
      float4 av0 = *(const float4*)&sA[kk][tx * 4];
      float4 av1 = *(const float4*)&sA[kk][64 + tx * 4];
      float4 wv0 = *(const float4*)&sW[kk][ty * 4];
      float4 wv1 = *(const float4*)&sW[kk][64 + ty * 4];
      float a[8] = {av0.x, av0.y, av0.z, av0.w, av1.x, av1.y, av1.z, av1.w};
      float w[8] = {wv0.x, wv0.y, wv0.z, wv0.w, wv1.x, wv1.y, wv1.z, wv1.w};
#pragma unroll
      for (int i = 0; i < 8; i++)
#pragma unroll
        for (int j = 0; j < 8; j++) acc[i][j] = fmaf(a[i], w[j], acc[i][j]);
    }
    __syncthreads();
  }
#pragma unroll
  for (int gi = 0; gi < 2; gi++)
#pragma unroll
    for (int u = 0; u < 4; u++) {
      const int ai = gi * 4 + u;
      float bv = 3.0e38f;
      int bi = 0x7fffffff;
#pragma unroll
      for (int gj = 0; gj < 2; gj++)
#pragma unroll
        for (int v = 0; v < 4; v++) {
          int c = n0 + gj * 64 + ty * 4 + v;
          float d = cnorm[c] - 2.0f * acc[ai][gj * 4 + v];
          if (d < bv || (d == bv && c < bi)) { bv = d; bi = c; }
        }
      int rl = gi * 64 + tx * 4 + u;
      rv[rl][ty] = bv;
      ri[rl][ty] = bi;
    }
  __syncthreads();
  if (tid < 128) {
    float bv = rv[tid][0];
    int bi = ri[tid][0];
#pragma unroll
    for (int t = 1; t < 16; t++) {
      float v = rv[tid][t];
      int i2 = ri[tid][t];
      if (v < bv || (v == bv && i2 < bi)) { bv = v; bi = i2; }
    }
    int row = m0 + tid;
    pval[row * 16 + blockIdx.y] = bv;
    pidx[row * 16 + blockIdx.y] = bi;
  }
}

// ---------------- argmin across the 16 N-block partials ----------------
__global__ __launch_bounds__(256) void argmin_reduce(
    const float* __restrict__ pval, const int* __restrict__ pidx,
    int* __restrict__ idxi, float* __restrict__ idxf, int rows) {
  int r = blockIdx.x * 256 + threadIdx.x;
  if (r >= rows) return;
  float bv = pval[r * 16];
  int bi = pidx[r * 16];
#pragma unroll
  for (int t = 1; t < 16; t++) {
    float v = pval[r * 16 + t];
    int i2 = pidx[r * 16 + t];
    if (v < bv || (v == bv && i2 < bi)) { bv = v; bi = i2; }
  }
  idxi[r] = bi;
  idxf[r] = (float)bi;
}

// ---------------- bucket build: count / scan / scatter ----------------
__global__ __launch_bounds__(256) void count_kernel(
    const int* __restrict__ idxi, int* __restrict__ cnt) {
  int r = blockIdx.x * 256 + threadIdx.x;
  if (r < RM) atomicAdd(&cnt[idxi[r]], 1);
}

// one block, 256 threads: exclusive scan of 2048 counts -> base & cursor;
// also n = 0.9*sum(ema_cs) + 0.1*RM  (sum of counts == RM exactly)
__global__ __launch_bounds__(256) void scan_kernel(
    const int* __restrict__ cnt, int* __restrict__ base,
    int* __restrict__ cursor, const float* __restrict__ ema_cs,
    float* __restrict__ nbuf) {
  __shared__ int part[256];
  __shared__ float esum[256];
  int t = threadIdx.x;
  int local[8];
  int s = 0;
  float es = 0.0f;
#pragma unroll
  for (int i = 0; i < 8; i++) {
    local[i] = cnt[t * 8 + i];
    s += local[i];
    es += ema_cs[t * 8 + i];
  }
  part[t] = s;
  esum[t] = es;
  __syncthreads();
  for (int off = 1; off < 256; off <<= 1) {
    int v = (t >= off) ? part[t - off] : 0;
    __syncthreads();
    part[t] += v;
    __syncthreads();
  }
  int run = part[t] - s;  // exclusive prefix for this thread's chunk
#pragma unroll
  for (int i = 0; i < 8; i++) {
    base[t * 8 + i] = run;
    cursor[t * 8 + i] = run;
    run += local[i];
  }
  // reduce esum
  for (int o = 128; o; o >>= 1) {
    if (t < o) esum[t] += esum[t + o];
    __syncthreads();
  }
  if (t == 0) nbuf[0] = 0.9f * esum[0] + 0.1f * (float)RM;
}

__global__ __launch_bounds__(256) void scatter_kernel(
    const int* __restrict__ idxi, int* __restrict__ cursor,
    int* __restrict__ bucket) {
  int r = blockIdx.x * 256 + threadIdx.x;
  if (r < RM) {
    int p = atomicAdd(&cursor[idxi[r]], 1);
    bucket[p] = r;
  }
}

// ---------------- quant gather (ptf out) + loss partials, no hot atomics ----------------
__global__ __launch_bounds__(256) void quant_out_kernel(
    const float* __restrict__ feat, const float* __restrict__ CBm,
    const int* __restrict__ idxi, float* __restrict__ ptf_out,
    float* __restrict__ lpart) {
  __shared__ float wred[4];
  int row = blockIdx.x * 2 + (threadIdx.x >> 7);
  int t = threadIdx.x & 127;
  int k = idxi[row];
  float4 f = ((const float4*)(feat + (size_t)row * 512))[t];
  float4 c = ((const float4*)(CBm + (size_t)k * 512))[t];
  float* po = ptf_out + (size_t)row * 512 + 4 * t;  // base misaligned -> scalar
  po[0] = c.x; po[1] = c.y; po[2] = c.z; po[3] = c.w;
  float dx = c.x - f.x, dy = c.y - f.y, dz = c.z - f.z, dwv = c.w - f.w;
  float ls = dx * dx + dy * dy + dz * dz + dwv * dwv;
#pragma unroll
  for (int m = 32; m; m >>= 1) ls += __shfl_xor(ls, m);
  if ((threadIdx.x & 63) == 0) wred[threadIdx.x >> 6] = ls;
  __syncthreads();
  if (threadIdx.x == 0)
    lpart[blockIdx.x] = wred[0] + wred[1] + wred[2] + wred[3];
}

__global__ __launch_bounds__(256) void loss_final_kernel(
    const float* __restrict__ lpart, float* __restrict__ loss_out) {
  __shared__ float red[256];
  float s = 0.0f;
  for (int i = threadIdx.x; i < RM / 2; i += 256) s += lpart[i];
  red[threadIdx.x] = s;
  __syncthreads();
  for (int o = 128; o; o >>= 1) {
    if (threadIdx.x < o) red[threadIdx.x] += red[threadIdx.x + o];
    __syncthreads();
  }
  if (threadIdx.x == 0)
    loss_out[0] = red[0] / (float)((size_t)RM * 512);
}

// ---------------- segment-sum dw + fused codebook_new ----------------
// grid (2048, 4): block = entry k, dim segment of 128. 64 threads, float2 each.
__global__ __launch_bounds__(64) void dwsum_cb_kernel(
    const float* __restrict__ feat, const int* __restrict__ cnt,
    const int* __restrict__ base, const int* __restrict__ bucket,
    const float* __restrict__ ema_cs, const float* __restrict__ ema_w,
    const float* __restrict__ nbuf, float* __restrict__ out_cb) {
  __shared__ int srows[64];
  const int k = blockIdx.x;
  const int dseg = blockIdx.y * 128;
  const int t = threadIdx.x;
  const int c = cnt[k];
  const int bs = base[k];
  float ax = 0.0f, ay = 0.0f;
  for (int c0 = 0; c0 < c; c0 += 64) {
    int lim = min(64, c - c0);
    if (t < lim) srows[t] = bucket[bs + c0 + t];
    __syncthreads();
    for (int i = 0; i < lim; i++) {
      const float2 f = *(const float2*)(feat + (size_t)srows[i] * 512 + dseg + 2 * t);
      ax += f.x;
      ay += f.y;
    }
    __syncthreads();
  }
  float n = nbuf[0];
  float csv = ema_cs[k] * 0.9f + 0.1f * (float)c;
  csv = (csv + 1e-5f) / (n + 0.02048f) * n;
  size_t o = (size_t)k * 512 + dseg + 2 * t;
  // out_cb base misaligned by 1 float -> scalar stores
  out_cb[o] = (ema_w[o] * 0.9f + 0.1f * ax) / csv;
  out_cb[o + 1] = (ema_w[o + 1] * 0.9f + 0.1f * ay) / csv;
}

// ---------------- small-N GEMM ----------------
template <int GELU_FLAG, int RES_FLAG>
__global__ __launch_bounds__(256) void small_gemm(
    const float* __restrict__ A, const float* __restrict__ W,
    const float* __restrict__ bias, const float* __restrict__ R,
    float* __restrict__ out, int Mrows, int K, int N) {
  int tid = blockIdx.x * 256 + threadIdx.x;
  int r = tid / N, c = tid % N;
  if (r >= Mrows) return;
  float s = bias[c];
  const float4* pa = (const float4*)(A + (size_t)r * K);
  const float* pw = W + c;
  int k4 = K >> 2;
  for (int kk = 0; kk < k4; kk++) {
    float4 a = pa[kk];
    s = fmaf(a.x, pw[(4 * kk + 0) * N], s);
    s = fmaf(a.y, pw[(4 * kk + 1) * N], s);
    s = fmaf(a.z, pw[(4 * kk + 2) * N], s);
    s = fmaf(a.w, pw[(4 * kk + 3) * N], s);
  }
  if (GELU_FLAG) s = gelu_f(s);
  if (RES_FLAG) s += R[(size_t)r * N + c];
  out[(size_t)r * N + c] = s;
}

// ================================================================
extern "C" void kernel_launch(void* const* d_in, const int* in_sizes, int n_in,
                              void* d_out, int out_size, void* d_ws, size_t ws_size,
                              hipStream_t stream) {
  const float* joints   = (const float*)d_in[0];
  const float* inv_tok  = (const float*)d_in[3];
  const float* start_w  = (const float*)d_in[4];
  const float* start_b  = (const float*)d_in[5];
  const float* e_ln1g = (const float*)d_in[6];
  const float* e_ln1b = (const float*)d_in[7];
  const float* e_tw1  = (const float*)d_in[8];
  const float* e_tb1  = (const float*)d_in[9];
  const float* e_tw2  = (const float*)d_in[10];
  const float* e_tb2  = (const float*)d_in[11];
  const float* e_ln2g = (const float*)d_in[12];
  const float* e_ln2b = (const float*)d_in[13];
  const float* e_cw1  = (const float*)d_in[14];
  const float* e_cb1  = (const float*)d_in[15];
  const float* e_cw2  = (const float*)d_in[16];
  const float* e_cb2  = (const float*)d_in[17];
  const float* d_ln1g = (const float*)d_in[18];
  const float* d_ln1b = (const float*)d_in[19];
  const float* d_tw1  = (const float*)d_in[20];
  const float* d_tb1  = (const float*)d_in[21];
  const float* d_tw2  = (const float*)d_in[22];
  const float* d_tb2  = (const float*)d_in[23];
  const float* d_ln2g = (const float*)d_in[24];
  const float* d_ln2b = (const float*)d_in[25];
  const float* d_cw1  = (const float*)d_in[26];
  const float* d_cb1  = (const float*)d_in[27];
  const float* d_cw2  = (const float*)d_in[28];
  const float* d_cb2  = (const float*)d_in[29];
  const float* enc_lng = (const float*)d_in[30];
  const float* enc_lnb = (const float*)d_in[31];
  const float* tok_w   = (const float*)d_in[32];
  const float* tok_b   = (const float*)d_in[33];
  const float* feat_w  = (const float*)d_in[34];
  const float* feat_b  = (const float*)d_in[35];
  const float* codebook = (const float*)d_in[36];
  const float* ema_cs   = (const float*)d_in[37];
  const float* ema_w    = (const float*)d_in[38];
  const float* dtok_w   = (const float*)d_in[39];
  const float* dtok_b   = (const float*)d_in[40];
  const float* dstart_w = (const float*)d_in[41];
  const float* dstart_b = (const float*)d_in[42];
  const float* dec_lng  = (const float*)d_in[43];
  const float* dec_lnb  = (const float*)d_in[44];
  const float* rec_w    = (const float*)d_in[45];
  const float* rec_b    = (const float*)d_in[46];

  // -------- workspace layout (floats) --------
  float* ws = (float*)d_ws;
  float* Ab = ws;                 // [RJ,512]; later feat spans Ab..Ab+SZM
  float* Bb = ws + SZX;
  float* Cc = ws + 2 * SZX;
  float* Mm = ws + 3 * SZX;       // [RM,512]
  float* feat = Ab;               // [RM,512]
  float* tail = ws + 3 * SZX + SZM;
  float* cnorm = tail;                          // 2048
  float* pval = cnorm + 2048;                   // RM*16
  int* pidx = (int*)(pval + (size_t)RM * 16);   // RM*16
  int* idxi = pidx + (size_t)RM * 16;           // RM
  int* cnt = idxi + RM;                         // 2048
  int* basebuf = cnt + 2048;                    // 2048
  int* cursor = basebuf + 2048;                 // 2048
  int* bucket = cursor + 2048;                  // RM
  float* nbuf = (float*)(bucket + RM);          // 1
  float* lpart = nbuf + 1;                      // RM/2
  // decoder small buffers carved from Mm region
  float* dy  = Mm;
  float* dx2 = Mm + (size_t)RJ * 32;
  float* dh  = Mm + (size_t)2 * RJ * 32;
  float* dln = Mm + (size_t)2 * RJ * 32 + (size_t)RJ * 64;

  // -------- outputs --------
  float* outp = (float*)d_out;
  float* o_rec = outp;                       // [RJ,2]
  float* o_idx = outp + (size_t)RJ * 2;      // [RM]
  float* o_loss = o_idx + RM;                // [1]
  float* o_ptf = o_loss + 1;                 // [RM,512]
  float* o_cb = o_ptf + SZM;                 // [2048,512]

  hipMemsetAsync(cnt, 0, 2048 * sizeof(int), stream);

  // -------- encoder --------
  embed_kernel<<<(RJ * 512) / 256, 256, 0, stream>>>(joints, inv_tok, start_w, start_b, Ab);
  for (int i = 0; i < 4; i++) {
    ln_kernel<8><<<RJ / 4, 256, 0, stream>>>(Ab, Cc, e_ln1g + i * 512, e_ln1b + i * 512, RJ, 512);
    tokenmix_kernel<<<(Bn * 512) / 256, 256, 0, stream>>>(
        Cc, Ab, Bb, e_tw1 + i * 17 * 64, e_tb1 + i * 64, e_tw2 + i * 64 * 17, e_tb2 + i * 17, Bn, 512);
    ln_kernel<8><<<RJ / 4, 256, 0, stream>>>(Bb, Cc, e_ln2g + i * 512, e_ln2b + i * 512, RJ, 512);
    gemm128<1, 0><<<dim3(RJ / 128, 4), 256, 0, stream>>>(
        Cc, e_cw1 + (size_t)i * 512 * 512, e_cb1 + i * 512, nullptr, Mm, RJ, 512, 512);
    gemm128<0, 1><<<dim3(RJ / 128, 4), 256, 0, stream>>>(
        Mm, e_cw2 + (size_t)i * 512 * 512, e_cb2 + i * 512, Bb, Ab, RJ, 512, 512);
  }
  ln_kernel<8><<<RJ / 4, 256, 0, stream>>>(Ab, Cc, enc_lng, enc_lnb, RJ, 512);
  linmix_kernel<17, 34><<<(Bn * 512) / 256, 256, 0, stream>>>(Cc, Mm, tok_w, tok_b, Bn, 512);
  gemm128<0, 0><<<dim3(RM / 128, 4), 256, 0, stream>>>(Mm, feat_w, feat_b, nullptr, feat, RM, 512, 512);

  // -------- VQ: distances + argmin --------
  cnorm_kernel<<<2048 / 4, 256, 0, stream>>>(codebook, cnorm);
  dist_gemm<<<dim3(RM / 128, 2048 / 128), 256, 0, stream>>>(feat, codebook, cnorm, pval, pidx, 512);
  argmin_reduce<<<RM / 256, 256, 0, stream>>>(pval, pidx, idxi, o_idx, RM);

  // -------- bucketed EMA update (no hot atomics) --------
  count_kernel<<<RM / 256, 256, 0, stream>>>(idxi, cnt);
  scan_kernel<<<1, 256, 0, stream>>>(cnt, basebuf, cursor, ema_cs, nbuf);
  scatter_kernel<<<RM / 256, 256, 0, stream>>>(idxi, cursor, bucket);
  quant_out_kernel<<<RM / 2, 256, 0, stream>>>(feat, codebook, idxi, o_ptf, lpart);
  loss_final_kernel<<<1, 256, 0, stream>>>(lpart, o_loss);
  dwsum_cb_kernel<<<dim3(2048, 4), 64, 0, stream>>>(
      feat, cnt, basebuf, bucket, ema_cs, ema_w, nbuf, o_cb);

  // -------- decoder --------
  linmix_kernel<34, 17><<<(Bn * 512) / 256, 256, 0, stream>>>(o_ptf, Cc, dtok_w, dtok_b, Bn, 512);
  small_gemm<0, 0><<<(RJ * 32) / 256, 256, 0, stream>>>(Cc, dstart_w, dstart_b, nullptr, dy, RJ, 512, 32);
  ln_kernel<1><<<RJ / 4, 256, 0, stream>>>(dy, dln, d_ln1g, d_ln1b, RJ, 32);
  tokenmix_kernel<<<(Bn * 32) / 256, 256, 0, stream>>>(dln, dy, dx2, d_tw1, d_tb1, d_tw2, d_tb2, Bn, 32);
  ln_kernel<1><<<RJ / 4, 256, 0, stream>>>(dx2, dln, d_ln2g, d_ln2b, RJ, 32);
  small_gemm<1, 0><<<(RJ * 64) / 256, 256, 0, stream>>>(dln, d_cw1, d_cb1, nullptr, dh, RJ, 32, 64);
  small_gemm<0, 1><<<(RJ * 32) / 256, 256, 0, stream>>>(dh, d_cw2, d_cb2, dx2, dy, RJ, 64, 32);
  ln_kernel<1><<<RJ / 4, 256, 0, stream>>>(dy, dln, dec_lng, dec_lnb, RJ, 32);
  small_gemm<0, 0><<<(RJ * 2) / 256, 256, 0, stream>>>(dln, rec_w, rec_b, nullptr, o_rec, RJ, 32, 2);
}

// Round 3
// 3061.559 us; speedup vs baseline: 1.8530x; 1.7380x over previous
//
#include <hip/hip_runtime.h>
#include <math.h>

// ---------------- problem constants ----------------
constexpr int Bn = 1024, Jn = 17, Dn = 512, Mn = 34, Kcb = 2048, DTn = 512;
constexpr int RJ = Bn * Jn;                 // 17408 rows [B,J]
constexpr int RM = Bn * Mn;                 // 34816 rows [B,M]
constexpr size_t SZX = (size_t)RJ * Dn;     // 8,912,896 floats
constexpr size_t SZM = (size_t)RM * DTn;    // 17,825,792 floats

__device__ __forceinline__ float gelu_f(float x) {
  return 0.5f * x * (1.0f + erff(x * 0.7071067811865475f));
}

// ---------------- embed ----------------
__global__ __launch_bounds__(256) void embed_kernel(
    const float* __restrict__ joints, const float* __restrict__ inv,
    const float* __restrict__ sw, const float* __restrict__ sb,
    float* __restrict__ out) {
  int tid = blockIdx.x * 256 + threadIdx.x;
  int row = tid >> 9, d = tid & 511;
  float j0 = joints[row * 3 + 0];
  float j1 = joints[row * 3 + 1];
  float j2 = joints[row * 3 + 2];
  float x = fmaf(j0, sw[d], fmaf(j1, sw[512 + d], sb[d]));
  float v = (j2 != 0.0f) ? 1.0f : 0.0f;
  out[tid] = x * v + inv[d] * (1.0f - v);
}

// ---------------- LayerNorm: wave per row ----------------
template <int NV>
__global__ __launch_bounds__(256) void ln_kernel(
    const float* __restrict__ src, float* __restrict__ dst,
    const float* __restrict__ g, const float* __restrict__ b,
    int rows, int D) {
  int wave = threadIdx.x >> 6;
  int lane = threadIdx.x & 63;
  int row = blockIdx.x * 4 + wave;
  if (row >= rows) return;
  const float* p = src + (size_t)row * D;
  float v[NV];
  float s = 0.0f;
#pragma unroll
  for (int i = 0; i < NV; i++) {
    int d = lane + 64 * i;
    v[i] = (d < D) ? p[d] : 0.0f;
    s += v[i];
  }
#pragma unroll
  for (int m = 32; m; m >>= 1) s += __shfl_xor(s, m);
  float mean = s / (float)D;
  float s2 = 0.0f;
#pragma unroll
  for (int i = 0; i < NV; i++) {
    int d = lane + 64 * i;
    float t = (d < D) ? (v[i] - mean) : 0.0f;
    s2 += t * t;
  }
#pragma unroll
  for (int m = 32; m; m >>= 1) s2 += __shfl_xor(s2, m);
  float rs = 1.0f / sqrtf(s2 / (float)D + 1e-5f);
  float* q = dst + (size_t)row * D;
#pragma unroll
  for (int i = 0; i < NV; i++) {
    int d = lane + 64 * i;
    if (d < D) q[d] = (v[i] - mean) * rs * g[d] + b[d];
  }
}

// ---------------- token mixing (17->64->17) fused residual ----------------
__global__ __launch_bounds__(256) void tokenmix_kernel(
    const float* __restrict__ ln, const float* __restrict__ xin,
    float* __restrict__ out, const float* __restrict__ tw1,
    const float* __restrict__ tb1, const float* __restrict__ tw2,
    const float* __restrict__ tb2, int B, int H) {
  __shared__ float sw1[17 * 64], sw2[64 * 17], sb1[64], sb2[17];
  for (int i = threadIdx.x; i < 17 * 64; i += 256) {
    sw1[i] = tw1[i];
    sw2[i] = tw2[i];
  }
  if (threadIdx.x < 64) sb1[threadIdx.x] = tb1[threadIdx.x];
  if (threadIdx.x < 17) sb2[threadIdx.x] = tb2[threadIdx.x];
  __syncthreads();
  int tid = blockIdx.x * 256 + threadIdx.x;
  if (tid >= B * H) return;
  int b = tid / H, d = tid % H;
  const float* pl = ln + (size_t)b * 17 * H + d;
  float t[17], acc[17];
#pragma unroll
  for (int j = 0; j < 17; j++) {
    t[j] = pl[j * H];
    acc[j] = 0.0f;
  }
  for (int k = 0; k < 64; k++) {
    float h = sb1[k];
#pragma unroll
    for (int j = 0; j < 17; j++) h = fmaf(t[j], sw1[j * 64 + k], h);
    h = gelu_f(h);
#pragma unroll
    for (int j = 0; j < 17; j++) acc[j] = fmaf(h, sw2[k * 17 + j], acc[j]);
  }
  const float* px = xin + (size_t)b * 17 * H + d;
  float* po = out + (size_t)b * 17 * H + d;
#pragma unroll
  for (int j = 0; j < 17; j++) po[j * H] = px[j * H] + acc[j] + sb2[j];
}

// ---------------- linear mix over joint/token axis ----------------
template <int JIN, int JOUT>
__global__ __launch_bounds__(256) void linmix_kernel(
    const float* __restrict__ in, float* __restrict__ out,
    const float* __restrict__ w, const float* __restrict__ bias,
    int B, int H) {
  __shared__ float sw[JIN * JOUT], sb[JOUT];
  for (int i = threadIdx.x; i < JIN * JOUT; i += 256) sw[i] = w[i];
  if (threadIdx.x < JOUT) sb[threadIdx.x] = bias[threadIdx.x];
  __syncthreads();
  int tid = blockIdx.x * 256 + threadIdx.x;
  if (tid >= B * H) return;
  int b = tid / H, d = tid % H;
  const float* pi = in + (size_t)b * JIN * H + d;
  float t[JIN];
#pragma unroll
  for (int j = 0; j < JIN; j++) t[j] = pi[(size_t)j * H];
  float* po = out + (size_t)b * JOUT * H + d;
#pragma unroll
  for (int m = 0; m < JOUT; m++) {
    float s = sb[m];
#pragma unroll
    for (int j = 0; j < JIN; j++) s = fmaf(t[j], sw[j * JOUT + m], s);
    po[(size_t)m * H] = s;
  }
}

// ---------------- big fp32 GEMM: 128x128 tile, 8x8/thread ----------------
template <int GELU_FLAG, int RES_FLAG>
__global__ __launch_bounds__(256) void gemm128(
    const float* __restrict__ A, const float* __restrict__ W,
    const float* __restrict__ bias, const float* __restrict__ R,
    float* __restrict__ C, int Mdim, int K, int N) {
  __shared__ float sA[16][132];
  __shared__ float sW[16][132];
  const int tid = threadIdx.x;
  const int tx = tid & 15, ty = tid >> 4;
  const int m0 = blockIdx.x * 128, n0 = blockIdx.y * 128;
  const int lr = tid >> 2;
  const int lc4 = (tid & 3) * 4;
  float acc[8][8] = {};
  for (int k0 = 0; k0 < K; k0 += 16) {
    float4 a0 = *(const float4*)(A + (size_t)(m0 + lr) * K + k0 + lc4);
    float4 a1 = *(const float4*)(A + (size_t)(m0 + lr + 64) * K + k0 + lc4);
    sA[lc4 + 0][lr] = a0.x; sA[lc4 + 1][lr] = a0.y;
    sA[lc4 + 2][lr] = a0.z; sA[lc4 + 3][lr] = a0.w;
    sA[lc4 + 0][lr + 64] = a1.x; sA[lc4 + 1][lr + 64] = a1.y;
    sA[lc4 + 2][lr + 64] = a1.z; sA[lc4 + 3][lr + 64] = a1.w;
    {
      const int wk = tid >> 5;
      const int wc = (tid & 31) * 4;
      float4 w0 = *(const float4*)(W + (size_t)(k0 + wk) * N + n0 + wc);
      float4 w1 = *(const float4*)(W + (size_t)(k0 + wk + 8) * N + n0 + wc);
      *(float4*)&sW[wk][wc] = w0;
      *(float4*)&sW[wk + 8][wc] = w1;
    }
    __syncthreads();
#pragma unroll
    for (int kk = 0; kk < 16; kk++) {
      float4 av0 = *(const float4*)&sA[kk][tx * 4];
      float4 av1 = *(const float4*)&sA[kk][64 + tx * 4];
      float4 wv0 = *(const float4*)&sW[kk][ty * 4];
      float4 wv1 = *(const float4*)&sW[kk][64 + ty * 4];
      float a[8] = {av0.x, av0.y, av0.z, av0.w, av1.x, av1.y, av1.z, av1.w};
      float w[8] = {wv0.x, wv0.y, wv0.z, wv0.w, wv1.x, wv1.y, wv1.z, wv1.w};
#pragma unroll
      for (int i = 0; i < 8; i++)
#pragma unroll
        for (int j = 0; j < 8; j++) acc[i][j] = fmaf(a[i], w[j], acc[i][j]);
    }
    __syncthreads();
  }
#pragma unroll
  for (int gi = 0; gi < 2; gi++)
#pragma unroll
    for (int u = 0; u < 4; u++) {
      int r = m0 + gi * 64 + tx * 4 + u;
      int ai = gi * 4 + u;
#pragma unroll
      for (int gj = 0; gj < 2; gj++) {
        int cb = n0 + gj * 64 + ty * 4;
        float4 bv = *(const float4*)(bias + cb);
        float4 o;
        o.x = acc[ai][gj * 4 + 0] + bv.x;
        o.y = acc[ai][gj * 4 + 1] + bv.y;
        o.z = acc[ai][gj * 4 + 2] + bv.z;
        o.w = acc[ai][gj * 4 + 3] + bv.w;
        if (GELU_FLAG) {
          o.x = gelu_f(o.x); o.y = gelu_f(o.y);
          o.z = gelu_f(o.z); o.w = gelu_f(o.w);
        }
        if (RES_FLAG) {
          float4 rv = *(const float4*)(R + (size_t)r * N + cb);
          o.x += rv.x; o.y += rv.y; o.z += rv.z; o.w += rv.w;
        }
        *(float4*)(C + (size_t)r * N + cb) = o;
      }
    }
}

// ---------------- codebook L2 norms ----------------
__global__ __launch_bounds__(256) void cnorm_kernel(
    const float* __restrict__ CBm, float* __restrict__ cnorm) {
  int wave = threadIdx.x >> 6, lane = threadIdx.x & 63;
  int k = blockIdx.x * 4 + wave;
  const float* p = CBm + (size_t)k * 512;
  float s = 0.0f;
#pragma unroll
  for (int i = 0; i < 8; i++) {
    float v = p[lane + 64 * i];
    s = fmaf(v, v, s);
  }
#pragma unroll
  for (int m = 32; m; m >>= 1) s += __shfl_xor(s, m);
  if (lane == 0) cnorm[k] = s;
}

// ---------------- distance GEMM + fused per-block argmin ----------------
__global__ __launch_bounds__(256) void dist_gemm(
    const float* __restrict__ A, const float* __restrict__ CBm,
    const float* __restrict__ cnorm, float* __restrict__ pval,
    int* __restrict__ pidx, int K) {
  __shared__ float sA[16][132];
  __shared__ float sW[16][132];
  __shared__ float rv[128][17];
  __shared__ int ri[128][17];
  const int tid = threadIdx.x;
  const int tx = tid & 15, ty = tid >> 4;
  const int m0 = blockIdx.x * 128, n0 = blockIdx.y * 128;
  const int lr = tid >> 2;
  const int lc4 = (tid & 3) * 4;
  float acc[8][8] = {};
  for (int k0 = 0; k0 < K; k0 += 16) {
    float4 a0 = *(const float4*)(A + (size_t)(m0 + lr) * K + k0 + lc4);
    float4 a1 = *(const float4*)(A + (size_t)(m0 + lr + 64) * K + k0 + lc4);
    float4 w0 = *(const float4*)(CBm + (size_t)(n0 + lr) * K + k0 + lc4);
    float4 w1 = *(const float4*)(CBm + (size_t)(n0 + lr + 64) * K + k0 + lc4);
    sA[lc4 + 0][lr] = a0.x; sA[lc4 + 1][lr] = a0.y;
    sA[lc4 + 2][lr] = a0.z; sA[lc4 + 3][lr] = a0.w;
    sA[lc4 + 0][lr + 64] = a1.x; sA[lc4 + 1][lr + 64] = a1.y;
    sA[lc4 + 2][lr + 64] = a1.z; sA[lc4 + 3][lr + 64] = a1.w;
    sW[lc4 + 0][lr] = w0.x; sW[lc4 + 1][lr] = w0.y;
    sW[lc4 + 2][lr] = w0.z; sW[lc4 + 3][lr] = w0.w;
    sW[lc4 + 0][lr + 64] = w1.x; sW[lc4 + 1][lr + 64] = w1.y;
    sW[lc4 + 2][lr + 64] = w1.z; sW[lc4 + 3][lr + 64] = w1.w;
    __syncthreads();
#pragma unroll
    for (int kk = 0; kk < 16; kk++) {
      float4 av0 = *(const float4*)&sA[kk][tx * 4];
      float4 av1 = *(const float4*)&sA[kk][64 + tx * 4];
      float4 wv0 = *(const float4*)&sW[kk][ty * 4];
      float4 wv1 = *(const float4*)&sW[kk][64 + ty * 4];
      float a[8] = {av0.x, av0.y, av0.z, av0.w, av1.x, av1.y, av1.z, av1.w};
      float w[8] = {wv0.x, wv0.y, wv0.z, wv0.w, wv1.x, wv1.y, wv1.z, wv1.w};
#pragma unroll
      for (int i = 0; i < 8; i++)
#pragma unroll
        for (int j = 0; j < 8; j++) acc[i][j] = fmaf(a[i], w[j], acc[i][j]);
    }
    __syncthreads();
  }
#pragma unroll
  for (int gi = 0; gi < 2; gi++)
#pragma unroll
    for (int u = 0; u < 4; u++) {
      const int ai = gi * 4 + u;
      float bv = 3.0e38f;
      int bi = 0x7fffffff;
#pragma unroll
      for (int gj = 0; gj < 2; gj++)
#pragma unroll
        for (int v = 0; v < 4; v++) {
          int c = n0 + gj * 64 + ty * 4 + v;
          float d = cnorm[c] - 2.0f * acc[ai][gj * 4 + v];
          if (d < bv || (d == bv && c < bi)) { bv = d; bi = c; }
        }
      int rl = gi * 64 + tx * 4 + u;
      rv[rl][ty] = bv;
      ri[rl][ty] = bi;
    }
  __syncthreads();
  if (tid < 128) {
    float bv = rv[tid][0];
    int bi = ri[tid][0];
#pragma unroll
    for (int t = 1; t < 16; t++) {
      float v = rv[tid][t];
      int i2 = ri[tid][t];
      if (v < bv || (v == bv && i2 < bi)) { bv = v; bi = i2; }
    }
    int row = m0 + tid;
    pval[row * 16 + blockIdx.y] = bv;
    pidx[row * 16 + blockIdx.y] = bi;
  }
}

// ---------------- argmin across the 16 N-block partials ----------------
__global__ __launch_bounds__(256) void argmin_reduce(
    const float* __restrict__ pval, const int* __restrict__ pidx,
    int* __restrict__ idxi, float* __restrict__ idxf, int rows) {
  int r = blockIdx.x * 256 + threadIdx.x;
  if (r >= rows) return;
  float bv = pval[r * 16];
  int bi = pidx[r * 16];
#pragma unroll
  for (int t = 1; t < 16; t++) {
    float v = pval[r * 16 + t];
    int i2 = pidx[r * 16 + t];
    if (v < bv || (v == bv && i2 < bi)) { bv = v; bi = i2; }
  }
  idxi[r] = bi;
  idxf[r] = (float)bi;
}

// ---------------- skew-oblivious count: per-block LDS histogram ----------------
__global__ __launch_bounds__(256) void count_kernel(
    const int* __restrict__ idxi, int* __restrict__ cnt) {
  __shared__ int h[2048];
  for (int i = threadIdx.x; i < 2048; i += 256) h[i] = 0;
  __syncthreads();
  int r = blockIdx.x * 256 + threadIdx.x;  // RM % 256 == 0
  atomicAdd(&h[idxi[r]], 1);
  __syncthreads();
  for (int i = threadIdx.x; i < 2048; i += 256) {
    int v = h[i];
    if (v) atomicAdd(&cnt[i], v);
  }
}

// one block: exclusive scan of 2048 counts; n = 0.9*sum(ema_cs) + 0.1*RM
__global__ __launch_bounds__(256) void scan_kernel(
    const int* __restrict__ cnt, int* __restrict__ base,
    int* __restrict__ cursor, const float* __restrict__ ema_cs,
    float* __restrict__ nbuf) {
  __shared__ int part[256];
  __shared__ float esum[256];
  int t = threadIdx.x;
  int local[8];
  int s = 0;
  float es = 0.0f;
#pragma unroll
  for (int i = 0; i < 8; i++) {
    local[i] = cnt[t * 8 + i];
    s += local[i];
    es += ema_cs[t * 8 + i];
  }
  part[t] = s;
  esum[t] = es;
  __syncthreads();
  for (int off = 1; off < 256; off <<= 1) {
    int v = (t >= off) ? part[t - off] : 0;
    __syncthreads();
    part[t] += v;
    __syncthreads();
  }
  int run = part[t] - s;
#pragma unroll
  for (int i = 0; i < 8; i++) {
    base[t * 8 + i] = run;
    cursor[t * 8 + i] = run;
    run += local[i];
  }
  for (int o = 128; o; o >>= 1) {
    if (t < o) esum[t] += esum[t + o];
    __syncthreads();
  }
  if (t == 0) nbuf[0] = 0.9f * esum[0] + 0.1f * (float)RM;
}

// ---------------- skew-oblivious scatter: block-aggregated cursor reservation ----------------
// bucket entry packs (k << 17) | row  (k < 2048 -> 11 bits, row < 131072)
__global__ __launch_bounds__(256) void scatter_kernel(
    const int* __restrict__ idxi, int* __restrict__ cursor,
    unsigned int* __restrict__ bucket) {
  __shared__ int h[2048];
  __shared__ int gb[2048];
  for (int i = threadIdx.x; i < 2048; i += 256) h[i] = 0;
  __syncthreads();
  int r = blockIdx.x * 256 + threadIdx.x;
  int k = idxi[r];
  int lrank = atomicAdd(&h[k], 1);
  __syncthreads();
  for (int i = threadIdx.x; i < 2048; i += 256) {
    int v = h[i];
    gb[i] = v ? atomicAdd(&cursor[i], v) : 0;
  }
  __syncthreads();
  bucket[gb[k] + lrank] = ((unsigned int)k << 17) | (unsigned int)r;
}

// ---------------- quant gather (ptf out) + loss partials ----------------
__global__ __launch_bounds__(256) void quant_out_kernel(
    const float* __restrict__ feat, const float* __restrict__ CBm,
    const int* __restrict__ idxi, float* __restrict__ ptf_out,
    float* __restrict__ lpart) {
  __shared__ float wred[4];
  int row = blockIdx.x * 2 + (threadIdx.x >> 7);
  int t = threadIdx.x & 127;
  int k = idxi[row];
  float4 f = ((const float4*)(feat + (size_t)row * 512))[t];
  float4 c = ((const float4*)(CBm + (size_t)k * 512))[t];
  float* po = ptf_out + (size_t)row * 512 + 4 * t;  // base misaligned -> scalar
  po[0] = c.x; po[1] = c.y; po[2] = c.z; po[3] = c.w;
  float dx = c.x - f.x, dy = c.y - f.y, dz = c.z - f.z, dwv = c.w - f.w;
  float ls = dx * dx + dy * dy + dz * dz + dwv * dwv;
#pragma unroll
  for (int m = 32; m; m >>= 1) ls += __shfl_xor(ls, m);
  if ((threadIdx.x & 63) == 0) wred[threadIdx.x >> 6] = ls;
  __syncthreads();
  if (threadIdx.x == 0)
    lpart[blockIdx.x] = wred[0] + wred[1] + wred[2] + wred[3];
}

__global__ __launch_bounds__(256) void loss_final_kernel(
    const float* __restrict__ lpart, float* __restrict__ loss_out) {
  __shared__ float red[256];
  float s = 0.0f;
  for (int i = threadIdx.x; i < RM / 2; i += 256) s += lpart[i];
  red[threadIdx.x] = s;
  __syncthreads();
  for (int o = 128; o; o >>= 1) {
    if (threadIdx.x < o) red[threadIdx.x] += red[threadIdx.x + o];
    __syncthreads();
  }
  if (threadIdx.x == 0)
    loss_out[0] = red[0] / (float)((size_t)RM * 512);
}

// ---------------- skew-oblivious dw: fixed 64-row chunks of bucket ----------------
// 256 threads: thread t owns dims [2t, 2t+1]. Flush partials on k-transition.
__global__ __launch_bounds__(256) void dwsum_chunk_kernel(
    const float* __restrict__ feat, const unsigned int* __restrict__ bucket,
    float* __restrict__ dw) {
  __shared__ unsigned int sp[64];
  const int t = threadIdx.x;
  if (t < 64) sp[t] = bucket[blockIdx.x * 64 + t];
  __syncthreads();
  float ax = 0.0f, ay = 0.0f;
  int curk = (int)(sp[0] >> 17);
  float2 fcur = *(const float2*)(feat + (size_t)(sp[0] & 0x1FFFF) * 512 + 2 * t);
  for (int i = 0; i < 64; i++) {
    float2 fnext = make_float2(0.0f, 0.0f);
    if (i + 1 < 64)
      fnext = *(const float2*)(feat + (size_t)(sp[i + 1] & 0x1FFFF) * 512 + 2 * t);
    int k = (int)(sp[i] >> 17);
    if (k != curk) {
      atomicAdd(&dw[(size_t)curk * 512 + 2 * t], ax);
      atomicAdd(&dw[(size_t)curk * 512 + 2 * t + 1], ay);
      ax = 0.0f; ay = 0.0f; curk = k;
    }
    ax += fcur.x;
    ay += fcur.y;
    fcur = fnext;
  }
  atomicAdd(&dw[(size_t)curk * 512 + 2 * t], ax);
  atomicAdd(&dw[(size_t)curk * 512 + 2 * t + 1], ay);
}

// ---------------- codebook_new finalize ----------------
__global__ __launch_bounds__(256) void cbnew_kernel(
    const float* __restrict__ ema_w, const float* __restrict__ dw,
    const float* __restrict__ ema_cs, const int* __restrict__ cnt,
    const float* __restrict__ nbuf, float* __restrict__ outp) {
  int tid = blockIdx.x * 256 + threadIdx.x;  // < 2048*512
  int k = tid >> 9;
  float n = nbuf[0];
  float cs = ema_cs[k] * 0.9f + 0.1f * (float)cnt[k];
  cs = (cs + 1e-5f) / (n + 0.02048f) * n;
  outp[tid] = (ema_w[tid] * 0.9f + 0.1f * dw[tid]) / cs;
}

// ---------------- small-N GEMM ----------------
template <int GELU_FLAG, int RES_FLAG>
__global__ __launch_bounds__(256) void small_gemm(
    const float* __restrict__ A, const float* __restrict__ W,
    const float* __restrict__ bias, const float* __restrict__ R,
    float* __restrict__ out, int Mrows, int K, int N) {
  int tid = blockIdx.x * 256 + threadIdx.x;
  int r = tid / N, c = tid % N;
  if (r >= Mrows) return;
  float s = bias[c];
  const float4* pa = (const float4*)(A + (size_t)r * K);
  const float* pw = W + c;
  int k4 = K >> 2;
  for (int kk = 0; kk < k4; kk++) {
    float4 a = pa[kk];
    s = fmaf(a.x, pw[(4 * kk + 0) * N], s);
    s = fmaf(a.y, pw[(4 * kk + 1) * N], s);
    s = fmaf(a.z, pw[(4 * kk + 2) * N], s);
    s = fmaf(a.w, pw[(4 * kk + 3) * N], s);
  }
  if (GELU_FLAG) s = gelu_f(s);
  if (RES_FLAG) s += R[(size_t)r * N + c];
  out[(size_t)r * N + c] = s;
}

// ================================================================
extern "C" void kernel_launch(void* const* d_in, const int* in_sizes, int n_in,
                              void* d_out, int out_size, void* d_ws, size_t ws_size,
                              hipStream_t stream) {
  const float* joints   = (const float*)d_in[0];
  const float* inv_tok  = (const float*)d_in[3];
  const float* start_w  = (const float*)d_in[4];
  const float* start_b  = (const float*)d_in[5];
  const float* e_ln1g = (const float*)d_in[6];
  const float* e_ln1b = (const float*)d_in[7];
  const float* e_tw1  = (const float*)d_in[8];
  const float* e_tb1  = (const float*)d_in[9];
  const float* e_tw2  = (const float*)d_in[10];
  const float* e_tb2  = (const float*)d_in[11];
  const float* e_ln2g = (const float*)d_in[12];
  const float* e_ln2b = (const float*)d_in[13];
  const float* e_cw1  = (const float*)d_in[14];
  const float* e_cb1  = (const float*)d_in[15];
  const float* e_cw2  = (const float*)d_in[16];
  const float* e_cb2  = (const float*)d_in[17];
  const float* d_ln1g = (const float*)d_in[18];
  const float* d_ln1b = (const float*)d_in[19];
  const float* d_tw1  = (const float*)d_in[20];
  const float* d_tb1  = (const float*)d_in[21];
  const float* d_tw2  = (const float*)d_in[22];
  const float* d_tb2  = (const float*)d_in[23];
  const float* d_ln2g = (const float*)d_in[24];
  const float* d_ln2b = (const float*)d_in[25];
  const float* d_cw1  = (const float*)d_in[26];
  const float* d_cb1  = (const float*)d_in[27];
  const float* d_cw2  = (const float*)d_in[28];
  const float* d_cb2  = (const float*)d_in[29];
  const float* enc_lng = (const float*)d_in[30];
  const float* enc_lnb = (const float*)d_in[31];
  const float* tok_w   = (const float*)d_in[32];
  const float* tok_b   = (const float*)d_in[33];
  const float* feat_w  = (const float*)d_in[34];
  const float* feat_b  = (const float*)d_in[35];
  const float* codebook = (const float*)d_in[36];
  const float* ema_cs   = (const float*)d_in[37];
  const float* ema_w    = (const float*)d_in[38];
  const float* dtok_w   = (const float*)d_in[39];
  const float* dtok_b   = (const float*)d_in[40];
  const float* dstart_w = (const float*)d_in[41];
  const float* dstart_b = (const float*)d_in[42];
  const float* dec_lng  = (const float*)d_in[43];
  const float* dec_lnb  = (const float*)d_in[44];
  const float* rec_w    = (const float*)d_in[45];
  const float* rec_b    = (const float*)d_in[46];

  // -------- workspace layout (floats) --------
  float* ws = (float*)d_ws;
  float* Ab = ws;                 // [RJ,512]; later feat spans Ab..Ab+SZM
  float* Bb = ws + SZX;
  float* Cc = ws + 2 * SZX;
  float* Mm = ws + 3 * SZX;       // [RM,512]
  float* feat = Ab;               // [RM,512]
  float* tail = ws + 3 * SZX + SZM;
  float* cnorm = tail;                          // 2048
  float* pval = cnorm + 2048;                   // RM*16
  int* pidx = (int*)(pval + (size_t)RM * 16);   // RM*16
  int* idxi = pidx + (size_t)RM * 16;           // RM
  int* cnt = idxi + RM;                         // 2048
  int* basebuf = cnt + 2048;                    // 2048
  int* cursor = basebuf + 2048;                 // 2048
  unsigned int* bucket = (unsigned int*)(cursor + 2048);  // RM
  float* nbuf = (float*)(bucket + RM);          // 1
  float* lpart = nbuf + 1;                      // RM/2
  float* dw = lpart + RM / 2;                   // 2048*512
  // decoder small buffers carved from Mm region
  float* dy  = Mm;
  float* dx2 = Mm + (size_t)RJ * 32;
  float* dh  = Mm + (size_t)2 * RJ * 32;
  float* dln = Mm + (size_t)2 * RJ * 32 + (size_t)RJ * 64;

  // -------- outputs --------
  float* outp = (float*)d_out;
  float* o_rec = outp;                       // [RJ,2]
  float* o_idx = outp + (size_t)RJ * 2;      // [RM]
  float* o_loss = o_idx + RM;                // [1]
  float* o_ptf = o_loss + 1;                 // [RM,512]
  float* o_cb = o_ptf + SZM;                 // [2048,512]

  hipMemsetAsync(cnt, 0, 2048 * sizeof(int), stream);
  hipMemsetAsync(dw, 0, (size_t)2048 * 512 * sizeof(float), stream);

  // -------- encoder --------
  embed_kernel<<<(RJ * 512) / 256, 256, 0, stream>>>(joints, inv_tok, start_w, start_b, Ab);
  for (int i = 0; i < 4; i++) {
    ln_kernel<8><<<RJ / 4, 256, 0, stream>>>(Ab, Cc, e_ln1g + i * 512, e_ln1b + i * 512, RJ, 512);
    tokenmix_kernel<<<(Bn * 512) / 256, 256, 0, stream>>>(
        Cc, Ab, Bb, e_tw1 + i * 17 * 64, e_tb1 + i * 64, e_tw2 + i * 64 * 17, e_tb2 + i * 17, Bn, 512);
    ln_kernel<8><<<RJ / 4, 256, 0, stream>>>(Bb, Cc, e_ln2g + i * 512, e_ln2b + i * 512, RJ, 512);
    gemm128<1, 0><<<dim3(RJ / 128, 4), 256, 0, stream>>>(
        Cc, e_cw1 + (size_t)i * 512 * 512, e_cb1 + i * 512, nullptr, Mm, RJ, 512, 512);
    gemm128<0, 1><<<dim3(RJ / 128, 4), 256, 0, stream>>>(
        Mm, e_cw2 + (size_t)i * 512 * 512, e_cb2 + i * 512, Bb, Ab, RJ, 512, 512);
  }
  ln_kernel<8><<<RJ / 4, 256, 0, stream>>>(Ab, Cc, enc_lng, enc_lnb, RJ, 512);
  linmix_kernel<17, 34><<<(Bn * 512) / 256, 256, 0, stream>>>(Cc, Mm, tok_w, tok_b, Bn, 512);
  gemm128<0, 0><<<dim3(RM / 128, 4), 256, 0, stream>>>(Mm, feat_w, feat_b, nullptr, feat, RM, 512, 512);

  // -------- VQ: distances + argmin --------
  cnorm_kernel<<<2048 / 4, 256, 0, stream>>>(codebook, cnorm);
  dist_gemm<<<dim3(RM / 128, 2048 / 128), 256, 0, stream>>>(feat, codebook, cnorm, pval, pidx, 512);
  argmin_reduce<<<RM / 256, 256, 0, stream>>>(pval, pidx, idxi, o_idx, RM);

  // -------- skew-oblivious bucketed EMA update --------
  count_kernel<<<RM / 256, 256, 0, stream>>>(idxi, cnt);
  scan_kernel<<<1, 256, 0, stream>>>(cnt, basebuf, cursor, ema_cs, nbuf);
  scatter_kernel<<<RM / 256, 256, 0, stream>>>(idxi, cursor, bucket);
  quant_out_kernel<<<RM / 2, 256, 0, stream>>>(feat, codebook, idxi, o_ptf, lpart);
  loss_final_kernel<<<1, 256, 0, stream>>>(lpart, o_loss);
  dwsum_chunk_kernel<<<RM / 64, 256, 0, stream>>>(feat, bucket, dw);
  cbnew_kernel<<<(2048 * 512) / 256, 256, 0, stream>>>(ema_w, dw, ema_cs, cnt, nbuf, o_cb);

  // -------- decoder --------
  linmix_kernel<34, 17><<<(Bn * 512) / 256, 256, 0, stream>>>(o_ptf, Cc, dtok_w, dtok_b, Bn, 512);
  small_gemm<0, 0><<<(RJ * 32) / 256, 256, 0, stream>>>(Cc, dstart_w, dstart_b, nullptr, dy, RJ, 512, 32);
  ln_kernel<1><<<RJ / 4, 256, 0, stream>>>(dy, dln, d_ln1g, d_ln1b, RJ, 32);
  tokenmix_kernel<<<(Bn * 32) / 256, 256, 0, stream>>>(dln, dy, dx2, d_tw1, d_tb1, d_tw2, d_tb2, Bn, 32);
  ln_kernel<1><<<RJ / 4, 256, 0, stream>>>(dx2, dln, d_ln2g, d_ln2b, RJ, 32);
  small_gemm<1, 0><<<(RJ * 64) / 256, 256, 0, stream>>>(dln, d_cw1, d_cb1, nullptr, dh, RJ, 32, 64);
  small_gemm<0, 1><<<(RJ * 32) / 256, 256, 0, stream>>>(dh, d_cw2, d_cb2, dx2, dy, RJ, 64, 32);
  ln_kernel<1><<<RJ / 4, 256, 0, stream>>>(dy, dln, dec_lng, dec_lnb, RJ, 32);
  small_gemm<0, 0><<<(RJ * 2) / 256, 256, 0, stream>>>(dln, rec_w, rec_b, nullptr, o_rec, RJ, 32, 2);
}

// Round 4
// 2749.931 us; speedup vs baseline: 2.0630x; 1.1133x over previous
//
#include <hip/hip_runtime.h>
#include <math.h>

// ---------------- problem constants ----------------
constexpr int Bn = 1024, Jn = 17, Dn = 512, Mn = 34, Kcb = 2048, DTn = 512;
constexpr int RJ = Bn * Jn;                 // 17408 rows [B,J]
constexpr int RM = Bn * Mn;                 // 34816 rows [B,M]
constexpr size_t SZX = (size_t)RJ * Dn;     // 8,912,896 floats
constexpr size_t SZM = (size_t)RM * DTn;    // 17,825,792 floats

typedef __attribute__((ext_vector_type(8))) short bf16x8;
typedef __attribute__((ext_vector_type(4))) float f32x4;

__device__ __forceinline__ float gelu_f(float x) {
  return 0.5f * x * (1.0f + erff(x * 0.7071067811865475f));
}

__device__ __forceinline__ unsigned short bf16_rne(float x) {
  unsigned int u = __float_as_uint(x);
  u += 0x7fffu + ((u >> 16) & 1u);
  return (unsigned short)(u >> 16);
}
__device__ __forceinline__ float bf16_f(unsigned short h) {
  return __uint_as_float((unsigned int)h << 16);
}

// ---------------- embed ----------------
__global__ __launch_bounds__(256) void embed_kernel(
    const float* __restrict__ joints, const float* __restrict__ inv,
    const float* __restrict__ sw, const float* __restrict__ sb,
    float* __restrict__ out) {
  int tid = blockIdx.x * 256 + threadIdx.x;
  int row = tid >> 9, d = tid & 511;
  float j0 = joints[row * 3 + 0];
  float j1 = joints[row * 3 + 1];
  float j2 = joints[row * 3 + 2];
  float x = fmaf(j0, sw[d], fmaf(j1, sw[512 + d], sb[d]));
  float v = (j2 != 0.0f) ? 1.0f : 0.0f;
  out[tid] = x * v + inv[d] * (1.0f - v);
}

// ---------------- LayerNorm: wave per row ----------------
template <int NV>
__global__ __launch_bounds__(256) void ln_kernel(
    const float* __restrict__ src, float* __restrict__ dst,
    const float* __restrict__ g, const float* __restrict__ b,
    int rows, int D) {
  int wave = threadIdx.x >> 6;
  int lane = threadIdx.x & 63;
  int row = blockIdx.x * 4 + wave;
  if (row >= rows) return;
  const float* p = src + (size_t)row * D;
  float v[NV];
  float s = 0.0f;
#pragma unroll
  for (int i = 0; i < NV; i++) {
    int d = lane + 64 * i;
    v[i] = (d < D) ? p[d] : 0.0f;
    s += v[i];
  }
#pragma unroll
  for (int m = 32; m; m >>= 1) s += __shfl_xor(s, m);
  float mean = s / (float)D;
  float s2 = 0.0f;
#pragma unroll
  for (int i = 0; i < NV; i++) {
    int d = lane + 64 * i;
    float t = (d < D) ? (v[i] - mean) : 0.0f;
    s2 += t * t;
  }
#pragma unroll
  for (int m = 32; m; m >>= 1) s2 += __shfl_xor(s2, m);
  float rs = 1.0f / sqrtf(s2 / (float)D + 1e-5f);
  float* q = dst + (size_t)row * D;
#pragma unroll
  for (int i = 0; i < NV; i++) {
    int d = lane + 64 * i;
    if (d < D) q[d] = (v[i] - mean) * rs * g[d] + b[d];
  }
}

// ---------------- token mixing (17->64->17) fused residual ----------------
__global__ __launch_bounds__(256) void tokenmix_kernel(
    const float* __restrict__ ln, const float* __restrict__ xin,
    float* __restrict__ out, const float* __restrict__ tw1,
    const float* __restrict__ tb1, const float* __restrict__ tw2,
    const float* __restrict__ tb2, int B, int H) {
  __shared__ float sw1[17 * 64], sw2[64 * 17], sb1[64], sb2[17];
  for (int i = threadIdx.x; i < 17 * 64; i += 256) {
    sw1[i] = tw1[i];
    sw2[i] = tw2[i];
  }
  if (threadIdx.x < 64) sb1[threadIdx.x] = tb1[threadIdx.x];
  if (threadIdx.x < 17) sb2[threadIdx.x] = tb2[threadIdx.x];
  __syncthreads();
  int tid = blockIdx.x * 256 + threadIdx.x;
  if (tid >= B * H) return;
  int b = tid / H, d = tid % H;
  const float* pl = ln + (size_t)b * 17 * H + d;
  float t[17], acc[17];
#pragma unroll
  for (int j = 0; j < 17; j++) {
    t[j] = pl[j * H];
    acc[j] = 0.0f;
  }
  for (int k = 0; k < 64; k++) {
    float h = sb1[k];
#pragma unroll
    for (int j = 0; j < 17; j++) h = fmaf(t[j], sw1[j * 64 + k], h);
    h = gelu_f(h);
#pragma unroll
    for (int j = 0; j < 17; j++) acc[j] = fmaf(h, sw2[k * 17 + j], acc[j]);
  }
  const float* px = xin + (size_t)b * 17 * H + d;
  float* po = out + (size_t)b * 17 * H + d;
#pragma unroll
  for (int j = 0; j < 17; j++) po[j * H] = px[j * H] + acc[j] + sb2[j];
}

// ---------------- linear mix over joint/token axis ----------------
template <int JIN, int JOUT>
__global__ __launch_bounds__(256) void linmix_kernel(
    const float* __restrict__ in, float* __restrict__ out,
    const float* __restrict__ w, const float* __restrict__ bias,
    int B, int H) {
  __shared__ float sw[JIN * JOUT], sb[JOUT];
  for (int i = threadIdx.x; i < JIN * JOUT; i += 256) sw[i] = w[i];
  if (threadIdx.x < JOUT) sb[threadIdx.x] = bias[threadIdx.x];
  __syncthreads();
  int tid = blockIdx.x * 256 + threadIdx.x;
  if (tid >= B * H) return;
  int b = tid / H, d = tid % H;
  const float* pi = in + (size_t)b * JIN * H + d;
  float t[JIN];
#pragma unroll
  for (int j = 0; j < JIN; j++) t[j] = pi[(size_t)j * H];
  float* po = out + (size_t)b * JOUT * H + d;
#pragma unroll
  for (int m = 0; m < JOUT; m++) {
    float s = sb[m];
#pragma unroll
    for (int j = 0; j < JIN; j++) s = fmaf(t[j], sw[j * JOUT + m], s);
    po[(size_t)m * H] = s;
  }
}

// ---------------- big fp32 GEMM: 128x128 tile, 8x8/thread ----------------
template <int GELU_FLAG, int RES_FLAG>
__global__ __launch_bounds__(256) void gemm128(
    const float* __restrict__ A, const float* __restrict__ W,
    const float* __restrict__ bias, const float* __restrict__ R,
    float* __restrict__ C, int Mdim, int K, int N) {
  __shared__ float sA[16][132];
  __shared__ float sW[16][132];
  const int tid = threadIdx.x;
  const int tx = tid & 15, ty = tid >> 4;
  const int m0 = blockIdx.x * 128, n0 = blockIdx.y * 128;
  const int lr = tid >> 2;
  const int lc4 = (tid & 3) * 4;
  float acc[8][8] = {};
  for (int k0 = 0; k0 < K; k0 += 16) {
    float4 a0 = *(const float4*)(A + (size_t)(m0 + lr) * K + k0 + lc4);
    float4 a1 = *(const float4*)(A + (size_t)(m0 + lr + 64) * K + k0 + lc4);
    sA[lc4 + 0][lr] = a0.x; sA[lc4 + 1][lr] = a0.y;
    sA[lc4 + 2][lr] = a0.z; sA[lc4 + 3][lr] = a0.w;
    sA[lc4 + 0][lr + 64] = a1.x; sA[lc4 + 1][lr + 64] = a1.y;
    sA[lc4 + 2][lr + 64] = a1.z; sA[lc4 + 3][lr + 64] = a1.w;
    {
      const int wk = tid >> 5;
      const int wc = (tid & 31) * 4;
      float4 w0 = *(const float4*)(W + (size_t)(k0 + wk) * N + n0 + wc);
      float4 w1 = *(const float4*)(W + (size_t)(k0 + wk + 8) * N + n0 + wc);
      *(float4*)&sW[wk][wc] = w0;
      *(float4*)&sW[wk + 8][wc] = w1;
    }
    __syncthreads();
#pragma unroll
    for (int kk = 0; kk < 16; kk++) {
      float4 av0 = *(const float4*)&sA[kk][tx * 4];
      float4 av1 = *(const float4*)&sA[kk][64 + tx * 4];
      float4 wv0 = *(const float4*)&sW[kk][ty * 4];
      float4 wv1 = *(const float4*)&sW[kk][64 + ty * 4];
      float a[8] = {av0.x, av0.y, av0.z, av0.w, av1.x, av1.y, av1.z, av1.w};
      float w[8] = {wv0.x, wv0.y, wv0.z, wv0.w, wv1.x, wv1.y, wv1.z, wv1.w};
#pragma unroll
      for (int i = 0; i < 8; i++)
#pragma unroll
        for (int j = 0; j < 8; j++) acc[i][j] = fmaf(a[i], w[j], acc[i][j]);
    }
    __syncthreads();
  }
#pragma unroll
  for (int gi = 0; gi < 2; gi++)
#pragma unroll
    for (int u = 0; u < 4; u++) {
      int r = m0 + gi * 64 + tx * 4 + u;
      int ai = gi * 4 + u;
#pragma unroll
      for (int gj = 0; gj < 2; gj++) {
        int cb = n0 + gj * 64 + ty * 4;
        float4 bv = *(const float4*)(bias + cb);
        float4 o;
        o.x = acc[ai][gj * 4 + 0] + bv.x;
        o.y = acc[ai][gj * 4 + 1] + bv.y;
        o.z = acc[ai][gj * 4 + 2] + bv.z;
        o.w = acc[ai][gj * 4 + 3] + bv.w;
        if (GELU_FLAG) {
          o.x = gelu_f(o.x); o.y = gelu_f(o.y);
          o.z = gelu_f(o.z); o.w = gelu_f(o.w);
        }
        if (RES_FLAG) {
          float4 rv = *(const float4*)(R + (size_t)r * N + cb);
          o.x += rv.x; o.y += rv.y; o.z += rv.z; o.w += rv.w;
        }
        *(float4*)(C + (size_t)r * N + cb) = o;
      }
    }
}

// ---------------- fp32 -> bf16 hi/lo split ----------------
__global__ __launch_bounds__(256) void split_kernel(
    const float* __restrict__ src, unsigned short* __restrict__ hi,
    unsigned short* __restrict__ lo) {
  int t = blockIdx.x * 256 + threadIdx.x;  // each handles 4 floats
  float4 x = ((const float4*)src)[t];
  ushort4 h, l;
  h.x = bf16_rne(x.x); l.x = bf16_rne(x.x - bf16_f(h.x));
  h.y = bf16_rne(x.y); l.y = bf16_rne(x.y - bf16_f(h.y));
  h.z = bf16_rne(x.z); l.z = bf16_rne(x.z - bf16_f(h.z));
  h.w = bf16_rne(x.w); l.w = bf16_rne(x.w - bf16_f(h.w));
  ((ushort4*)hi)[t] = h;
  ((ushort4*)lo)[t] = l;
}

// ---------------- codebook L2 norms ----------------
__global__ __launch_bounds__(256) void cnorm_kernel(
    const float* __restrict__ CBm, float* __restrict__ cnorm) {
  int wave = threadIdx.x >> 6, lane = threadIdx.x & 63;
  int k = blockIdx.x * 4 + wave;
  const float* p = CBm + (size_t)k * 512;
  float s = 0.0f;
#pragma unroll
  for (int i = 0; i < 8; i++) {
    float v = p[lane + 64 * i];
    s = fmaf(v, v, s);
  }
#pragma unroll
  for (int m = 32; m; m >>= 1) s += __shfl_xor(s, m);
  if (lane == 0) cnorm[k] = s;
}

// ---------------- split-bf16 MFMA distance GEMM + fused argmin ----------------
// D[m][n] = feat[m]·cb[n] via (fh+fl)·(ch+cl) ~ fh·ch + fh·cl + fl·ch  (3 MFMA)
// Block: 128 rows x 128 entries; 4 waves, each 64x64 (4x4 of 16x16x32 tiles).
__global__ __launch_bounds__(256) void dist_mfma(
    const unsigned short* __restrict__ fh, const unsigned short* __restrict__ fl,
    const unsigned short* __restrict__ ch, const unsigned short* __restrict__ cl,
    const float* __restrict__ cnorm, float* __restrict__ pval,
    int* __restrict__ pidx) {
  __shared__ unsigned short sAh[128][40], sAl[128][40];
  __shared__ unsigned short sBh[128][40], sBl[128][40];
  __shared__ float rv2[128][2];
  __shared__ int ri2[128][2];
  const int tid = threadIdx.x;
  const int m0 = blockIdx.x * 128, n0 = blockIdx.y * 128;
  const int lane = tid & 63, wave = tid >> 6;
  const int wm = wave >> 1, wn = wave & 1;
  const int sr = tid & 127;        // staging row
  const int sk = (tid >> 7) * 16;  // staging k offset (0 or 16)
  const int fr = lane & 15, fq = (lane >> 4) * 8;
  f32x4 acc[4][4];
#pragma unroll
  for (int i = 0; i < 4; i++)
#pragma unroll
    for (int j = 0; j < 4; j++) {
      acc[i][j][0] = 0.0f; acc[i][j][1] = 0.0f;
      acc[i][j][2] = 0.0f; acc[i][j][3] = 0.0f;
    }
  for (int k0 = 0; k0 < 512; k0 += 32) {
    {
      const uint4* ga = (const uint4*)(fh + (size_t)(m0 + sr) * 512 + k0 + sk);
      const uint4* gb = (const uint4*)(fl + (size_t)(m0 + sr) * 512 + k0 + sk);
      const uint4* gc = (const uint4*)(ch + (size_t)(n0 + sr) * 512 + k0 + sk);
      const uint4* gd = (const uint4*)(cl + (size_t)(n0 + sr) * 512 + k0 + sk);
      uint4 a0 = ga[0], a1 = ga[1];
      uint4 b0 = gb[0], b1 = gb[1];
      uint4 c0 = gc[0], c1 = gc[1];
      uint4 d0 = gd[0], d1 = gd[1];
      *(uint4*)&sAh[sr][sk] = a0; *(uint4*)&sAh[sr][sk + 8] = a1;
      *(uint4*)&sAl[sr][sk] = b0; *(uint4*)&sAl[sr][sk + 8] = b1;
      *(uint4*)&sBh[sr][sk] = c0; *(uint4*)&sBh[sr][sk + 8] = c1;
      *(uint4*)&sBl[sr][sk] = d0; *(uint4*)&sBl[sr][sk + 8] = d1;
    }
    __syncthreads();
    bf16x8 ah[4], al[4], bh[4], bl[4];
#pragma unroll
    for (int t = 0; t < 4; t++) {
      ah[t] = *(const bf16x8*)&sAh[wm * 64 + t * 16 + fr][fq];
      al[t] = *(const bf16x8*)&sAl[wm * 64 + t * 16 + fr][fq];
      bh[t] = *(const bf16x8*)&sBh[wn * 64 + t * 16 + fr][fq];
      bl[t] = *(const bf16x8*)&sBl[wn * 64 + t * 16 + fr][fq];
    }
#pragma unroll
    for (int mt = 0; mt < 4; mt++)
#pragma unroll
      for (int nt = 0; nt < 4; nt++) {
        acc[mt][nt] = __builtin_amdgcn_mfma_f32_16x16x32_bf16(
            ah[mt], bh[nt], acc[mt][nt], 0, 0, 0);
        acc[mt][nt] = __builtin_amdgcn_mfma_f32_16x16x32_bf16(
            ah[mt], bl[nt], acc[mt][nt], 0, 0, 0);
        acc[mt][nt] = __builtin_amdgcn_mfma_f32_16x16x32_bf16(
            al[mt], bh[nt], acc[mt][nt], 0, 0, 0);
      }
    __syncthreads();
  }
  // argmin: C/D layout col=lane&15, row=(lane>>4)*4+reg
  const int qd = lane >> 4;
#pragma unroll
  for (int mt = 0; mt < 4; mt++)
#pragma unroll
    for (int reg = 0; reg < 4; reg++) {
      float bv = 3.0e38f;
      int bi = 0x7fffffff;
#pragma unroll
      for (int nt = 0; nt < 4; nt++) {
        int c = n0 + wn * 64 + nt * 16 + fr;
        float d = cnorm[c] - 2.0f * acc[mt][nt][reg];
        if (d < bv || (d == bv && c < bi)) { bv = d; bi = c; }
      }
#pragma unroll
      for (int m = 1; m <= 8; m <<= 1) {
        float ov = __shfl_xor(bv, m);
        int oi = __shfl_xor(bi, m);
        if (ov < bv || (ov == bv && oi < bi)) { bv = ov; bi = oi; }
      }
      if (fr == 0) {
        int rl = wm * 64 + mt * 16 + qd * 4 + reg;
        rv2[rl][wn] = bv;
        ri2[rl][wn] = bi;
      }
    }
  __syncthreads();
  if (tid < 128) {
    float bv = rv2[tid][0];
    int bi = ri2[tid][0];
    float v = rv2[tid][1];
    int i2 = ri2[tid][1];
    if (v < bv || (v == bv && i2 < bi)) { bv = v; bi = i2; }
    pval[(m0 + tid) * 16 + blockIdx.y] = bv;
    pidx[(m0 + tid) * 16 + blockIdx.y] = bi;
  }
}

// ---------------- argmin across the 16 N-block partials ----------------
__global__ __launch_bounds__(256) void argmin_reduce(
    const float* __restrict__ pval, const int* __restrict__ pidx,
    int* __restrict__ idxi, float* __restrict__ idxf, int rows) {
  int r = blockIdx.x * 256 + threadIdx.x;
  if (r >= rows) return;
  float bv = pval[r * 16];
  int bi = pidx[r * 16];
#pragma unroll
  for (int t = 1; t < 16; t++) {
    float v = pval[r * 16 + t];
    int i2 = pidx[r * 16 + t];
    if (v < bv || (v == bv && i2 < bi)) { bv = v; bi = i2; }
  }
  idxi[r] = bi;
  idxf[r] = (float)bi;
}

// ---------------- skew-oblivious count: per-block LDS histogram ----------------
__global__ __launch_bounds__(256) void count_kernel(
    const int* __restrict__ idxi, int* __restrict__ cnt) {
  __shared__ int h[2048];
  for (int i = threadIdx.x; i < 2048; i += 256) h[i] = 0;
  __syncthreads();
  int r = blockIdx.x * 256 + threadIdx.x;  // RM % 256 == 0
  atomicAdd(&h[idxi[r]], 1);
  __syncthreads();
  for (int i = threadIdx.x; i < 2048; i += 256) {
    int v = h[i];
    if (v) atomicAdd(&cnt[i], v);
  }
}

// one block: exclusive scan of 2048 counts; n = 0.9*sum(ema_cs) + 0.1*RM
__global__ __launch_bounds__(256) void scan_kernel(
    const int* __restrict__ cnt, int* __restrict__ base,
    int* __restrict__ cursor, const float* __restrict__ ema_cs,
    float* __restrict__ nbuf) {
  __shared__ int part[256];
  __shared__ float esum[256];
  int t = threadIdx.x;
  int local[8];
  int s = 0;
  float es = 0.0f;
#pragma unroll
  for (int i = 0; i < 8; i++) {
    local[i] = cnt[t * 8 + i];
    s += local[i];
    es += ema_cs[t * 8 + i];
  }
  part[t] = s;
  esum[t] = es;
  __syncthreads();
  for (int off = 1; off < 256; off <<= 1) {
    int v = (t >= off) ? part[t - off] : 0;
    __syncthreads();
    part[t] += v;
    __syncthreads();
  }
  int run = part[t] - s;
#pragma unroll
  for (int i = 0; i < 8; i++) {
    base[t * 8 + i] = run;
    cursor[t * 8 + i] = run;
    run += local[i];
  }
  for (int o = 128; o; o >>= 1) {
    if (t < o) esum[t] += esum[t + o];
    __syncthreads();
  }
  if (t == 0) nbuf[0] = 0.9f * esum[0] + 0.1f * (float)RM;
}

// ---------------- skew-oblivious scatter ----------------
__global__ __launch_bounds__(256) void scatter_kernel(
    const int* __restrict__ idxi, int* __restrict__ cursor,
    unsigned int* __restrict__ bucket) {
  __shared__ int h[2048];
  __shared__ int gb[2048];
  for (int i = threadIdx.x; i < 2048; i += 256) h[i] = 0;
  __syncthreads();
  int r = blockIdx.x * 256 + threadIdx.x;
  int k = idxi[r];
  int lrank = atomicAdd(&h[k], 1);
  __syncthreads();
  for (int i = threadIdx.x; i < 2048; i += 256) {
    int v = h[i];
    gb[i] = v ? atomicAdd(&cursor[i], v) : 0;
  }
  __syncthreads();
  bucket[gb[k] + lrank] = ((unsigned int)k << 17) | (unsigned int)r;
}

// ---------------- quant gather (ptf out) + loss partials ----------------
__global__ __launch_bounds__(256) void quant_out_kernel(
    const float* __restrict__ feat, const float* __restrict__ CBm,
    const int* __restrict__ idxi, float* __restrict__ ptf_out,
    float* __restrict__ lpart) {
  __shared__ float wred[4];
  int row = blockIdx.x * 2 + (threadIdx.x >> 7);
  int t = threadIdx.x & 127;
  int k = idxi[row];
  float4 f = ((const float4*)(feat + (size_t)row * 512))[t];
  float4 c = ((const float4*)(CBm + (size_t)k * 512))[t];
  float* po = ptf_out + (size_t)row * 512 + 4 * t;  // base misaligned -> scalar
  po[0] = c.x; po[1] = c.y; po[2] = c.z; po[3] = c.w;
  float dx = c.x - f.x, dy = c.y - f.y, dz = c.z - f.z, dwv = c.w - f.w;
  float ls = dx * dx + dy * dy + dz * dz + dwv * dwv;
#pragma unroll
  for (int m = 32; m; m >>= 1) ls += __shfl_xor(ls, m);
  if ((threadIdx.x & 63) == 0) wred[threadIdx.x >> 6] = ls;
  __syncthreads();
  if (threadIdx.x == 0)
    lpart[blockIdx.x] = wred[0] + wred[1] + wred[2] + wred[3];
}

__global__ __launch_bounds__(256) void loss_final_kernel(
    const float* __restrict__ lpart, float* __restrict__ loss_out) {
  __shared__ float red[256];
  float s = 0.0f;
  for (int i = threadIdx.x; i < RM / 2; i += 256) s += lpart[i];
  red[threadIdx.x] = s;
  __syncthreads();
  for (int o = 128; o; o >>= 1) {
    if (threadIdx.x < o) red[threadIdx.x] += red[threadIdx.x + o];
    __syncthreads();
  }
  if (threadIdx.x == 0)
    loss_out[0] = red[0] / (float)((size_t)RM * 512);
}

// ---------------- skew-oblivious dw: fixed 64-row chunks of bucket ----------------
__global__ __launch_bounds__(256) void dwsum_chunk_kernel(
    const float* __restrict__ feat, const unsigned int* __restrict__ bucket,
    float* __restrict__ dw) {
  __shared__ unsigned int sp[64];
  const int t = threadIdx.x;
  if (t < 64) sp[t] = bucket[blockIdx.x * 64 + t];
  __syncthreads();
  float ax = 0.0f, ay = 0.0f;
  int curk = (int)(sp[0] >> 17);
  float2 fcur = *(const float2*)(feat + (size_t)(sp[0] & 0x1FFFF) * 512 + 2 * t);
  for (int i = 0; i < 64; i++) {
    float2 fnext = make_float2(0.0f, 0.0f);
    if (i + 1 < 64)
      fnext = *(const float2*)(feat + (size_t)(sp[i + 1] & 0x1FFFF) * 512 + 2 * t);
    int k = (int)(sp[i] >> 17);
    if (k != curk) {
      atomicAdd(&dw[(size_t)curk * 512 + 2 * t], ax);
      atomicAdd(&dw[(size_t)curk * 512 + 2 * t + 1], ay);
      ax = 0.0f; ay = 0.0f; curk = k;
    }
    ax += fcur.x;
    ay += fcur.y;
    fcur = fnext;
  }
  atomicAdd(&dw[(size_t)curk * 512 + 2 * t], ax);
  atomicAdd(&dw[(size_t)curk * 512 + 2 * t + 1], ay);
}

// ---------------- codebook_new finalize ----------------
__global__ __launch_bounds__(256) void cbnew_kernel(
    const float* __restrict__ ema_w, const float* __restrict__ dw,
    const float* __restrict__ ema_cs, const int* __restrict__ cnt,
    const float* __restrict__ nbuf, float* __restrict__ outp) {
  int tid = blockIdx.x * 256 + threadIdx.x;  // < 2048*512
  int k = tid >> 9;
  float n = nbuf[0];
  float cs = ema_cs[k] * 0.9f + 0.1f * (float)cnt[k];
  cs = (cs + 1e-5f) / (n + 0.02048f) * n;
  outp[tid] = (ema_w[tid] * 0.9f + 0.1f * dw[tid]) / cs;
}

// ---------------- small-N GEMM ----------------
template <int GELU_FLAG, int RES_FLAG>
__global__ __launch_bounds__(256) void small_gemm(
    const float* __restrict__ A, const float* __restrict__ W,
    const float* __restrict__ bias, const float* __restrict__ R,
    float* __restrict__ out, int Mrows, int K, int N) {
  int tid = blockIdx.x * 256 + threadIdx.x;
  int r = tid / N, c = tid % N;
  if (r >= Mrows) return;
  float s = bias[c];
  const float4* pa = (const float4*)(A + (size_t)r * K);
  const float* pw = W + c;
  int k4 = K >> 2;
  for (int kk = 0; kk < k4; kk++) {
    float4 a = pa[kk];
    s = fmaf(a.x, pw[(4 * kk + 0) * N], s);
    s = fmaf(a.y, pw[(4 * kk + 1) * N], s);
    s = fmaf(a.z, pw[(4 * kk + 2) * N], s);
    s = fmaf(a.w, pw[(4 * kk + 3) * N], s);
  }
  if (GELU_FLAG) s = gelu_f(s);
  if (RES_FLAG) s += R[(size_t)r * N + c];
  out[(size_t)r * N + c] = s;
}

// ================================================================
extern "C" void kernel_launch(void* const* d_in, const int* in_sizes, int n_in,
                              void* d_out, int out_size, void* d_ws, size_t ws_size,
                              hipStream_t stream) {
  const float* joints   = (const float*)d_in[0];
  const float* inv_tok  = (const float*)d_in[3];
  const float* start_w  = (const float*)d_in[4];
  const float* start_b  = (const float*)d_in[5];
  const float* e_ln1g = (const float*)d_in[6];
  const float* e_ln1b = (const float*)d_in[7];
  const float* e_tw1  = (const float*)d_in[8];
  const float* e_tb1  = (const float*)d_in[9];
  const float* e_tw2  = (const float*)d_in[10];
  const float* e_tb2  = (const float*)d_in[11];
  const float* e_ln2g = (const float*)d_in[12];
  const float* e_ln2b = (const float*)d_in[13];
  const float* e_cw1  = (const float*)d_in[14];
  const float* e_cb1  = (const float*)d_in[15];
  const float* e_cw2  = (const float*)d_in[16];
  const float* e_cb2  = (const float*)d_in[17];
  const float* d_ln1g = (const float*)d_in[18];
  const float* d_ln1b = (const float*)d_in[19];
  const float* d_tw1  = (const float*)d_in[20];
  const float* d_tb1  = (const float*)d_in[21];
  const float* d_tw2  = (const float*)d_in[22];
  const float* d_tb2  = (const float*)d_in[23];
  const float* d_ln2g = (const float*)d_in[24];
  const float* d_ln2b = (const float*)d_in[25];
  const float* d_cw1  = (const float*)d_in[26];
  const float* d_cb1  = (const float*)d_in[27];
  const float* d_cw2  = (const float*)d_in[28];
  const float* d_cb2  = (const float*)d_in[29];
  const float* enc_lng = (const float*)d_in[30];
  const float* enc_lnb = (const float*)d_in[31];
  const float* tok_w   = (const float*)d_in[32];
  const float* tok_b   = (const float*)d_in[33];
  const float* feat_w  = (const float*)d_in[34];
  const float* feat_b  = (const float*)d_in[35];
  const float* codebook = (const float*)d_in[36];
  const float* ema_cs   = (const float*)d_in[37];
  const float* ema_w    = (const float*)d_in[38];
  const float* dtok_w   = (const float*)d_in[39];
  const float* dtok_b   = (const float*)d_in[40];
  const float* dstart_w = (const float*)d_in[41];
  const float* dstart_b = (const float*)d_in[42];
  const float* dec_lng  = (const float*)d_in[43];
  const float* dec_lnb  = (const float*)d_in[44];
  const float* rec_w    = (const float*)d_in[45];
  const float* rec_b    = (const float*)d_in[46];

  // -------- workspace layout (floats) --------
  float* ws = (float*)d_ws;
  float* Ab = ws;                 // [RJ,512]; later feat spans Ab..Ab+SZM
  float* Bb = ws + SZX;
  float* Cc = ws + 2 * SZX;
  float* Mm = ws + 3 * SZX;       // [RM,512]
  float* feat = Ab;               // [RM,512] (Ab+Bb regions)
  float* tail = ws + 3 * SZX + SZM;
  float* cnorm = tail;                          // 2048
  float* pval = cnorm + 2048;                   // RM*16
  int* pidx = (int*)(pval + (size_t)RM * 16);   // RM*16
  int* idxi = pidx + (size_t)RM * 16;           // RM
  int* cnt = idxi + RM;                         // 2048
  int* basebuf = cnt + 2048;                    // 2048
  int* cursor = basebuf + 2048;                 // 2048
  unsigned int* bucket = (unsigned int*)(cursor + 2048);  // RM
  float* nbuf = (float*)(bucket + RM);          // 1
  float* lpart = nbuf + 1;                      // RM/2
  float* dw = lpart + RM / 2;                   // 2048*512
  // bf16 split buffers reuse Cc/Mm (dead between feat-gemm and decoder):
  unsigned short* fh = (unsigned short*)Cc;              // RM*512 ushort == SZX floats
  unsigned short* flo = (unsigned short*)Mm;             // RM*512 ushort
  unsigned short* chh = (unsigned short*)(Mm + SZX);     // 2048*512 ushort
  unsigned short* cll = (unsigned short*)(Mm + SZX + 524288);
  // decoder small buffers carved from Mm region (after VQ done)
  float* dy  = Mm;
  float* dx2 = Mm + (size_t)RJ * 32;
  float* dh  = Mm + (size_t)2 * RJ * 32;
  float* dln = Mm + (size_t)2 * RJ * 32 + (size_t)RJ * 64;

  // -------- outputs --------
  float* outp = (float*)d_out;
  float* o_rec = outp;                       // [RJ,2]
  float* o_idx = outp + (size_t)RJ * 2;      // [RM]
  float* o_loss = o_idx + RM;                // [1]
  float* o_ptf = o_loss + 1;                 // [RM,512]
  float* o_cb = o_ptf + SZM;                 // [2048,512]

  hipMemsetAsync(cnt, 0, 2048 * sizeof(int), stream);
  hipMemsetAsync(dw, 0, (size_t)2048 * 512 * sizeof(float), stream);

  // -------- encoder --------
  embed_kernel<<<(RJ * 512) / 256, 256, 0, stream>>>(joints, inv_tok, start_w, start_b, Ab);
  for (int i = 0; i < 4; i++) {
    ln_kernel<8><<<RJ / 4, 256, 0, stream>>>(Ab, Cc, e_ln1g + i * 512, e_ln1b + i * 512, RJ, 512);
    tokenmix_kernel<<<(Bn * 512) / 256, 256, 0, stream>>>(
        Cc, Ab, Bb, e_tw1 + i * 17 * 64, e_tb1 + i * 64, e_tw2 + i * 64 * 17, e_tb2 + i * 17, Bn, 512);
    ln_kernel<8><<<RJ / 4, 256, 0, stream>>>(Bb, Cc, e_ln2g + i * 512, e_ln2b + i * 512, RJ, 512);
    gemm128<1, 0><<<dim3(RJ / 128, 4), 256, 0, stream>>>(
        Cc, e_cw1 + (size_t)i * 512 * 512, e_cb1 + i * 512, nullptr, Mm, RJ, 512, 512);
    gemm128<0, 1><<<dim3(RJ / 128, 4), 256, 0, stream>>>(
        Mm, e_cw2 + (size_t)i * 512 * 512, e_cb2 + i * 512, Bb, Ab, RJ, 512, 512);
  }
  ln_kernel<8><<<RJ / 4, 256, 0, stream>>>(Ab, Cc, enc_lng, enc_lnb, RJ, 512);
  linmix_kernel<17, 34><<<(Bn * 512) / 256, 256, 0, stream>>>(Cc, Mm, tok_w, tok_b, Bn, 512);
  gemm128<0, 0><<<dim3(RM / 128, 4), 256, 0, stream>>>(Mm, feat_w, feat_b, nullptr, feat, RM, 512, 512);

  // -------- VQ: split + distances + argmin --------
  split_kernel<<<(int)(SZM / 4 / 256), 256, 0, stream>>>(feat, fh, flo);
  split_kernel<<<(2048 * 512 / 4) / 256, 256, 0, stream>>>(codebook, chh, cll);
  cnorm_kernel<<<2048 / 4, 256, 0, stream>>>(codebook, cnorm);
  dist_mfma<<<dim3(RM / 128, 2048 / 128), 256, 0, stream>>>(fh, flo, chh, cll, cnorm, pval, pidx);
  argmin_reduce<<<RM / 256, 256, 0, stream>>>(pval, pidx, idxi, o_idx, RM);

  // -------- skew-oblivious bucketed EMA update --------
  count_kernel<<<RM / 256, 256, 0, stream>>>(idxi, cnt);
  scan_kernel<<<1, 256, 0, stream>>>(cnt, basebuf, cursor, ema_cs, nbuf);
  scatter_kernel<<<RM / 256, 256, 0, stream>>>(idxi, cursor, bucket);
  quant_out_kernel<<<RM / 2, 256, 0, stream>>>(feat, codebook, idxi, o_ptf, lpart);
  loss_final_kernel<<<1, 256, 0, stream>>>(lpart, o_loss);
  dwsum_chunk_kernel<<<RM / 64, 256, 0, stream>>>(feat, bucket, dw);
  cbnew_kernel<<<(2048 * 512) / 256, 256, 0, stream>>>(ema_w, dw, ema_cs, cnt, nbuf, o_cb);

  // -------- decoder --------
  linmix_kernel<34, 17><<<(Bn * 512) / 256, 256, 0, stream>>>(o_ptf, Cc, dtok_w, dtok_b, Bn, 512);
  small_gemm<0, 0><<<(RJ * 32) / 256, 256, 0, stream>>>(Cc, dstart_w, dstart_b, nullptr, dy, RJ, 512, 32);
  ln_kernel<1><<<RJ / 4, 256, 0, stream>>>(dy, dln, d_ln1g, d_ln1b, RJ, 32);
  tokenmix_kernel<<<(Bn * 32) / 256, 256, 0, stream>>>(dln, dy, dx2, d_tw1, d_tb1, d_tw2, d_tb2, Bn, 32);
  ln_kernel<1><<<RJ / 4, 256, 0, stream>>>(dx2, dln, d_ln2g, d_ln2b, RJ, 32);
  small_gemm<1, 0><<<(RJ * 64) / 256, 256, 0, stream>>>(dln, d_cw1, d_cb1, nullptr, dh, RJ, 32, 64);
  small_gemm<0, 1><<<(RJ * 32) / 256, 256, 0, stream>>>(dh, d_cw2, d_cb2, dx2, dy, RJ, 64, 32);
  ln_kernel<1><<<RJ / 4, 256, 0, stream>>>(dy, dln, dec_lng, dec_lnb, RJ, 32);
  small_gemm<0, 0><<<(RJ * 2) / 256, 256, 0, stream>>>(dln, rec_w, rec_b, nullptr, o_rec, RJ, 32, 2);
}

// Round 5
// 2003.605 us; speedup vs baseline: 2.8314x; 1.3725x over previous
//
#include <hip/hip_runtime.h>
#include <math.h>

// ---------------- problem constants ----------------
constexpr int Bn = 1024, Jn = 17, Mn = 34;
constexpr int RJ = Bn * Jn;                 // 17408
constexpr int RM = Bn * Mn;                 // 34816
constexpr size_t SZX = (size_t)RJ * 512;    // 8,912,896 floats
constexpr size_t SZM = (size_t)RM * 512;    // 17,825,792 floats

typedef __attribute__((ext_vector_type(8))) short bf16x8;
typedef __attribute__((ext_vector_type(4))) float f32x4;
typedef unsigned long long u64;
typedef unsigned short u16;
typedef unsigned int u32;

__device__ __forceinline__ float gelu_f(float x) {
  return 0.5f * x * (1.0f + erff(x * 0.7071067811865475f));
}
__device__ __forceinline__ u16 bf16_rne(float x) {
  u32 u = __float_as_uint(x);
  u += 0x7fffu + ((u >> 16) & 1u);
  return (u16)(u >> 16);
}
__device__ __forceinline__ float bf16_f(u16 h) {
  return __uint_as_float((u32)h << 16);
}

// conflict-free LDS fragment load: 2x ds_read_b64, stride 9 uint2 (72B) per row
__device__ __forceinline__ bf16x8 frag_ld(const uint2 (&s)[128][9], int row, int c2) {
  uint2 a = s[row][c2], b = s[row][c2 + 1];
  union { u32 u[4]; bf16x8 v; } t;
  t.u[0] = a.x; t.u[1] = a.y; t.u[2] = b.x; t.u[3] = b.y;
  return t.v;
}

// ---------------- embed ----------------
__global__ __launch_bounds__(256) void embed_kernel(
    const float* __restrict__ joints, const float* __restrict__ inv,
    const float* __restrict__ sw, const float* __restrict__ sb,
    float* __restrict__ out) {
  int tid = blockIdx.x * 256 + threadIdx.x;
  int row = tid >> 9, d = tid & 511;
  float j0 = joints[row * 3 + 0];
  float j1 = joints[row * 3 + 1];
  float j2 = joints[row * 3 + 2];
  float x = fmaf(j0, sw[d], fmaf(j1, sw[512 + d], sb[d]));
  float v = (j2 != 0.0f) ? 1.0f : 0.0f;
  out[tid] = x * v + inv[d] * (1.0f - v);
}

// ---------------- LayerNorm fp32 out ----------------
template <int NV>
__global__ __launch_bounds__(256) void ln_kernel(
    const float* __restrict__ src, float* __restrict__ dst,
    const float* __restrict__ g, const float* __restrict__ b,
    int rows, int D) {
  int wave = threadIdx.x >> 6, lane = threadIdx.x & 63;
  int row = blockIdx.x * 4 + wave;
  if (row >= rows) return;
  const float* p = src + (size_t)row * D;
  float v[NV];
  float s = 0.0f;
#pragma unroll
  for (int i = 0; i < NV; i++) {
    int d = lane + 64 * i;
    v[i] = (d < D) ? p[d] : 0.0f;
    s += v[i];
  }
#pragma unroll
  for (int m = 32; m; m >>= 1) s += __shfl_xor(s, m);
  float mean = s / (float)D;
  float s2 = 0.0f;
#pragma unroll
  for (int i = 0; i < NV; i++) {
    int d = lane + 64 * i;
    float t = (d < D) ? (v[i] - mean) : 0.0f;
    s2 += t * t;
  }
#pragma unroll
  for (int m = 32; m; m >>= 1) s2 += __shfl_xor(s2, m);
  float rs = 1.0f / sqrtf(s2 / (float)D + 1e-5f);
  float* q = dst + (size_t)row * D;
#pragma unroll
  for (int i = 0; i < NV; i++) {
    int d = lane + 64 * i;
    if (d < D) q[d] = (v[i] - mean) * rs * g[d] + b[d];
  }
}

// ---------------- LayerNorm bf16 hi/lo out (D=512) ----------------
__global__ __launch_bounds__(256) void ln_bf16_kernel(
    const float* __restrict__ src, u16* __restrict__ oh, u16* __restrict__ ol,
    const float* __restrict__ g, const float* __restrict__ b, int rows) {
  int wave = threadIdx.x >> 6, lane = threadIdx.x & 63;
  int row = blockIdx.x * 4 + wave;
  if (row >= rows) return;
  const float* p = src + (size_t)row * 512;
  float v[8];
  float s = 0.0f;
#pragma unroll
  for (int i = 0; i < 8; i++) { v[i] = p[lane + 64 * i]; s += v[i]; }
#pragma unroll
  for (int m = 32; m; m >>= 1) s += __shfl_xor(s, m);
  float mean = s * (1.0f / 512.0f);
  float s2 = 0.0f;
#pragma unroll
  for (int i = 0; i < 8; i++) { float t = v[i] - mean; s2 += t * t; }
#pragma unroll
  for (int m = 32; m; m >>= 1) s2 += __shfl_xor(s2, m);
  float rs = 1.0f / sqrtf(s2 * (1.0f / 512.0f) + 1e-5f);
#pragma unroll
  for (int i = 0; i < 8; i++) {
    int d = lane + 64 * i;
    float o = (v[i] - mean) * rs * g[d] + b[d];
    u16 h = bf16_rne(o);
    oh[(size_t)row * 512 + d] = h;
    ol[(size_t)row * 512 + d] = bf16_rne(o - bf16_f(h));
  }
}

// ---------------- token mixing (17->64->17) fused residual ----------------
__global__ __launch_bounds__(256) void tokenmix_kernel(
    const float* __restrict__ ln, const float* __restrict__ xin,
    float* __restrict__ out, const float* __restrict__ tw1,
    const float* __restrict__ tb1, const float* __restrict__ tw2,
    const float* __restrict__ tb2, int B, int H) {
  __shared__ float sw1[17 * 64], sw2[64 * 17], sb1[64], sb2[17];
  for (int i = threadIdx.x; i < 17 * 64; i += 256) {
    sw1[i] = tw1[i];
    sw2[i] = tw2[i];
  }
  if (threadIdx.x < 64) sb1[threadIdx.x] = tb1[threadIdx.x];
  if (threadIdx.x < 17) sb2[threadIdx.x] = tb2[threadIdx.x];
  __syncthreads();
  int tid = blockIdx.x * 256 + threadIdx.x;
  if (tid >= B * H) return;
  int b = tid / H, d = tid % H;
  const float* pl = ln + (size_t)b * 17 * H + d;
  float t[17], acc[17];
#pragma unroll
  for (int j = 0; j < 17; j++) { t[j] = pl[j * H]; acc[j] = 0.0f; }
  for (int k = 0; k < 64; k++) {
    float h = sb1[k];
#pragma unroll
    for (int j = 0; j < 17; j++) h = fmaf(t[j], sw1[j * 64 + k], h);
    h = gelu_f(h);
#pragma unroll
    for (int j = 0; j < 17; j++) acc[j] = fmaf(h, sw2[k * 17 + j], acc[j]);
  }
  const float* px = xin + (size_t)b * 17 * H + d;
  float* po = out + (size_t)b * 17 * H + d;
#pragma unroll
  for (int j = 0; j < 17; j++) po[j * H] = px[j * H] + acc[j] + sb2[j];
}

// ---------------- linear mix over joint/token axis, fp32 out ----------------
template <int JIN, int JOUT>
__global__ __launch_bounds__(256) void linmix_kernel(
    const float* __restrict__ in, float* __restrict__ out,
    const float* __restrict__ w, const float* __restrict__ bias,
    int B, int H) {
  __shared__ float sw[JIN * JOUT], sb[JOUT];
  for (int i = threadIdx.x; i < JIN * JOUT; i += 256) sw[i] = w[i];
  if (threadIdx.x < JOUT) sb[threadIdx.x] = bias[threadIdx.x];
  __syncthreads();
  int tid = blockIdx.x * 256 + threadIdx.x;
  if (tid >= B * H) return;
  int b = tid / H, d = tid % H;
  const float* pi = in + (size_t)b * JIN * H + d;
  float t[JIN];
#pragma unroll
  for (int j = 0; j < JIN; j++) t[j] = pi[(size_t)j * H];
  float* po = out + (size_t)b * JOUT * H + d;
#pragma unroll
  for (int m = 0; m < JOUT; m++) {
    float s = sb[m];
#pragma unroll
    for (int j = 0; j < JIN; j++) s = fmaf(t[j], sw[j * JOUT + m], s);
    po[(size_t)m * H] = s;
  }
}

// ---------------- linear mix, bf16 hi/lo out (17 -> 34, H=512) ----------------
__global__ __launch_bounds__(256) void linmix_bf16_kernel(
    const float* __restrict__ in, u16* __restrict__ oh, u16* __restrict__ ol,
    const float* __restrict__ w, const float* __restrict__ bias) {
  __shared__ float sw[17 * 34], sb[34];
  for (int i = threadIdx.x; i < 17 * 34; i += 256) sw[i] = w[i];
  if (threadIdx.x < 34) sb[threadIdx.x] = bias[threadIdx.x];
  __syncthreads();
  int tid = blockIdx.x * 256 + threadIdx.x;  // < Bn*512
  int b = tid >> 9, d = tid & 511;
  const float* pi = in + (size_t)b * 17 * 512 + d;
  float t[17];
#pragma unroll
  for (int j = 0; j < 17; j++) t[j] = pi[(size_t)j * 512];
#pragma unroll
  for (int m = 0; m < 34; m++) {
    float s = sb[m];
#pragma unroll
    for (int j = 0; j < 17; j++) s = fmaf(t[j], sw[j * 34 + m], s);
    size_t o = ((size_t)b * 34 + m) * 512 + d;
    u16 h = bf16_rne(s);
    oh[o] = h;
    ol[o] = bf16_rne(s - bf16_f(h));
  }
}

// ---------------- weight transpose + split: W[512,512] -> WT hi/lo [512,512] ----------------
__global__ __launch_bounds__(256) void prep_wT(
    const float* __restrict__ W, u16* __restrict__ Th, u16* __restrict__ Tl) {
  int tid = blockIdx.x * 256 + threadIdx.x;  // < 512*512
  int k = tid >> 9, n = tid & 511;
  float v = W[tid];
  u16 h = bf16_rne(v);
  Th[(size_t)n * 512 + k] = h;
  Tl[(size_t)n * 512 + k] = bf16_rne(v - bf16_f(h));
}

// ---------------- fp32 -> bf16 hi/lo split (codebook, already [N,K]) ----------------
__global__ __launch_bounds__(256) void split_kernel(
    const float* __restrict__ src, u16* __restrict__ hi, u16* __restrict__ lo) {
  int t = blockIdx.x * 256 + threadIdx.x;
  float4 x = ((const float4*)src)[t];
  ushort4 h, l;
  h.x = bf16_rne(x.x); l.x = bf16_rne(x.x - bf16_f(h.x));
  h.y = bf16_rne(x.y); l.y = bf16_rne(x.y - bf16_f(h.y));
  h.z = bf16_rne(x.z); l.z = bf16_rne(x.z - bf16_f(h.z));
  h.w = bf16_rne(x.w); l.w = bf16_rne(x.w - bf16_f(h.w));
  ((ushort4*)hi)[t] = h;
  ((ushort4*)lo)[t] = l;
}

// ---------------- codebook L2 norms ----------------
__global__ __launch_bounds__(256) void cnorm_kernel(
    const float* __restrict__ CBm, float* __restrict__ cnorm) {
  int wave = threadIdx.x >> 6, lane = threadIdx.x & 63;
  int k = blockIdx.x * 4 + wave;
  const float* p = CBm + (size_t)k * 512;
  float s = 0.0f;
#pragma unroll
  for (int i = 0; i < 8; i++) {
    float v = p[lane + 64 * i];
    s = fmaf(v, v, s);
  }
#pragma unroll
  for (int m = 32; m; m >>= 1) s += __shfl_xor(s, m);
  if (lane == 0) cnorm[k] = s;
}

// ---------------- split-bf16 MFMA GEMM: C = act(A@W^T + bias)(+R), K=512 ----------------
// A hi/lo [M,512] bf16; B hi/lo [N,512] bf16 (pre-transposed). 3-term split.
// Block 128x128, 4 waves, wave=64x64 of 4x4 16x16x32 tiles. Conflict-free stride-36 LDS.
template <int GELU_FLAG, int RES_FLAG, int HILO_OUT>
__global__ __launch_bounds__(256) void mgemm(
    const u16* __restrict__ Ah, const u16* __restrict__ Al,
    const u16* __restrict__ Bh, const u16* __restrict__ Bl,
    const float* __restrict__ bias, const float* __restrict__ R,
    float* __restrict__ C, u16* __restrict__ Oh, u16* __restrict__ Ol, int N) {
  __shared__ uint2 sAh[128][9], sAl[128][9], sBh[128][9], sBl[128][9];
  const int tid = threadIdx.x;
  const int m0 = blockIdx.x * 128, n0 = blockIdx.y * 128;
  const int lane = tid & 63, wave = tid >> 6, wm = wave >> 1, wn = wave & 1;
  const int sr = tid & 127, skb = (tid >> 7) * 4, sks = (tid >> 7) * 16;
  const int fr = lane & 15, c2 = (lane >> 4) * 2, qd = lane >> 4;
  f32x4 acc[4][4];
#pragma unroll
  for (int i = 0; i < 4; i++)
#pragma unroll
    for (int j = 0; j < 4; j++) {
      acc[i][j][0] = 0.0f; acc[i][j][1] = 0.0f;
      acc[i][j][2] = 0.0f; acc[i][j][3] = 0.0f;
    }
  for (int k0 = 0; k0 < 512; k0 += 32) {
    {
      size_t aoff = (size_t)(m0 + sr) * 512 + k0 + sks;
      size_t boff = (size_t)(n0 + sr) * 512 + k0 + sks;
      uint4 a0 = *(const uint4*)(Ah + aoff), a1 = *(const uint4*)(Ah + aoff + 8);
      uint4 b0 = *(const uint4*)(Al + aoff), b1 = *(const uint4*)(Al + aoff + 8);
      uint4 c0 = *(const uint4*)(Bh + boff), c1 = *(const uint4*)(Bh + boff + 8);
      uint4 d0 = *(const uint4*)(Bl + boff), d1 = *(const uint4*)(Bl + boff + 8);
      sAh[sr][skb + 0] = make_uint2(a0.x, a0.y); sAh[sr][skb + 1] = make_uint2(a0.z, a0.w);
      sAh[sr][skb + 2] = make_uint2(a1.x, a1.y); sAh[sr][skb + 3] = make_uint2(a1.z, a1.w);
      sAl[sr][skb + 0] = make_uint2(b0.x, b0.y); sAl[sr][skb + 1] = make_uint2(b0.z, b0.w);
      sAl[sr][skb + 2] = make_uint2(b1.x, b1.y); sAl[sr][skb + 3] = make_uint2(b1.z, b1.w);
      sBh[sr][skb + 0] = make_uint2(c0.x, c0.y); sBh[sr][skb + 1] = make_uint2(c0.z, c0.w);
      sBh[sr][skb + 2] = make_uint2(c1.x, c1.y); sBh[sr][skb + 3] = make_uint2(c1.z, c1.w);
      sBl[sr][skb + 0] = make_uint2(d0.x, d0.y); sBl[sr][skb + 1] = make_uint2(d0.z, d0.w);
      sBl[sr][skb + 2] = make_uint2(d1.x, d1.y); sBl[sr][skb + 3] = make_uint2(d1.z, d1.w);
    }
    __syncthreads();
    bf16x8 ah[4], al4[4], bh4[4], bl4[4];
#pragma unroll
    for (int t4 = 0; t4 < 4; t4++) {
      ah[t4] = frag_ld(sAh, wm * 64 + t4 * 16 + fr, c2);
      al4[t4] = frag_ld(sAl, wm * 64 + t4 * 16 + fr, c2);
      bh4[t4] = frag_ld(sBh, wn * 64 + t4 * 16 + fr, c2);
      bl4[t4] = frag_ld(sBl, wn * 64 + t4 * 16 + fr, c2);
    }
#pragma unroll
    for (int mt = 0; mt < 4; mt++)
#pragma unroll
      for (int nt = 0; nt < 4; nt++) {
        acc[mt][nt] = __builtin_amdgcn_mfma_f32_16x16x32_bf16(ah[mt], bh4[nt], acc[mt][nt], 0, 0, 0);
        acc[mt][nt] = __builtin_amdgcn_mfma_f32_16x16x32_bf16(ah[mt], bl4[nt], acc[mt][nt], 0, 0, 0);
        acc[mt][nt] = __builtin_amdgcn_mfma_f32_16x16x32_bf16(al4[mt], bh4[nt], acc[mt][nt], 0, 0, 0);
      }
    __syncthreads();
  }
  // epilogue: C/D layout col=lane&15, row=(lane>>4)*4+reg
#pragma unroll
  for (int mt = 0; mt < 4; mt++)
#pragma unroll
    for (int reg = 0; reg < 4; reg++) {
      int row = m0 + wm * 64 + mt * 16 + qd * 4 + reg;
#pragma unroll
      for (int nt = 0; nt < 4; nt++) {
        int col = n0 + wn * 64 + nt * 16 + fr;
        float v = acc[mt][nt][reg] + bias[col];
        if (GELU_FLAG) v = gelu_f(v);
        if (RES_FLAG) v += R[(size_t)row * N + col];
        if (HILO_OUT) {
          u16 h = bf16_rne(v);
          Oh[(size_t)row * N + col] = h;
          Ol[(size_t)row * N + col] = bf16_rne(v - bf16_f(h));
        } else {
          C[(size_t)row * N + col] = v;
        }
      }
    }
}

// ---------------- distance GEMM (split-bf16 MFMA) + packed-u64 argmin ----------------
__global__ __launch_bounds__(256) void dist_mfma(
    const u16* __restrict__ Ah, const u16* __restrict__ Al,
    const u16* __restrict__ Bh, const u16* __restrict__ Bl,
    const float* __restrict__ cnorm, u64* __restrict__ packed) {
  __shared__ uint2 sAh[128][9], sAl[128][9], sBh[128][9], sBl[128][9];
  const int tid = threadIdx.x;
  const int m0 = blockIdx.x * 128, n0 = blockIdx.y * 128;
  const int lane = tid & 63, wave = tid >> 6, wm = wave >> 1, wn = wave & 1;
  const int sr = tid & 127, skb = (tid >> 7) * 4, sks = (tid >> 7) * 16;
  const int fr = lane & 15, c2 = (lane >> 4) * 2, qd = lane >> 4;
  f32x4 acc[4][4];
#pragma unroll
  for (int i = 0; i < 4; i++)
#pragma unroll
    for (int j = 0; j < 4; j++) {
      acc[i][j][0] = 0.0f; acc[i][j][1] = 0.0f;
      acc[i][j][2] = 0.0f; acc[i][j][3] = 0.0f;
    }
  for (int k0 = 0; k0 < 512; k0 += 32) {
    {
      size_t aoff = (size_t)(m0 + sr) * 512 + k0 + sks;
      size_t boff = (size_t)(n0 + sr) * 512 + k0 + sks;
      uint4 a0 = *(const uint4*)(Ah + aoff), a1 = *(const uint4*)(Ah + aoff + 8);
      uint4 b0 = *(const uint4*)(Al + aoff), b1 = *(const uint4*)(Al + aoff + 8);
      uint4 c0 = *(const uint4*)(Bh + boff), c1 = *(const uint4*)(Bh + boff + 8);
      uint4 d0 = *(const uint4*)(Bl + boff), d1 = *(const uint4*)(Bl + boff + 8);
      sAh[sr][skb + 0] = make_uint2(a0.x, a0.y); sAh[sr][skb + 1] = make_uint2(a0.z, a0.w);
      sAh[sr][skb + 2] = make_uint2(a1.x, a1.y); sAh[sr][skb + 3] = make_uint2(a1.z, a1.w);
      sAl[sr][skb + 0] = make_uint2(b0.x, b0.y); sAl[sr][skb + 1] = make_uint2(b0.z, b0.w);
      sAl[sr][skb + 2] = make_uint2(b1.x, b1.y); sAl[sr][skb + 3] = make_uint2(b1.z, b1.w);
      sBh[sr][skb + 0] = make_uint2(c0.x, c0.y); sBh[sr][skb + 1] = make_uint2(c0.z, c0.w);
      sBh[sr][skb + 2] = make_uint2(c1.x, c1.y); sBh[sr][skb + 3] = make_uint2(c1.z, c1.w);
      sBl[sr][skb + 0] = make_uint2(d0.x, d0.y); sBl[sr][skb + 1] = make_uint2(d0.z, d0.w);
      sBl[sr][skb + 2] = make_uint2(d1.x, d1.y); sBl[sr][skb + 3] = make_uint2(d1.z, d1.w);
    }
    __syncthreads();
    bf16x8 ah[4], al4[4], bh4[4], bl4[4];
#pragma unroll
    for (int t4 = 0; t4 < 4; t4++) {
      ah[t4] = frag_ld(sAh, wm * 64 + t4 * 16 + fr, c2);
      al4[t4] = frag_ld(sAl, wm * 64 + t4 * 16 + fr, c2);
      bh4[t4] = frag_ld(sBh, wn * 64 + t4 * 16 + fr, c2);
      bl4[t4] = frag_ld(sBl, wn * 64 + t4 * 16 + fr, c2);
    }
#pragma unroll
    for (int mt = 0; mt < 4; mt++)
#pragma unroll
      for (int nt = 0; nt < 4; nt++) {
        acc[mt][nt] = __builtin_amdgcn_mfma_f32_16x16x32_bf16(ah[mt], bh4[nt], acc[mt][nt], 0, 0, 0);
        acc[mt][nt] = __builtin_amdgcn_mfma_f32_16x16x32_bf16(ah[mt], bl4[nt], acc[mt][nt], 0, 0, 0);
        acc[mt][nt] = __builtin_amdgcn_mfma_f32_16x16x32_bf16(al4[mt], bh4[nt], acc[mt][nt], 0, 0, 0);
      }
    __syncthreads();
  }
  // argmin epilogue: encode order-preserving (dist,idx) u64, shuffle-min over fr, atomicMin
#pragma unroll
  for (int mt = 0; mt < 4; mt++)
#pragma unroll
    for (int reg = 0; reg < 4; reg++) {
      u64 best = ~0ull;
#pragma unroll
      for (int nt = 0; nt < 4; nt++) {
        int c = n0 + wn * 64 + nt * 16 + fr;
        float d = cnorm[c] - 2.0f * acc[mt][nt][reg];
        u32 ub = __float_as_uint(d);
        ub = (ub & 0x80000000u) ? ~ub : (ub | 0x80000000u);
        u64 p = ((u64)ub << 32) | (u32)c;
        best = (p < best) ? p : best;
      }
#pragma unroll
      for (int mm = 1; mm <= 8; mm <<= 1) {
        u32 h2 = __shfl_xor((u32)(best >> 32), mm);
        u32 l2 = __shfl_xor((u32)best, mm);
        u64 o = ((u64)h2 << 32) | l2;
        best = (o < best) ? o : best;
      }
      if (fr == 0) {
        int row = m0 + wm * 64 + mt * 16 + qd * 4 + reg;
        atomicMin(&packed[row], best);
      }
    }
}

// ---------------- idx output ----------------
__global__ __launch_bounds__(256) void idx_out_kernel(
    const u64* __restrict__ packed, float* __restrict__ o_idx) {
  int r = blockIdx.x * 256 + threadIdx.x;
  if (r < RM) o_idx[r] = (float)(u32)packed[r];
}

// ---------------- skew-oblivious count ----------------
__global__ __launch_bounds__(256) void count_kernel(
    const u64* __restrict__ packed, int* __restrict__ cnt) {
  __shared__ int h[2048];
  for (int i = threadIdx.x; i < 2048; i += 256) h[i] = 0;
  __syncthreads();
  int r = blockIdx.x * 256 + threadIdx.x;
  atomicAdd(&h[(u32)packed[r]], 1);
  __syncthreads();
  for (int i = threadIdx.x; i < 2048; i += 256) {
    int v = h[i];
    if (v) atomicAdd(&cnt[i], v);
  }
}

// one block: exclusive scan; n = 0.9*sum(ema_cs) + 0.1*RM
__global__ __launch_bounds__(256) void scan_kernel(
    const int* __restrict__ cnt, int* __restrict__ base,
    int* __restrict__ cursor, const float* __restrict__ ema_cs,
    float* __restrict__ nbuf) {
  __shared__ int part[256];
  __shared__ float esum[256];
  int t = threadIdx.x;
  int local[8];
  int s = 0;
  float es = 0.0f;
#pragma unroll
  for (int i = 0; i < 8; i++) {
    local[i] = cnt[t * 8 + i];
    s += local[i];
    es += ema_cs[t * 8 + i];
  }
  part[t] = s;
  esum[t] = es;
  __syncthreads();
  for (int off = 1; off < 256; off <<= 1) {
    int v = (t >= off) ? part[t - off] : 0;
    __syncthreads();
    part[t] += v;
    __syncthreads();
  }
  int run = part[t] - s;
#pragma unroll
  for (int i = 0; i < 8; i++) {
    base[t * 8 + i] = run;
    cursor[t * 8 + i] = run;
    run += local[i];
  }
  for (int o = 128; o; o >>= 1) {
    if (t < o) esum[t] += esum[t + o];
    __syncthreads();
  }
  if (t == 0) nbuf[0] = 0.9f * esum[0] + 0.1f * (float)RM;
}

// ---------------- skew-oblivious scatter ----------------
__global__ __launch_bounds__(256) void scatter_kernel(
    const u64* __restrict__ packed, int* __restrict__ cursor,
    u32* __restrict__ bucket) {
  __shared__ int h[2048];
  __shared__ int gb[2048];
  for (int i = threadIdx.x; i < 2048; i += 256) h[i] = 0;
  __syncthreads();
  int r = blockIdx.x * 256 + threadIdx.x;
  int k = (int)(u32)packed[r];
  int lrank = atomicAdd(&h[k], 1);
  __syncthreads();
  for (int i = threadIdx.x; i < 2048; i += 256) {
    int v = h[i];
    gb[i] = v ? atomicAdd(&cursor[i], v) : 0;
  }
  __syncthreads();
  bucket[gb[k] + lrank] = ((u32)k << 17) | (u32)r;
}

// ---------------- quant gather (ptf out) + loss partials; f = fh+fl ----------------
__global__ __launch_bounds__(256) void quant_out_kernel(
    const u16* __restrict__ fh, const u16* __restrict__ fl,
    const float* __restrict__ CBm, const u64* __restrict__ packed,
    float* __restrict__ ptf_out, float* __restrict__ lpart) {
  __shared__ float wred[4];
  int row = blockIdx.x * 2 + (threadIdx.x >> 7);
  int t = threadIdx.x & 127;
  int k = (int)(u32)packed[row];
  uint2 hb = ((const uint2*)(fh + (size_t)row * 512))[t];
  uint2 lb = ((const uint2*)(fl + (size_t)row * 512))[t];
  float f0 = bf16_f((u16)hb.x) + bf16_f((u16)lb.x);
  float f1 = bf16_f((u16)(hb.x >> 16)) + bf16_f((u16)(lb.x >> 16));
  float f2 = bf16_f((u16)hb.y) + bf16_f((u16)lb.y);
  float f3 = bf16_f((u16)(hb.y >> 16)) + bf16_f((u16)(lb.y >> 16));
  float4 c = ((const float4*)(CBm + (size_t)k * 512))[t];
  float* po = ptf_out + (size_t)row * 512 + 4 * t;  // base misaligned -> scalar
  po[0] = c.x; po[1] = c.y; po[2] = c.z; po[3] = c.w;
  float dx = c.x - f0, dy = c.y - f1, dz = c.z - f2, dwv = c.w - f3;
  float ls = dx * dx + dy * dy + dz * dz + dwv * dwv;
#pragma unroll
  for (int m = 32; m; m >>= 1) ls += __shfl_xor(ls, m);
  if ((threadIdx.x & 63) == 0) wred[threadIdx.x >> 6] = ls;
  __syncthreads();
  if (threadIdx.x == 0)
    lpart[blockIdx.x] = wred[0] + wred[1] + wred[2] + wred[3];
}

__global__ __launch_bounds__(256) void loss_final_kernel(
    const float* __restrict__ lpart, float* __restrict__ loss_out) {
  __shared__ float red[256];
  float s = 0.0f;
  for (int i = threadIdx.x; i < RM / 2; i += 256) s += lpart[i];
  red[threadIdx.x] = s;
  __syncthreads();
  for (int o = 128; o; o >>= 1) {
    if (threadIdx.x < o) red[threadIdx.x] += red[threadIdx.x + o];
    __syncthreads();
  }
  if (threadIdx.x == 0)
    loss_out[0] = red[0] / (float)((size_t)RM * 512);
}

// ---------------- skew-oblivious dw from bucket chunks; f = fh+fl ----------------
__global__ __launch_bounds__(256) void dwsum_chunk_kernel(
    const u16* __restrict__ fh, const u16* __restrict__ fl,
    const u32* __restrict__ bucket, float* __restrict__ dw) {
  __shared__ u32 sp[64];
  const int t = threadIdx.x;
  if (t < 64) sp[t] = bucket[blockIdx.x * 64 + t];
  __syncthreads();
  float ax = 0.0f, ay = 0.0f;
  int curk = (int)(sp[0] >> 17);
  u32 hb = *(const u32*)(fh + (size_t)(sp[0] & 0x1FFFF) * 512 + 2 * t);
  u32 lb = *(const u32*)(fl + (size_t)(sp[0] & 0x1FFFF) * 512 + 2 * t);
  for (int i = 0; i < 64; i++) {
    u32 hn = 0, ln2 = 0;
    if (i + 1 < 64) {
      hn = *(const u32*)(fh + (size_t)(sp[i + 1] & 0x1FFFF) * 512 + 2 * t);
      ln2 = *(const u32*)(fl + (size_t)(sp[i + 1] & 0x1FFFF) * 512 + 2 * t);
    }
    int k = (int)(sp[i] >> 17);
    if (k != curk) {
      atomicAdd(&dw[(size_t)curk * 512 + 2 * t], ax);
      atomicAdd(&dw[(size_t)curk * 512 + 2 * t + 1], ay);
      ax = 0.0f; ay = 0.0f; curk = k;
    }
    ax += bf16_f((u16)hb) + bf16_f((u16)lb);
    ay += bf16_f((u16)(hb >> 16)) + bf16_f((u16)(lb >> 16));
    hb = hn; lb = ln2;
  }
  atomicAdd(&dw[(size_t)curk * 512 + 2 * t], ax);
  atomicAdd(&dw[(size_t)curk * 512 + 2 * t + 1], ay);
}

// ---------------- codebook_new finalize ----------------
__global__ __launch_bounds__(256) void cbnew_kernel(
    const float* __restrict__ ema_w, const float* __restrict__ dw,
    const float* __restrict__ ema_cs, const int* __restrict__ cnt,
    const float* __restrict__ nbuf, float* __restrict__ outp) {
  int tid = blockIdx.x * 256 + threadIdx.x;
  int k = tid >> 9;
  float n = nbuf[0];
  float cs = ema_cs[k] * 0.9f + 0.1f * (float)cnt[k];
  cs = (cs + 1e-5f) / (n + 0.02048f) * n;
  outp[tid] = (ema_w[tid] * 0.9f + 0.1f * dw[tid]) / cs;
}

// ---------------- small-N GEMM (decoder) ----------------
template <int GELU_FLAG, int RES_FLAG>
__global__ __launch_bounds__(256) void small_gemm(
    const float* __restrict__ A, const float* __restrict__ W,
    const float* __restrict__ bias, const float* __restrict__ R,
    float* __restrict__ out, int Mrows, int K, int N) {
  int tid = blockIdx.x * 256 + threadIdx.x;
  int r = tid / N, c = tid % N;
  if (r >= Mrows) return;
  float s = bias[c];
  const float4* pa = (const float4*)(A + (size_t)r * K);
  const float* pw = W + c;
  int k4 = K >> 2;
  for (int kk = 0; kk < k4; kk++) {
    float4 a = pa[kk];
    s = fmaf(a.x, pw[(4 * kk + 0) * N], s);
    s = fmaf(a.y, pw[(4 * kk + 1) * N], s);
    s = fmaf(a.z, pw[(4 * kk + 2) * N], s);
    s = fmaf(a.w, pw[(4 * kk + 3) * N], s);
  }
  if (GELU_FLAG) s = gelu_f(s);
  if (RES_FLAG) s += R[(size_t)r * N + c];
  out[(size_t)r * N + c] = s;
}

// ================================================================
extern "C" void kernel_launch(void* const* d_in, const int* in_sizes, int n_in,
                              void* d_out, int out_size, void* d_ws, size_t ws_size,
                              hipStream_t stream) {
  const float* joints   = (const float*)d_in[0];
  const float* inv_tok  = (const float*)d_in[3];
  const float* start_w  = (const float*)d_in[4];
  const float* start_b  = (const float*)d_in[5];
  const float* e_ln1g = (const float*)d_in[6];
  const float* e_ln1b = (const float*)d_in[7];
  const float* e_tw1  = (const float*)d_in[8];
  const float* e_tb1  = (const float*)d_in[9];
  const float* e_tw2  = (const float*)d_in[10];
  const float* e_tb2  = (const float*)d_in[11];
  const float* e_ln2g = (const float*)d_in[12];
  const float* e_ln2b = (const float*)d_in[13];
  const float* e_cw1  = (const float*)d_in[14];
  const float* e_cb1  = (const float*)d_in[15];
  const float* e_cw2  = (const float*)d_in[16];
  const float* e_cb2  = (const float*)d_in[17];
  const float* d_ln1g = (const float*)d_in[18];
  const float* d_ln1b = (const float*)d_in[19];
  const float* d_tw1  = (const float*)d_in[20];
  const float* d_tb1  = (const float*)d_in[21];
  const float* d_tw2  = (const float*)d_in[22];
  const float* d_tb2  = (const float*)d_in[23];
  const float* d_ln2g = (const float*)d_in[24];
  const float* d_ln2b = (const float*)d_in[25];
  const float* d_cw1  = (const float*)d_in[26];
  const float* d_cb1  = (const float*)d_in[27];
  const float* d_cw2  = (const float*)d_in[28];
  const float* d_cb2  = (const float*)d_in[29];
  const float* enc_lng = (const float*)d_in[30];
  const float* enc_lnb = (const float*)d_in[31];
  const float* tok_w   = (const float*)d_in[32];
  const float* tok_b   = (const float*)d_in[33];
  const float* feat_w  = (const float*)d_in[34];
  const float* feat_b  = (const float*)d_in[35];
  const float* codebook = (const float*)d_in[36];
  const float* ema_cs   = (const float*)d_in[37];
  const float* ema_w    = (const float*)d_in[38];
  const float* dtok_w   = (const float*)d_in[39];
  const float* dtok_b   = (const float*)d_in[40];
  const float* dstart_w = (const float*)d_in[41];
  const float* dstart_b = (const float*)d_in[42];
  const float* dec_lng  = (const float*)d_in[43];
  const float* dec_lnb  = (const float*)d_in[44];
  const float* rec_w    = (const float*)d_in[45];
  const float* rec_b    = (const float*)d_in[46];

  // -------- workspace layout (floats; total 46,793,728 <= proven 46.82M) --------
  float* ws = (float*)d_ws;
  float* Ab  = ws;                  // [RJ,512] fp32 residual
  float* Bb  = ws + SZX;            // [RJ,512] fp32 temp
  float* Cc  = ws + 2 * SZX;        // [RJ,512] fp32 (ln1/enc_ln/decoder linmix out)
  float* P1e = ws + 3 * SZX;        // RJ bf16 hi+lo (ln2 out)
  float* P2e = ws + 4 * SZX;        // RJ bf16 hi+lo (mgemm1 out); decoder temps later
  float* cbs = ws + 5 * SZX;        // codebook split hi+lo (1,048,576)
  float* cnorm = cbs + 1048576;                      // 2048
  u64*  packed = (u64*)(cnorm + 2048);               // RM u64 (69,632 floats)
  int*  cnt    = (int*)(cnorm + 2048 + 69632);       // 2048
  int*  basebuf = cnt + 2048;                        // 2048
  int*  cursor  = basebuf + 2048;                    // 2048
  u32*  bucket  = (u32*)(cursor + 2048);             // RM
  float* lpart  = (float*)(bucket + RM);             // RM/2
  float* nbuf   = lpart + RM / 2;                    // 1 (padded to 2048)
  float* dw     = nbuf + 2048;                       // 2048*512
  // WT (weight transpose+split) aliases dw: only live before dw memset
  u16* WTh = (u16*)dw;
  u16* WTl = (u16*)(dw + 131072);
  // bf16 pair views
  u16* P1eh = (u16*)P1e;  u16* P1el = (u16*)(P1e + SZX / 2);
  u16* P2eh = (u16*)P2e;  u16* P2el = (u16*)(P2e + SZX / 2);
  u16* P1mh = (u16*)Ab;   u16* P1ml = (u16*)Bb;        // RM-sized (linmix out), Ab/Bb dead
  u16* P2mh = (u16*)Cc;   u16* P2ml = (u16*)P1e;       // RM-sized (feat out), Cc/P1e dead
  u16* chh = (u16*)cbs;   u16* cll = (u16*)(cbs + 524288);
  // decoder temps in P2e region
  float* dy  = P2e;
  float* dx2 = P2e + (size_t)RJ * 32;
  float* dh  = P2e + (size_t)2 * RJ * 32;
  float* dln = P2e + (size_t)2 * RJ * 32 + (size_t)RJ * 64;

  // -------- outputs --------
  float* outp = (float*)d_out;
  float* o_rec = outp;
  float* o_idx = outp + (size_t)RJ * 2;
  float* o_loss = o_idx + RM;
  float* o_ptf = o_loss + 1;
  float* o_cb = o_ptf + SZM;

  // -------- encoder --------
  embed_kernel<<<(RJ * 512) / 256, 256, 0, stream>>>(joints, inv_tok, start_w, start_b, Ab);
  for (int i = 0; i < 4; i++) {
    ln_kernel<8><<<RJ / 4, 256, 0, stream>>>(Ab, Cc, e_ln1g + i * 512, e_ln1b + i * 512, RJ, 512);
    tokenmix_kernel<<<(Bn * 512) / 256, 256, 0, stream>>>(
        Cc, Ab, Bb, e_tw1 + i * 17 * 64, e_tb1 + i * 64, e_tw2 + i * 64 * 17, e_tb2 + i * 17, Bn, 512);
    ln_bf16_kernel<<<RJ / 4, 256, 0, stream>>>(Bb, P1eh, P1el, e_ln2g + i * 512, e_ln2b + i * 512, RJ);
    prep_wT<<<1024, 256, 0, stream>>>(e_cw1 + (size_t)i * 512 * 512, WTh, WTl);
    mgemm<1, 0, 1><<<dim3(RJ / 128, 4), 256, 0, stream>>>(
        P1eh, P1el, WTh, WTl, e_cb1 + i * 512, nullptr, nullptr, P2eh, P2el, 512);
    prep_wT<<<1024, 256, 0, stream>>>(e_cw2 + (size_t)i * 512 * 512, WTh, WTl);
    mgemm<0, 1, 0><<<dim3(RJ / 128, 4), 256, 0, stream>>>(
        P2eh, P2el, WTh, WTl, e_cb2 + i * 512, Bb, Ab, nullptr, nullptr, 512);
  }
  ln_kernel<8><<<RJ / 4, 256, 0, stream>>>(Ab, Cc, enc_lng, enc_lnb, RJ, 512);
  linmix_bf16_kernel<<<(Bn * 512) / 256, 256, 0, stream>>>(Cc, P1mh, P1ml, tok_w, tok_b);
  prep_wT<<<1024, 256, 0, stream>>>(feat_w, WTh, WTl);
  mgemm<0, 0, 1><<<dim3(RM / 128, 4), 256, 0, stream>>>(
      P1mh, P1ml, WTh, WTl, feat_b, nullptr, nullptr, P2mh, P2ml, 512);

  // -------- VQ: distances + argmin (packed u64 atomicMin) --------
  split_kernel<<<(2048 * 512 / 4) / 256, 256, 0, stream>>>(codebook, chh, cll);
  cnorm_kernel<<<2048 / 4, 256, 0, stream>>>(codebook, cnorm);
  hipMemsetAsync(packed, 0xFF, (size_t)RM * 8, stream);
  dist_mfma<<<dim3(RM / 128, 2048 / 128), 256, 0, stream>>>(P2mh, P2ml, chh, cll, cnorm, packed);
  idx_out_kernel<<<RM / 256, 256, 0, stream>>>(packed, o_idx);

  // -------- skew-oblivious bucketed EMA update --------
  hipMemsetAsync(cnt, 0, 2048 * sizeof(int), stream);
  count_kernel<<<RM / 256, 256, 0, stream>>>(packed, cnt);
  scan_kernel<<<1, 256, 0, stream>>>(cnt, basebuf, cursor, ema_cs, nbuf);
  scatter_kernel<<<RM / 256, 256, 0, stream>>>(packed, cursor, bucket);
  quant_out_kernel<<<RM / 2, 256, 0, stream>>>(P2mh, P2ml, codebook, packed, o_ptf, lpart);
  loss_final_kernel<<<1, 256, 0, stream>>>(lpart, o_loss);
  hipMemsetAsync(dw, 0, (size_t)2048 * 512 * sizeof(float), stream);  // WT dead now
  dwsum_chunk_kernel<<<RM / 64, 256, 0, stream>>>(P2mh, P2ml, bucket, dw);
  cbnew_kernel<<<(2048 * 512) / 256, 256, 0, stream>>>(ema_w, dw, ema_cs, cnt, nbuf, o_cb);

  // -------- decoder (after dwsum: it overwrites Cc/P2e regions) --------
  linmix_kernel<34, 17><<<(Bn * 512) / 256, 256, 0, stream>>>(o_ptf, Cc, dtok_w, dtok_b, Bn, 512);
  small_gemm<0, 0><<<(RJ * 32) / 256, 256, 0, stream>>>(Cc, dstart_w, dstart_b, nullptr, dy, RJ, 512, 32);
  ln_kernel<1><<<RJ / 4, 256, 0, stream>>>(dy, dln, d_ln1g, d_ln1b, RJ, 32);
  tokenmix_kernel<<<(Bn * 32) / 256, 256, 0, stream>>>(dln, dy, dx2, d_tw1, d_tb1, d_tw2, d_tb2, Bn, 32);
  ln_kernel<1><<<RJ / 4, 256, 0, stream>>>(dx2, dln, d_ln2g, d_ln2b, RJ, 32);
  small_gemm<1, 0><<<(RJ * 64) / 256, 256, 0, stream>>>(dln, d_cw1, d_cb1, nullptr, dh, RJ, 32, 64);
  small_gemm<0, 1><<<(RJ * 32) / 256, 256, 0, stream>>>(dh, d_cw2, d_cb2, dx2, dy, RJ, 64, 32);
  ln_kernel<1><<<RJ / 4, 256, 0, stream>>>(dy, dln, dec_lng, dec_lnb, RJ, 32);
  small_gemm<0, 0><<<(RJ * 2) / 256, 256, 0, stream>>>(dln, rec_w, rec_b, nullptr, o_rec, RJ, 32, 2);
}

// Round 6
// 1732.256 us; speedup vs baseline: 3.2749x; 1.1566x over previous
//
#include <hip/hip_runtime.h>
#include <math.h>

// ---------------- problem constants ----------------
constexpr int Bn = 1024, Jn = 17, Mn = 34;
constexpr int RJ = Bn * Jn;                 // 17408
constexpr int RM = Bn * Mn;                 // 34816
constexpr size_t SZX = (size_t)RJ * 512;    // floats
constexpr size_t SZM = (size_t)RM * 512;    // floats

typedef __attribute__((ext_vector_type(8))) short bf16x8;
typedef __attribute__((ext_vector_type(4))) float f32x4;
typedef unsigned long long u64;
typedef unsigned short u16;
typedef unsigned int u32;

__device__ __forceinline__ float gelu_f(float x) {
  return 0.5f * x * (1.0f + erff(x * 0.7071067811865475f));
}
__device__ __forceinline__ u16 bf16_rne(float x) {
  u32 u = __float_as_uint(x);
  u += 0x7fffu + ((u >> 16) & 1u);
  return (u16)(u >> 16);
}
__device__ __forceinline__ float bf16_f(u16 h) {
  return __uint_as_float((u32)h << 16);
}

// async global->LDS, 16B per lane; LDS dest = wave-uniform base + lane*16
typedef __attribute__((address_space(1))) const void gas_t;
typedef __attribute__((address_space(3))) void las_t;
__device__ __forceinline__ void gll16(const void* g, void* l) {
  __builtin_amdgcn_global_load_lds((gas_t*)g, (las_t*)l, 16, 0, 0);
}

// ---------------- embed ----------------
__global__ __launch_bounds__(256) void embed_kernel(
    const float* __restrict__ joints, const float* __restrict__ inv,
    const float* __restrict__ sw, const float* __restrict__ sb,
    float* __restrict__ out) {
  int tid = blockIdx.x * 256 + threadIdx.x;
  int row = tid >> 9, d = tid & 511;
  float j0 = joints[row * 3 + 0];
  float j1 = joints[row * 3 + 1];
  float j2 = joints[row * 3 + 2];
  float x = fmaf(j0, sw[d], fmaf(j1, sw[512 + d], sb[d]));
  float v = (j2 != 0.0f) ? 1.0f : 0.0f;
  out[tid] = x * v + inv[d] * (1.0f - v);
}

// ---------------- fused mixer prefix: LN1 + tokenmix + residual + LN2(hi/lo) ----------------
// one block per pose b; 256 threads
__global__ __launch_bounds__(256) void mixer_fused(
    const float* __restrict__ x_in, float* __restrict__ res_out,
    u16* __restrict__ oh, u16* __restrict__ ol,
    const float* __restrict__ g1, const float* __restrict__ b1,
    const float* __restrict__ tw1, const float* __restrict__ tb1,
    const float* __restrict__ tw2, const float* __restrict__ tb2,
    const float* __restrict__ g2, const float* __restrict__ b2) {
  __shared__ float xs[17][513];
  __shared__ float ls[17][513];
  __shared__ float sw1[17 * 64], sw2[64 * 17], sb1v[64], sb2v[17];
  const int tid = threadIdx.x;
  const int b = blockIdx.x;
  for (int i = tid; i < 17 * 64; i += 256) { sw1[i] = tw1[i]; sw2[i] = tw2[i]; }
  if (tid < 64) sb1v[tid] = tb1[tid];
  if (tid < 17) sb2v[tid] = tb2[tid];
  const float* px = x_in + (size_t)b * 17 * 512;
  for (int i = tid; i < 17 * 512; i += 256) xs[i >> 9][i & 511] = px[i];
  __syncthreads();
  const int wv = tid >> 6, ln_ = tid & 63;
  // LN1 rows -> ls
  for (int j = wv; j < 17; j += 4) {
    float v[8];
    float s = 0.0f;
#pragma unroll
    for (int i = 0; i < 8; i++) { v[i] = xs[j][ln_ + 64 * i]; s += v[i]; }
#pragma unroll
    for (int m = 32; m; m >>= 1) s += __shfl_xor(s, m);
    float mean = s * (1.0f / 512.0f);
    float s2 = 0.0f;
#pragma unroll
    for (int i = 0; i < 8; i++) { float t = v[i] - mean; s2 += t * t; }
#pragma unroll
    for (int m = 32; m; m >>= 1) s2 += __shfl_xor(s2, m);
    float rs = 1.0f / sqrtf(s2 * (1.0f / 512.0f) + 1e-5f);
#pragma unroll
    for (int i = 0; i < 8; i++) {
      int d = ln_ + 64 * i;
      ls[j][d] = (v[i] - mean) * rs * g1[d] + b1[d];
    }
  }
  __syncthreads();
  // tokenmix: 2 columns per thread; res = x + y -> ls (in place) + global
  for (int cc = 0; cc < 2; cc++) {
    int d = tid + cc * 256;
    float t[17], acc[17];
#pragma unroll
    for (int j = 0; j < 17; j++) { t[j] = ls[j][d]; acc[j] = 0.0f; }
    for (int k = 0; k < 64; k++) {
      float h = sb1v[k];
#pragma unroll
      for (int j = 0; j < 17; j++) h = fmaf(t[j], sw1[j * 64 + k], h);
      h = gelu_f(h);
#pragma unroll
      for (int j = 0; j < 17; j++) acc[j] = fmaf(h, sw2[k * 17 + j], acc[j]);
    }
#pragma unroll
    for (int j = 0; j < 17; j++) {
      float r = xs[j][d] + acc[j] + sb2v[j];
      ls[j][d] = r;
      res_out[((size_t)b * 17 + j) * 512 + d] = r;
    }
  }
  __syncthreads();
  // LN2 rows of ls -> hi/lo global
  for (int j = wv; j < 17; j += 4) {
    float v[8];
    float s = 0.0f;
#pragma unroll
    for (int i = 0; i < 8; i++) { v[i] = ls[j][ln_ + 64 * i]; s += v[i]; }
#pragma unroll
    for (int m = 32; m; m >>= 1) s += __shfl_xor(s, m);
    float mean = s * (1.0f / 512.0f);
    float s2 = 0.0f;
#pragma unroll
    for (int i = 0; i < 8; i++) { float t = v[i] - mean; s2 += t * t; }
#pragma unroll
    for (int m = 32; m; m >>= 1) s2 += __shfl_xor(s2, m);
    float rs = 1.0f / sqrtf(s2 * (1.0f / 512.0f) + 1e-5f);
#pragma unroll
    for (int i = 0; i < 8; i++) {
      int d = ln_ + 64 * i;
      float o = (v[i] - mean) * rs * g2[d] + b2[d];
      u16 h = bf16_rne(o);
      size_t off = ((size_t)b * 17 + j) * 512 + d;
      oh[off] = h;
      ol[off] = bf16_rne(o - bf16_f(h));
    }
  }
}

// ---------------- fused enc_ln + token linmix (17->34), hi/lo out ----------------
__global__ __launch_bounds__(256) void lnmix_fused(
    const float* __restrict__ x_in, u16* __restrict__ oh, u16* __restrict__ ol,
    const float* __restrict__ g, const float* __restrict__ bb,
    const float* __restrict__ w, const float* __restrict__ bias) {
  __shared__ float xs[17][513];
  __shared__ float sw[17 * 34], sb[34];
  const int tid = threadIdx.x;
  const int b = blockIdx.x;
  for (int i = tid; i < 17 * 34; i += 256) sw[i] = w[i];
  if (tid < 34) sb[tid] = bias[tid];
  const float* px = x_in + (size_t)b * 17 * 512;
  for (int i = tid; i < 17 * 512; i += 256) xs[i >> 9][i & 511] = px[i];
  __syncthreads();
  const int wv = tid >> 6, ln_ = tid & 63;
  for (int j = wv; j < 17; j += 4) {
    float v[8];
    float s = 0.0f;
#pragma unroll
    for (int i = 0; i < 8; i++) { v[i] = xs[j][ln_ + 64 * i]; s += v[i]; }
#pragma unroll
    for (int m = 32; m; m >>= 1) s += __shfl_xor(s, m);
    float mean = s * (1.0f / 512.0f);
    float s2 = 0.0f;
#pragma unroll
    for (int i = 0; i < 8; i++) { float t = v[i] - mean; s2 += t * t; }
#pragma unroll
    for (int m = 32; m; m >>= 1) s2 += __shfl_xor(s2, m);
    float rs = 1.0f / sqrtf(s2 * (1.0f / 512.0f) + 1e-5f);
#pragma unroll
    for (int i = 0; i < 8; i++) {
      int d = ln_ + 64 * i;
      xs[j][d] = (v[i] - mean) * rs * g[d] + bb[d];  // in place, own row
    }
  }
  __syncthreads();
  for (int cc = 0; cc < 2; cc++) {
    int d = tid + cc * 256;
    float t[17];
#pragma unroll
    for (int j = 0; j < 17; j++) t[j] = xs[j][d];
#pragma unroll
    for (int m = 0; m < 34; m++) {
      float s = sb[m];
#pragma unroll
      for (int j = 0; j < 17; j++) s = fmaf(t[j], sw[j * 34 + m], s);
      size_t o = ((size_t)b * 34 + m) * 512 + d;
      u16 h = bf16_rne(s);
      oh[o] = h;
      ol[o] = bf16_rne(s - bf16_f(h));
    }
  }
}

// ---------------- weight transpose+split: two 512x512 weights per launch ----------------
__global__ __launch_bounds__(256) void prep2_wT(
    const float* __restrict__ W1, const float* __restrict__ W2,
    u16* __restrict__ Th1, u16* __restrict__ Tl1,
    u16* __restrict__ Th2, u16* __restrict__ Tl2) {
  int tid = blockIdx.x * 256 + threadIdx.x;  // < 2*262144
  const float* W = (tid < 262144) ? W1 : W2;
  u16* Th = (tid < 262144) ? Th1 : Th2;
  u16* Tl = (tid < 262144) ? Tl1 : Tl2;
  int t = tid & 262143;
  int k = t >> 9, n = t & 511;
  float v = W[t];
  u16 h = bf16_rne(v);
  Th[(size_t)n * 512 + k] = h;
  Tl[(size_t)n * 512 + k] = bf16_rne(v - bf16_f(h));
}

__global__ __launch_bounds__(256) void prep_wT(
    const float* __restrict__ W, u16* __restrict__ Th, u16* __restrict__ Tl) {
  int tid = blockIdx.x * 256 + threadIdx.x;
  int k = tid >> 9, n = tid & 511;
  float v = W[tid];
  u16 h = bf16_rne(v);
  Th[(size_t)n * 512 + k] = h;
  Tl[(size_t)n * 512 + k] = bf16_rne(v - bf16_f(h));
}

// ---------------- fp32 -> bf16 hi/lo split (codebook) ----------------
__global__ __launch_bounds__(256) void split_kernel(
    const float* __restrict__ src, u16* __restrict__ hi, u16* __restrict__ lo) {
  int t = blockIdx.x * 256 + threadIdx.x;
  float4 x = ((const float4*)src)[t];
  ushort4 h, l;
  h.x = bf16_rne(x.x); l.x = bf16_rne(x.x - bf16_f(h.x));
  h.y = bf16_rne(x.y); l.y = bf16_rne(x.y - bf16_f(h.y));
  h.z = bf16_rne(x.z); l.z = bf16_rne(x.z - bf16_f(h.z));
  h.w = bf16_rne(x.w); l.w = bf16_rne(x.w - bf16_f(h.w));
  ((ushort4*)hi)[t] = h;
  ((ushort4*)lo)[t] = l;
}

// ---------------- codebook L2 norms ----------------
__global__ __launch_bounds__(256) void cnorm_kernel(
    const float* __restrict__ CBm, float* __restrict__ cnorm) {
  int wave = threadIdx.x >> 6, lane = threadIdx.x & 63;
  int k = blockIdx.x * 4 + wave;
  const float* p = CBm + (size_t)k * 512;
  float s = 0.0f;
#pragma unroll
  for (int i = 0; i < 8; i++) {
    float v = p[lane + 64 * i];
    s = fmaf(v, v, s);
  }
#pragma unroll
  for (int m = 32; m; m >>= 1) s += __shfl_xor(s, m);
  if (lane == 0) cnorm[k] = s;
}

// ======== shared staging/compute macros for the MFMA GEMMs ========
// LDS tile per array: 128 rows x 32 u16 as 512 16B-chunks;
// chunk(r,c) = r*4 + (c ^ ((r>>1)&3)). global_load_lds lane i -> base+16i.
#define MG_PROLOGUE()                                                        \
  const int tid = threadIdx.x;                                               \
  const int m0 = blockIdx.x * 128, n0 = blockIdx.y * 128;                    \
  const int lane = tid & 63, wave = tid >> 6;                                \
  const int wm = wave >> 1, wn = wave & 1;                                   \
  const int fr = lane & 15, q = lane >> 4, qd = q;                           \
  const int ci0 = wave * 128 + lane, ci1 = ci0 + 64;                         \
  const int r0 = ci0 >> 2, c0x = (ci0 & 3) ^ ((r0 >> 1) & 3);                \
  const int r1 = ci1 >> 2, c1x = (ci1 & 3) ^ ((r1 >> 1) & 3);                \
  const size_t aoff0 = (size_t)(m0 + r0) * 512 + c0x * 8;                    \
  const size_t aoff1 = (size_t)(m0 + r1) * 512 + c1x * 8;                    \
  const size_t boff0 = (size_t)(n0 + r0) * 512 + c0x * 8;                    \
  const size_t boff1 = (size_t)(n0 + r1) * 512 + c1x * 8;                    \
  const int ld0 = wave * 1024, ld1 = ld0 + 512; /* u16 index of dest */      \
  int fca[4], fcb[4];                                                        \
  _Pragma("unroll") for (int t4 = 0; t4 < 4; t4++) {                         \
    int rra = wm * 64 + t4 * 16 + fr;                                        \
    int rrb = wn * 64 + t4 * 16 + fr;                                        \
    int sz = q ^ ((fr >> 1) & 3);                                            \
    fca[t4] = (rra * 4 + sz) * 8;                                            \
    fcb[t4] = (rrb * 4 + sz) * 8;                                            \
  }                                                                          \
  f32x4 acc[4][4];                                                           \
  _Pragma("unroll") for (int i = 0; i < 4; i++)                              \
    _Pragma("unroll") for (int j = 0; j < 4; j++) {                          \
      acc[i][j][0] = 0.0f; acc[i][j][1] = 0.0f;                              \
      acc[i][j][2] = 0.0f; acc[i][j][3] = 0.0f;                              \
    }

#define MG_KLOOP(Ah, Al, Bh, Bl)                                             \
  for (int k0 = 0; k0 < 512; k0 += 32) {                                     \
    gll16(Ah + aoff0 + k0, &sAh[ld0]);                                       \
    gll16(Ah + aoff1 + k0, &sAh[ld1]);                                       \
    gll16(Al + aoff0 + k0, &sAl[ld0]);                                       \
    gll16(Al + aoff1 + k0, &sAl[ld1]);                                       \
    gll16(Bh + boff0 + k0, &sBh[ld0]);                                       \
    gll16(Bh + boff1 + k0, &sBh[ld1]);                                       \
    gll16(Bl + boff0 + k0, &sBl[ld0]);                                       \
    gll16(Bl + boff1 + k0, &sBl[ld1]);                                       \
    __syncthreads();                                                         \
    bf16x8 fah[4], fal[4], fbh[4], fbl[4];                                   \
    _Pragma("unroll") for (int t4 = 0; t4 < 4; t4++) {                       \
      fah[t4] = *(const bf16x8*)&sAh[fca[t4]];                               \
      fal[t4] = *(const bf16x8*)&sAl[fca[t4]];                               \
      fbh[t4] = *(const bf16x8*)&sBh[fcb[t4]];                               \
      fbl[t4] = *(const bf16x8*)&sBl[fcb[t4]];                               \
    }                                                                        \
    _Pragma("unroll") for (int mt = 0; mt < 4; mt++)                         \
      _Pragma("unroll") for (int nt = 0; nt < 4; nt++) {                     \
        acc[mt][nt] = __builtin_amdgcn_mfma_f32_16x16x32_bf16(               \
            fah[mt], fbh[nt], acc[mt][nt], 0, 0, 0);                         \
        acc[mt][nt] = __builtin_amdgcn_mfma_f32_16x16x32_bf16(               \
            fah[mt], fbl[nt], acc[mt][nt], 0, 0, 0);                         \
        acc[mt][nt] = __builtin_amdgcn_mfma_f32_16x16x32_bf16(               \
            fal[mt], fbh[nt], acc[mt][nt], 0, 0, 0);                         \
      }                                                                      \
    __syncthreads();                                                         \
  }

// ---------------- split-bf16 MFMA GEMM: C = act(A@W^T + bias)(+R) ----------------
template <int GELU_FLAG, int RES_FLAG, int HILO_OUT>
__global__ __launch_bounds__(256, 3) void mgemm(
    const u16* __restrict__ Ah, const u16* __restrict__ Al,
    const u16* __restrict__ Bh, const u16* __restrict__ Bl,
    const float* __restrict__ bias, const float* __restrict__ R,
    float* __restrict__ C, u16* __restrict__ Oh, u16* __restrict__ Ol, int N) {
  __shared__ __align__(16) u16 sAh[4096], sAl[4096], sBh[4096], sBl[4096];
  MG_PROLOGUE()
  MG_KLOOP(Ah, Al, Bh, Bl)
#pragma unroll
  for (int mt = 0; mt < 4; mt++)
#pragma unroll
    for (int reg = 0; reg < 4; reg++) {
      int row = m0 + wm * 64 + mt * 16 + qd * 4 + reg;
#pragma unroll
      for (int nt = 0; nt < 4; nt++) {
        int col = n0 + wn * 64 + nt * 16 + fr;
        float v = acc[mt][nt][reg] + bias[col];
        if (GELU_FLAG) v = gelu_f(v);
        if (RES_FLAG) v += R[(size_t)row * N + col];
        if (HILO_OUT) {
          u16 h = bf16_rne(v);
          Oh[(size_t)row * N + col] = h;
          Ol[(size_t)row * N + col] = bf16_rne(v - bf16_f(h));
        } else {
          C[(size_t)row * N + col] = v;
        }
      }
    }
}

// ---------------- distance GEMM + packed-u64 argmin ----------------
__global__ __launch_bounds__(256, 3) void dist_mfma(
    const u16* __restrict__ Ah, const u16* __restrict__ Al,
    const u16* __restrict__ Bh, const u16* __restrict__ Bl,
    const float* __restrict__ cnorm, u64* __restrict__ packed) {
  __shared__ __align__(16) u16 sAh[4096], sAl[4096], sBh[4096], sBl[4096];
  MG_PROLOGUE()
  MG_KLOOP(Ah, Al, Bh, Bl)
#pragma unroll
  for (int mt = 0; mt < 4; mt++)
#pragma unroll
    for (int reg = 0; reg < 4; reg++) {
      u64 best = ~0ull;
#pragma unroll
      for (int nt = 0; nt < 4; nt++) {
        int c = n0 + wn * 64 + nt * 16 + fr;
        float d = cnorm[c] - 2.0f * acc[mt][nt][reg];
        u32 ub = __float_as_uint(d);
        ub = (ub & 0x80000000u) ? ~ub : (ub | 0x80000000u);
        u64 p = ((u64)ub << 32) | (u32)c;
        best = (p < best) ? p : best;
      }
#pragma unroll
      for (int mm = 1; mm <= 8; mm <<= 1) {
        u32 h2 = __shfl_xor((u32)(best >> 32), mm);
        u32 l2 = __shfl_xor((u32)best, mm);
        u64 o = ((u64)h2 << 32) | l2;
        best = (o < best) ? o : best;
      }
      if (fr == 0) {
        int row = m0 + wm * 64 + mt * 16 + qd * 4 + reg;
        atomicMin(&packed[row], best);
      }
    }
}

// ---------------- idx output ----------------
__global__ __launch_bounds__(256) void idx_out_kernel(
    const u64* __restrict__ packed, float* __restrict__ o_idx) {
  int r = blockIdx.x * 256 + threadIdx.x;
  if (r < RM) o_idx[r] = (float)(u32)packed[r];
}

// ---------------- skew-oblivious count ----------------
__global__ __launch_bounds__(256) void count_kernel(
    const u64* __restrict__ packed, int* __restrict__ cnt) {
  __shared__ int h[2048];
  for (int i = threadIdx.x; i < 2048; i += 256) h[i] = 0;
  __syncthreads();
  int r = blockIdx.x * 256 + threadIdx.x;
  atomicAdd(&h[(u32)packed[r]], 1);
  __syncthreads();
  for (int i = threadIdx.x; i < 2048; i += 256) {
    int v = h[i];
    if (v) atomicAdd(&cnt[i], v);
  }
}

__global__ __launch_bounds__(256) void scan_kernel(
    const int* __restrict__ cnt, int* __restrict__ base,
    int* __restrict__ cursor, const float* __restrict__ ema_cs,
    float* __restrict__ nbuf) {
  __shared__ int part[256];
  __shared__ float esum[256];
  int t = threadIdx.x;
  int local[8];
  int s = 0;
  float es = 0.0f;
#pragma unroll
  for (int i = 0; i < 8; i++) {
    local[i] = cnt[t * 8 + i];
    s += local[i];
    es += ema_cs[t * 8 + i];
  }
  part[t] = s;
  esum[t] = es;
  __syncthreads();
  for (int off = 1; off < 256; off <<= 1) {
    int v = (t >= off) ? part[t - off] : 0;
    __syncthreads();
    part[t] += v;
    __syncthreads();
  }
  int run = part[t] - s;
#pragma unroll
  for (int i = 0; i < 8; i++) {
    base[t * 8 + i] = run;
    cursor[t * 8 + i] = run;
    run += local[i];
  }
  for (int o = 128; o; o >>= 1) {
    if (t < o) esum[t] += esum[t + o];
    __syncthreads();
  }
  if (t == 0) nbuf[0] = 0.9f * esum[0] + 0.1f * (float)RM;
}

__global__ __launch_bounds__(256) void scatter_kernel(
    const u64* __restrict__ packed, int* __restrict__ cursor,
    u32* __restrict__ bucket) {
  __shared__ int h[2048];
  __shared__ int gb[2048];
  for (int i = threadIdx.x; i < 2048; i += 256) h[i] = 0;
  __syncthreads();
  int r = blockIdx.x * 256 + threadIdx.x;
  int k = (int)(u32)packed[r];
  int lrank = atomicAdd(&h[k], 1);
  __syncthreads();
  for (int i = threadIdx.x; i < 2048; i += 256) {
    int v = h[i];
    gb[i] = v ? atomicAdd(&cursor[i], v) : 0;
  }
  __syncthreads();
  bucket[gb[k] + lrank] = ((u32)k << 17) | (u32)r;
}

// ---------------- quant gather + loss partials; f = fh+fl ----------------
__global__ __launch_bounds__(256) void quant_out_kernel(
    const u16* __restrict__ fh, const u16* __restrict__ fl,
    const float* __restrict__ CBm, const u64* __restrict__ packed,
    float* __restrict__ ptf_out, float* __restrict__ lpart) {
  __shared__ float wred[4];
  int row = blockIdx.x * 2 + (threadIdx.x >> 7);
  int t = threadIdx.x & 127;
  int k = (int)(u32)packed[row];
  uint2 hb = ((const uint2*)(fh + (size_t)row * 512))[t];
  uint2 lb = ((const uint2*)(fl + (size_t)row * 512))[t];
  float f0 = bf16_f((u16)hb.x) + bf16_f((u16)lb.x);
  float f1 = bf16_f((u16)(hb.x >> 16)) + bf16_f((u16)(lb.x >> 16));
  float f2 = bf16_f((u16)hb.y) + bf16_f((u16)lb.y);
  float f3 = bf16_f((u16)(hb.y >> 16)) + bf16_f((u16)(lb.y >> 16));
  float4 c = ((const float4*)(CBm + (size_t)k * 512))[t];
  float* po = ptf_out + (size_t)row * 512 + 4 * t;
  po[0] = c.x; po[1] = c.y; po[2] = c.z; po[3] = c.w;
  float dx = c.x - f0, dy = c.y - f1, dz = c.z - f2, dwv = c.w - f3;
  float ls = dx * dx + dy * dy + dz * dz + dwv * dwv;
#pragma unroll
  for (int m = 32; m; m >>= 1) ls += __shfl_xor(ls, m);
  if ((threadIdx.x & 63) == 0) wred[threadIdx.x >> 6] = ls;
  __syncthreads();
  if (threadIdx.x == 0)
    lpart[blockIdx.x] = wred[0] + wred[1] + wred[2] + wred[3];
}

__global__ __launch_bounds__(256) void loss_final_kernel(
    const float* __restrict__ lpart, float* __restrict__ loss_out) {
  __shared__ float red[256];
  float s = 0.0f;
  for (int i = threadIdx.x; i < RM / 2; i += 256) s += lpart[i];
  red[threadIdx.x] = s;
  __syncthreads();
  for (int o = 128; o; o >>= 1) {
    if (threadIdx.x < o) red[threadIdx.x] += red[threadIdx.x + o];
    __syncthreads();
  }
  if (threadIdx.x == 0)
    loss_out[0] = red[0] / (float)((size_t)RM * 512);
}

// ---------------- skew-oblivious dw from bucket chunks ----------------
__global__ __launch_bounds__(256) void dwsum_chunk_kernel(
    const u16* __restrict__ fh, const u16* __restrict__ fl,
    const u32* __restrict__ bucket, float* __restrict__ dw) {
  __shared__ u32 sp[64];
  const int t = threadIdx.x;
  if (t < 64) sp[t] = bucket[blockIdx.x * 64 + t];
  __syncthreads();
  float ax = 0.0f, ay = 0.0f;
  int curk = (int)(sp[0] >> 17);
  u32 hb = *(const u32*)(fh + (size_t)(sp[0] & 0x1FFFF) * 512 + 2 * t);
  u32 lb = *(const u32*)(fl + (size_t)(sp[0] & 0x1FFFF) * 512 + 2 * t);
  for (int i = 0; i < 64; i++) {
    u32 hn = 0, ln2 = 0;
    if (i + 1 < 64) {
      hn = *(const u32*)(fh + (size_t)(sp[i + 1] & 0x1FFFF) * 512 + 2 * t);
      ln2 = *(const u32*)(fl + (size_t)(sp[i + 1] & 0x1FFFF) * 512 + 2 * t);
    }
    int k = (int)(sp[i] >> 17);
    if (k != curk) {
      atomicAdd(&dw[(size_t)curk * 512 + 2 * t], ax);
      atomicAdd(&dw[(size_t)curk * 512 + 2 * t + 1], ay);
      ax = 0.0f; ay = 0.0f; curk = k;
    }
    ax += bf16_f((u16)hb) + bf16_f((u16)lb);
    ay += bf16_f((u16)(hb >> 16)) + bf16_f((u16)(lb >> 16));
    hb = hn; lb = ln2;
  }
  atomicAdd(&dw[(size_t)curk * 512 + 2 * t], ax);
  atomicAdd(&dw[(size_t)curk * 512 + 2 * t + 1], ay);
}

// ---------------- codebook_new finalize ----------------
__global__ __launch_bounds__(256) void cbnew_kernel(
    const float* __restrict__ ema_w, const float* __restrict__ dw,
    const float* __restrict__ ema_cs, const int* __restrict__ cnt,
    const float* __restrict__ nbuf, float* __restrict__ outp) {
  int tid = blockIdx.x * 256 + threadIdx.x;
  int k = tid >> 9;
  float n = nbuf[0];
  float cs = ema_cs[k] * 0.9f + 0.1f * (float)cnt[k];
  cs = (cs + 1e-5f) / (n + 0.02048f) * n;
  outp[tid] = (ema_w[tid] * 0.9f + 0.1f * dw[tid]) / cs;
}

// ---------------- decoder helpers (small sizes, fp32) ----------------
template <int NV>
__global__ __launch_bounds__(256) void ln_kernel(
    const float* __restrict__ src, float* __restrict__ dst,
    const float* __restrict__ g, const float* __restrict__ b,
    int rows, int D) {
  int wave = threadIdx.x >> 6, lane = threadIdx.x & 63;
  int row = blockIdx.x * 4 + wave;
  if (row >= rows) return;
  const float* p = src + (size_t)row * D;
  float v[NV];
  float s = 0.0f;
#pragma unroll
  for (int i = 0; i < NV; i++) {
    int d = lane + 64 * i;
    v[i] = (d < D) ? p[d] : 0.0f;
    s += v[i];
  }
#pragma unroll
  for (int m = 32; m; m >>= 1) s += __shfl_xor(s, m);
  float mean = s / (float)D;
  float s2 = 0.0f;
#pragma unroll
  for (int i = 0; i < NV; i++) {
    int d = lane + 64 * i;
    float t = (d < D) ? (v[i] - mean) : 0.0f;
    s2 += t * t;
  }
#pragma unroll
  for (int m = 32; m; m >>= 1) s2 += __shfl_xor(s2, m);
  float rs = 1.0f / sqrtf(s2 / (float)D + 1e-5f);
  float* qo = dst + (size_t)row * D;
#pragma unroll
  for (int i = 0; i < NV; i++) {
    int d = lane + 64 * i;
    if (d < D) qo[d] = (v[i] - mean) * rs * g[d] + b[d];
  }
}

__global__ __launch_bounds__(256) void tokenmix_kernel(
    const float* __restrict__ ln, const float* __restrict__ xin,
    float* __restrict__ out, const float* __restrict__ tw1,
    const float* __restrict__ tb1, const float* __restrict__ tw2,
    const float* __restrict__ tb2, int B, int H) {
  __shared__ float sw1[17 * 64], sw2[64 * 17], sb1[64], sb2[17];
  for (int i = threadIdx.x; i < 17 * 64; i += 256) {
    sw1[i] = tw1[i];
    sw2[i] = tw2[i];
  }
  if (threadIdx.x < 64) sb1[threadIdx.x] = tb1[threadIdx.x];
  if (threadIdx.x < 17) sb2[threadIdx.x] = tb2[threadIdx.x];
  __syncthreads();
  int tid = blockIdx.x * 256 + threadIdx.x;
  if (tid >= B * H) return;
  int b = tid / H, d = tid % H;
  const float* pl = ln + (size_t)b * 17 * H + d;
  float t[17], acc[17];
#pragma unroll
  for (int j = 0; j < 17; j++) { t[j] = pl[j * H]; acc[j] = 0.0f; }
  for (int k = 0; k < 64; k++) {
    float h = sb1[k];
#pragma unroll
    for (int j = 0; j < 17; j++) h = fmaf(t[j], sw1[j * 64 + k], h);
    h = gelu_f(h);
#pragma unroll
    for (int j = 0; j < 17; j++) acc[j] = fmaf(h, sw2[k * 17 + j], acc[j]);
  }
  const float* px = xin + (size_t)b * 17 * H + d;
  float* po = out + (size_t)b * 17 * H + d;
#pragma unroll
  for (int j = 0; j < 17; j++) po[j * H] = px[j * H] + acc[j] + sb2[j];
}

template <int JIN, int JOUT>
__global__ __launch_bounds__(256) void linmix_kernel(
    const float* __restrict__ in, float* __restrict__ out,
    const float* __restrict__ w, const float* __restrict__ bias,
    int B, int H) {
  __shared__ float sw[JIN * JOUT], sb[JOUT];
  for (int i = threadIdx.x; i < JIN * JOUT; i += 256) sw[i] = w[i];
  if (threadIdx.x < JOUT) sb[threadIdx.x] = bias[threadIdx.x];
  __syncthreads();
  int tid = blockIdx.x * 256 + threadIdx.x;
  if (tid >= B * H) return;
  int b = tid / H, d = tid % H;
  const float* pi = in + (size_t)b * JIN * H + d;
  float t[JIN];
#pragma unroll
  for (int j = 0; j < JIN; j++) t[j] = pi[(size_t)j * H];
  float* po = out + (size_t)b * JOUT * H + d;
#pragma unroll
  for (int m = 0; m < JOUT; m++) {
    float s = sb[m];
#pragma unroll
    for (int j = 0; j < JIN; j++) s = fmaf(t[j], sw[j * JOUT + m], s);
    po[(size_t)m * H] = s;
  }
}

template <int GELU_FLAG, int RES_FLAG>
__global__ __launch_bounds__(256) void small_gemm(
    const float* __restrict__ A, const float* __restrict__ W,
    const float* __restrict__ bias, const float* __restrict__ R,
    float* __restrict__ out, int Mrows, int K, int N) {
  int tid = blockIdx.x * 256 + threadIdx.x;
  int r = tid / N, c = tid % N;
  if (r >= Mrows) return;
  float s = bias[c];
  const float4* pa = (const float4*)(A + (size_t)r * K);
  const float* pw = W + c;
  int k4 = K >> 2;
  for (int kk = 0; kk < k4; kk++) {
    float4 a = pa[kk];
    s = fmaf(a.x, pw[(4 * kk + 0) * N], s);
    s = fmaf(a.y, pw[(4 * kk + 1) * N], s);
    s = fmaf(a.z, pw[(4 * kk + 2) * N], s);
    s = fmaf(a.w, pw[(4 * kk + 3) * N], s);
  }
  if (GELU_FLAG) s = gelu_f(s);
  if (RES_FLAG) s += R[(size_t)r * N + c];
  out[(size_t)r * N + c] = s;
}

// ================================================================
extern "C" void kernel_launch(void* const* d_in, const int* in_sizes, int n_in,
                              void* d_out, int out_size, void* d_ws, size_t ws_size,
                              hipStream_t stream) {
  const float* joints   = (const float*)d_in[0];
  const float* inv_tok  = (const float*)d_in[3];
  const float* start_w  = (const float*)d_in[4];
  const float* start_b  = (const float*)d_in[5];
  const float* e_ln1g = (const float*)d_in[6];
  const float* e_ln1b = (const float*)d_in[7];
  const float* e_tw1  = (const float*)d_in[8];
  const float* e_tb1  = (const float*)d_in[9];
  const float* e_tw2  = (const float*)d_in[10];
  const float* e_tb2  = (const float*)d_in[11];
  const float* e_ln2g = (const float*)d_in[12];
  const float* e_ln2b = (const float*)d_in[13];
  const float* e_cw1  = (const float*)d_in[14];
  const float* e_cb1  = (const float*)d_in[15];
  const float* e_cw2  = (const float*)d_in[16];
  const float* e_cb2  = (const float*)d_in[17];
  const float* d_ln1g = (const float*)d_in[18];
  const float* d_ln1b = (const float*)d_in[19];
  const float* d_tw1  = (const float*)d_in[20];
  const float* d_tb1  = (const float*)d_in[21];
  const float* d_tw2  = (const float*)d_in[22];
  const float* d_tb2  = (const float*)d_in[23];
  const float* d_ln2g = (const float*)d_in[24];
  const float* d_ln2b = (const float*)d_in[25];
  const float* d_cw1  = (const float*)d_in[26];
  const float* d_cb1  = (const float*)d_in[27];
  const float* d_cw2  = (const float*)d_in[28];
  const float* d_cb2  = (const float*)d_in[29];
  const float* enc_lng = (const float*)d_in[30];
  const float* enc_lnb = (const float*)d_in[31];
  const float* tok_w   = (const float*)d_in[32];
  const float* tok_b   = (const float*)d_in[33];
  const float* feat_w  = (const float*)d_in[34];
  const float* feat_b  = (const float*)d_in[35];
  const float* codebook = (const float*)d_in[36];
  const float* ema_cs   = (const float*)d_in[37];
  const float* ema_w    = (const float*)d_in[38];
  const float* dtok_w   = (const float*)d_in[39];
  const float* dtok_b   = (const float*)d_in[40];
  const float* dstart_w = (const float*)d_in[41];
  const float* dstart_b = (const float*)d_in[42];
  const float* dec_lng  = (const float*)d_in[43];
  const float* dec_lnb  = (const float*)d_in[44];
  const float* rec_w    = (const float*)d_in[45];
  const float* rec_b    = (const float*)d_in[46];

  // -------- workspace layout (same proven footprint as round 5) --------
  float* ws = (float*)d_ws;
  float* Ab  = ws;                  // [RJ,512] fp32 residual
  float* Bb  = ws + SZX;            // [RJ,512] fp32 (x+y residual)
  float* Cc  = ws + 2 * SZX;        // fp32 scratch (decoder linmix out)
  float* P1e = ws + 3 * SZX;        // RJ bf16 hi+lo (ln2 out)
  float* P2e = ws + 4 * SZX;        // RJ bf16 hi+lo (mgemm1 out); decoder temps later
  float* cbs = ws + 5 * SZX;        // codebook split hi+lo
  float* cnorm = cbs + 1048576;                      // 2048
  u64*  packed = (u64*)(cnorm + 2048);               // RM u64
  int*  cnt    = (int*)(cnorm + 2048 + 69632);       // 2048
  int*  basebuf = cnt + 2048;
  int*  cursor  = basebuf + 2048;
  u32*  bucket  = (u32*)(cursor + 2048);             // RM
  float* lpart  = (float*)(bucket + RM);             // RM/2
  float* nbuf   = lpart + RM / 2;                    // 1 (padded)
  float* dw     = nbuf + 2048;                       // 2048*512
  // WT buffers alias dw (live only before dw memset)
  u16* WTh1 = (u16*)dw;
  u16* WTl1 = (u16*)(dw + 131072);
  u16* WTh2 = (u16*)(dw + 262144);
  u16* WTl2 = (u16*)(dw + 393216);
  // bf16 pair views
  u16* P1eh = (u16*)P1e;  u16* P1el = (u16*)(P1e + SZX / 2);
  u16* P2eh = (u16*)P2e;  u16* P2el = (u16*)(P2e + SZX / 2);
  u16* P1mh = (u16*)Ab;   u16* P1ml = (u16*)Bb;     // RM-sized, lnmix_fused out
  u16* P2mh = (u16*)Cc;   u16* P2ml = (u16*)P1e;    // RM-sized, feat out
  u16* chh = (u16*)cbs;   u16* cll = (u16*)(cbs + 524288);
  // decoder temps in P2e region
  float* dy  = P2e;
  float* dx2 = P2e + (size_t)RJ * 32;
  float* dh  = P2e + (size_t)2 * RJ * 32;
  float* dln = P2e + (size_t)2 * RJ * 32 + (size_t)RJ * 64;

  // -------- outputs --------
  float* outp = (float*)d_out;
  float* o_rec = outp;
  float* o_idx = outp + (size_t)RJ * 2;
  float* o_loss = o_idx + RM;
  float* o_ptf = o_loss + 1;
  float* o_cb = o_ptf + SZM;

  // -------- encoder --------
  embed_kernel<<<(RJ * 512) / 256, 256, 0, stream>>>(joints, inv_tok, start_w, start_b, Ab);
  for (int i = 0; i < 4; i++) {
    prep2_wT<<<2048, 256, 0, stream>>>(
        e_cw1 + (size_t)i * 512 * 512, e_cw2 + (size_t)i * 512 * 512,
        WTh1, WTl1, WTh2, WTl2);
    mixer_fused<<<Bn, 256, 0, stream>>>(
        Ab, Bb, P1eh, P1el,
        e_ln1g + i * 512, e_ln1b + i * 512,
        e_tw1 + i * 17 * 64, e_tb1 + i * 64, e_tw2 + i * 64 * 17, e_tb2 + i * 17,
        e_ln2g + i * 512, e_ln2b + i * 512);
    mgemm<1, 0, 1><<<dim3(RJ / 128, 4), 256, 0, stream>>>(
        P1eh, P1el, WTh1, WTl1, e_cb1 + i * 512, nullptr, nullptr, P2eh, P2el, 512);
    mgemm<0, 1, 0><<<dim3(RJ / 128, 4), 256, 0, stream>>>(
        P2eh, P2el, WTh2, WTl2, e_cb2 + i * 512, Bb, Ab, nullptr, nullptr, 512);
  }
  lnmix_fused<<<Bn, 256, 0, stream>>>(Ab, P1mh, P1ml, enc_lng, enc_lnb, tok_w, tok_b);
  prep_wT<<<1024, 256, 0, stream>>>(feat_w, WTh1, WTl1);
  mgemm<0, 0, 1><<<dim3(RM / 128, 4), 256, 0, stream>>>(
      P1mh, P1ml, WTh1, WTl1, feat_b, nullptr, nullptr, P2mh, P2ml, 512);

  // -------- VQ: distances + argmin --------
  split_kernel<<<(2048 * 512 / 4) / 256, 256, 0, stream>>>(codebook, chh, cll);
  cnorm_kernel<<<2048 / 4, 256, 0, stream>>>(codebook, cnorm);
  hipMemsetAsync(packed, 0xFF, (size_t)RM * 8, stream);
  dist_mfma<<<dim3(RM / 128, 2048 / 128), 256, 0, stream>>>(P2mh, P2ml, chh, cll, cnorm, packed);
  idx_out_kernel<<<RM / 256, 256, 0, stream>>>(packed, o_idx);

  // -------- skew-oblivious bucketed EMA update --------
  hipMemsetAsync(cnt, 0, 2048 * sizeof(int), stream);
  count_kernel<<<RM / 256, 256, 0, stream>>>(packed, cnt);
  scan_kernel<<<1, 256, 0, stream>>>(cnt, basebuf, cursor, ema_cs, nbuf);
  scatter_kernel<<<RM / 256, 256, 0, stream>>>(packed, cursor, bucket);
  quant_out_kernel<<<RM / 2, 256, 0, stream>>>(P2mh, P2ml, codebook, packed, o_ptf, lpart);
  loss_final_kernel<<<1, 256, 0, stream>>>(lpart, o_loss);
  hipMemsetAsync(dw, 0, (size_t)2048 * 512 * sizeof(float), stream);  // WT dead now
  dwsum_chunk_kernel<<<RM / 64, 256, 0, stream>>>(P2mh, P2ml, bucket, dw);
  cbnew_kernel<<<(2048 * 512) / 256, 256, 0, stream>>>(ema_w, dw, ema_cs, cnt, nbuf, o_cb);

  // -------- decoder --------
  linmix_kernel<34, 17><<<(Bn * 512) / 256, 256, 0, stream>>>(o_ptf, Cc, dtok_w, dtok_b, Bn, 512);
  small_gemm<0, 0><<<(RJ * 32) / 256, 256, 0, stream>>>(Cc, dstart_w, dstart_b, nullptr, dy, RJ, 512, 32);
  ln_kernel<1><<<RJ / 4, 256, 0, stream>>>(dy, dln, d_ln1g, d_ln1b, RJ, 32);
  tokenmix_kernel<<<(Bn * 32) / 256, 256, 0, stream>>>(dln, dy, dx2, d_tw1, d_tb1, d_tw2, d_tb2, Bn, 32);
  ln_kernel<1><<<RJ / 4, 256, 0, stream>>>(dx2, dln, d_ln2g, d_ln2b, RJ, 32);
  small_gemm<1, 0><<<(RJ * 64) / 256, 256, 0, stream>>>(dln, d_cw1, d_cb1, nullptr, dh, RJ, 32, 64);
  small_gemm<0, 1><<<(RJ * 32) / 256, 256, 0, stream>>>(dh, d_cw2, d_cb2, dx2, dy, RJ, 64, 32);
  ln_kernel<1><<<RJ / 4, 256, 0, stream>>>(dy, dln, dec_lng, dec_lnb, RJ, 32);
  small_gemm<0, 0><<<(RJ * 2) / 256, 256, 0, stream>>>(dln, rec_w, rec_b, nullptr, o_rec, RJ, 32, 2);
}

// Round 8
// 1627.434 us; speedup vs baseline: 3.4859x; 1.0644x over previous
//
#include <hip/hip_runtime.h>
#include <math.h>

// ---------------- problem constants ----------------
constexpr int Bn = 1024, Jn = 17, Mn = 34;
constexpr int RJ = Bn * Jn;                 // 17408
constexpr int RM = Bn * Mn;                 // 34816
constexpr size_t SZX = (size_t)RJ * 512;    // floats
constexpr size_t SZM = (size_t)RM * 512;    // floats

typedef __attribute__((ext_vector_type(8))) short bf16x8;
typedef __attribute__((ext_vector_type(4))) float f32x4;
typedef unsigned long long u64;
typedef unsigned short u16;
typedef unsigned int u32;

__device__ __forceinline__ float gelu_f(float x) {
  return 0.5f * x * (1.0f + erff(x * 0.7071067811865475f));
}
__device__ __forceinline__ u16 bf16_rne(float x) {
  u32 u = __float_as_uint(x);
  u += 0x7fffu + ((u >> 16) & 1u);
  return (u16)(u >> 16);
}
__device__ __forceinline__ float bf16_f(u16 h) {
  return __uint_as_float((u32)h << 16);
}

// async global->LDS, 16B per lane; LDS dest = wave-uniform base + lane*16
typedef __attribute__((address_space(1))) const void gas_t;
typedef __attribute__((address_space(3))) void las_t;
__device__ __forceinline__ void gll16(const void* g, void* l) {
  __builtin_amdgcn_global_load_lds((gas_t*)g, (las_t*)l, 16, 0, 0);
}

// ---------------- embed ----------------
__global__ __launch_bounds__(256) void embed_kernel(
    const float* __restrict__ joints, const float* __restrict__ inv,
    const float* __restrict__ sw, const float* __restrict__ sb,
    float* __restrict__ out) {
  int tid = blockIdx.x * 256 + threadIdx.x;
  int row = tid >> 9, d = tid & 511;
  float j0 = joints[row * 3 + 0];
  float j1 = joints[row * 3 + 1];
  float j2 = joints[row * 3 + 2];
  float x = fmaf(j0, sw[d], fmaf(j1, sw[512 + d], sb[d]));
  float v = (j2 != 0.0f) ? 1.0f : 0.0f;
  out[tid] = x * v + inv[d] * (1.0f - v);
}

// ---------------- fused mixer prefix: LN1(stats) + tokenmix + residual + LN2(hi/lo) ----------------
__global__ __launch_bounds__(256) void mixer_fused(
    const float* __restrict__ x_in, float* __restrict__ res_out,
    u16* __restrict__ oh, u16* __restrict__ ol,
    const float* __restrict__ g1, const float* __restrict__ b1,
    const float* __restrict__ tw1, const float* __restrict__ tb1,
    const float* __restrict__ tw2, const float* __restrict__ tb2,
    const float* __restrict__ g2, const float* __restrict__ b2) {
  __shared__ float xs[17][512];
  __shared__ float sw1[17 * 64], sw2[64 * 17], sb1v[64], sb2v[17];
  __shared__ float stats[17][2];
  const int tid = threadIdx.x;
  const int b = blockIdx.x;
  for (int i = tid; i < 17 * 64; i += 256) { sw1[i] = tw1[i]; sw2[i] = tw2[i]; }
  if (tid < 64) sb1v[tid] = tb1[tid];
  if (tid < 17) sb2v[tid] = tb2[tid];
  const float* px = x_in + (size_t)b * 17 * 512;
  for (int i = tid; i < 17 * 512; i += 256) xs[i >> 9][i & 511] = px[i];
  __syncthreads();
  const int wv = tid >> 6, ln_ = tid & 63;
  // phase A: LN1 stats only
  for (int j = wv; j < 17; j += 4) {
    float v[8];
    float s = 0.0f;
#pragma unroll
    for (int i = 0; i < 8; i++) { v[i] = xs[j][ln_ + 64 * i]; s += v[i]; }
#pragma unroll
    for (int m = 32; m; m >>= 1) s += __shfl_xor(s, m);
    float mean = s * (1.0f / 512.0f);
    float s2 = 0.0f;
#pragma unroll
    for (int i = 0; i < 8; i++) { float t = v[i] - mean; s2 += t * t; }
#pragma unroll
    for (int m = 32; m; m >>= 1) s2 += __shfl_xor(s2, m);
    float rs = 1.0f / sqrtf(s2 * (1.0f / 512.0f) + 1e-5f);
    if (ln_ == 0) { stats[j][0] = mean; stats[j][1] = rs; }
  }
  __syncthreads();
  // phase B: column threads apply LN1 inline, tokenmix, residual in place
  for (int cc = 0; cc < 2; cc++) {
    int d = tid + cc * 256;
    float gd = g1[d], bd = b1[d];
    float t[17], acc[17];
#pragma unroll
    for (int j = 0; j < 17; j++) {
      t[j] = (xs[j][d] - stats[j][0]) * stats[j][1] * gd + bd;
      acc[j] = 0.0f;
    }
    for (int k = 0; k < 64; k++) {
      float h = sb1v[k];
#pragma unroll
      for (int j = 0; j < 17; j++) h = fmaf(t[j], sw1[j * 64 + k], h);
      h = gelu_f(h);
#pragma unroll
      for (int j = 0; j < 17; j++) acc[j] = fmaf(h, sw2[k * 17 + j], acc[j]);
    }
#pragma unroll
    for (int j = 0; j < 17; j++) {
      float r = xs[j][d] + acc[j] + sb2v[j];
      xs[j][d] = r;
      res_out[((size_t)b * 17 + j) * 512 + d] = r;
    }
  }
  __syncthreads();
  // phase C: LN2 rows -> hi/lo
  for (int j = wv; j < 17; j += 4) {
    float v[8];
    float s = 0.0f;
#pragma unroll
    for (int i = 0; i < 8; i++) { v[i] = xs[j][ln_ + 64 * i]; s += v[i]; }
#pragma unroll
    for (int m = 32; m; m >>= 1) s += __shfl_xor(s, m);
    float mean = s * (1.0f / 512.0f);
    float s2 = 0.0f;
#pragma unroll
    for (int i = 0; i < 8; i++) { float t = v[i] - mean; s2 += t * t; }
#pragma unroll
    for (int m = 32; m; m >>= 1) s2 += __shfl_xor(s2, m);
    float rs = 1.0f / sqrtf(s2 * (1.0f / 512.0f) + 1e-5f);
#pragma unroll
    for (int i = 0; i < 8; i++) {
      int d = ln_ + 64 * i;
      float o = (v[i] - mean) * rs * g2[d] + b2[d];
      u16 h = bf16_rne(o);
      size_t off = ((size_t)b * 17 + j) * 512 + d;
      oh[off] = h;
      ol[off] = bf16_rne(o - bf16_f(h));
    }
  }
}

// ---------------- fused enc_ln + token linmix (17->34), hi/lo out ----------------
__global__ __launch_bounds__(256) void lnmix_fused(
    const float* __restrict__ x_in, u16* __restrict__ oh, u16* __restrict__ ol,
    const float* __restrict__ g, const float* __restrict__ bb,
    const float* __restrict__ w, const float* __restrict__ bias) {
  __shared__ float xs[17][513];
  __shared__ float sw[17 * 34], sb[34];
  const int tid = threadIdx.x;
  const int b = blockIdx.x;
  for (int i = tid; i < 17 * 34; i += 256) sw[i] = w[i];
  if (tid < 34) sb[tid] = bias[tid];
  const float* px = x_in + (size_t)b * 17 * 512;
  for (int i = tid; i < 17 * 512; i += 256) xs[i >> 9][i & 511] = px[i];
  __syncthreads();
  const int wv = tid >> 6, ln_ = tid & 63;
  for (int j = wv; j < 17; j += 4) {
    float v[8];
    float s = 0.0f;
#pragma unroll
    for (int i = 0; i < 8; i++) { v[i] = xs[j][ln_ + 64 * i]; s += v[i]; }
#pragma unroll
    for (int m = 32; m; m >>= 1) s += __shfl_xor(s, m);
    float mean = s * (1.0f / 512.0f);
    float s2 = 0.0f;
#pragma unroll
    for (int i = 0; i < 8; i++) { float t = v[i] - mean; s2 += t * t; }
#pragma unroll
    for (int m = 32; m; m >>= 1) s2 += __shfl_xor(s2, m);
    float rs = 1.0f / sqrtf(s2 * (1.0f / 512.0f) + 1e-5f);
#pragma unroll
    for (int i = 0; i < 8; i++) {
      int d = ln_ + 64 * i;
      xs[j][d] = (v[i] - mean) * rs * g[d] + bb[d];
    }
  }
  __syncthreads();
  for (int cc = 0; cc < 2; cc++) {
    int d = tid + cc * 256;
    float t[17];
#pragma unroll
    for (int j = 0; j < 17; j++) t[j] = xs[j][d];
#pragma unroll
    for (int m = 0; m < 34; m++) {
      float s = sb[m];
#pragma unroll
      for (int j = 0; j < 17; j++) s = fmaf(t[j], sw[j * 34 + m], s);
      size_t o = ((size_t)b * 34 + m) * 512 + d;
      u16 h = bf16_rne(s);
      oh[o] = h;
      ol[o] = bf16_rne(s - bf16_f(h));
    }
  }
}

// ---------------- weight transpose+split ----------------
__global__ __launch_bounds__(256) void prep2_wT(
    const float* __restrict__ W1, const float* __restrict__ W2,
    u16* __restrict__ Th1, u16* __restrict__ Tl1,
    u16* __restrict__ Th2, u16* __restrict__ Tl2) {
  int tid = blockIdx.x * 256 + threadIdx.x;
  const float* W = (tid < 262144) ? W1 : W2;
  u16* Th = (tid < 262144) ? Th1 : Th2;
  u16* Tl = (tid < 262144) ? Tl1 : Tl2;
  int t = tid & 262143;
  int k = t >> 9, n = t & 511;
  float v = W[t];
  u16 h = bf16_rne(v);
  Th[(size_t)n * 512 + k] = h;
  Tl[(size_t)n * 512 + k] = bf16_rne(v - bf16_f(h));
}

__global__ __launch_bounds__(256) void prep_wT(
    const float* __restrict__ W, u16* __restrict__ Th, u16* __restrict__ Tl) {
  int tid = blockIdx.x * 256 + threadIdx.x;
  int k = tid >> 9, n = tid & 511;
  float v = W[tid];
  u16 h = bf16_rne(v);
  Th[(size_t)n * 512 + k] = h;
  Tl[(size_t)n * 512 + k] = bf16_rne(v - bf16_f(h));
}

// ---------------- fused codebook split + L2 norms: wave per entry ----------------
__global__ __launch_bounds__(256) void splitnorm_kernel(
    const float* __restrict__ CBm, u16* __restrict__ hi, u16* __restrict__ lo,
    float* __restrict__ cnorm) {
  int wave = threadIdx.x >> 6, lane = threadIdx.x & 63;
  int k = blockIdx.x * 4 + wave;
  const float4* p4 = (const float4*)(CBm + (size_t)k * 512);
  ushort4* h4 = (ushort4*)(hi + (size_t)k * 512);
  ushort4* l4 = (ushort4*)(lo + (size_t)k * 512);
  float s = 0.0f;
#pragma unroll
  for (int i = 0; i < 2; i++) {
    float4 x = p4[lane + 64 * i];
    ushort4 h, l;
    h.x = bf16_rne(x.x); l.x = bf16_rne(x.x - bf16_f(h.x));
    h.y = bf16_rne(x.y); l.y = bf16_rne(x.y - bf16_f(h.y));
    h.z = bf16_rne(x.z); l.z = bf16_rne(x.z - bf16_f(h.z));
    h.w = bf16_rne(x.w); l.w = bf16_rne(x.w - bf16_f(h.w));
    h4[lane + 64 * i] = h;
    l4[lane + 64 * i] = l;
    s = fmaf(x.x, x.x, s); s = fmaf(x.y, x.y, s);
    s = fmaf(x.z, x.z, s); s = fmaf(x.w, x.w, s);
  }
#pragma unroll
  for (int m = 32; m; m >>= 1) s += __shfl_xor(s, m);
  if (lane == 0) cnorm[k] = s;
}

// ======== shared staging/compute macros for the MFMA GEMMs ========
#define MG_PROLOGUE()                                                        \
  const int tid = threadIdx.x;                                               \
  const int m0 = blockIdx.x * 128, n0 = blockIdx.y * 128;                    \
  const int lane = tid & 63, wave = tid >> 6;                                \
  const int wm = wave >> 1, wn = wave & 1;                                   \
  const int fr = lane & 15, q = lane >> 4, qd = q;                           \
  const int ci0 = wave * 128 + lane, ci1 = ci0 + 64;                         \
  const int r0 = ci0 >> 2, c0x = (ci0 & 3) ^ ((r0 >> 1) & 3);                \
  const int r1 = ci1 >> 2, c1x = (ci1 & 3) ^ ((r1 >> 1) & 3);                \
  const size_t aoff0 = (size_t)(m0 + r0) * 512 + c0x * 8;                    \
  const size_t aoff1 = (size_t)(m0 + r1) * 512 + c1x * 8;                    \
  const size_t boff0 = (size_t)(n0 + r0) * 512 + c0x * 8;                    \
  const size_t boff1 = (size_t)(n0 + r1) * 512 + c1x * 8;                    \
  const int ld0 = wave * 1024, ld1 = ld0 + 512; /* u16 index of dest */      \
  int fca[4], fcb[4];                                                        \
  _Pragma("unroll") for (int t4 = 0; t4 < 4; t4++) {                         \
    int rra = wm * 64 + t4 * 16 + fr;                                        \
    int rrb = wn * 64 + t4 * 16 + fr;                                        \
    int sz = q ^ ((fr >> 1) & 3);                                            \
    fca[t4] = (rra * 4 + sz) * 8;                                            \
    fcb[t4] = (rrb * 4 + sz) * 8;                                            \
  }                                                                          \
  f32x4 acc[4][4];                                                           \
  _Pragma("unroll") for (int i = 0; i < 4; i++)                              \
    _Pragma("unroll") for (int j = 0; j < 4; j++) {                          \
      acc[i][j][0] = 0.0f; acc[i][j][1] = 0.0f;                              \
      acc[i][j][2] = 0.0f; acc[i][j][3] = 0.0f;                              \
    }

#define MG_KLOOP(Ah, Al, Bh, Bl)                                             \
  for (int k0 = 0; k0 < 512; k0 += 32) {                                     \
    gll16(Ah + aoff0 + k0, &sAh[ld0]);                                       \
    gll16(Ah + aoff1 + k0, &sAh[ld1]);                                       \
    gll16(Al + aoff0 + k0, &sAl[ld0]);                                       \
    gll16(Al + aoff1 + k0, &sAl[ld1]);                                       \
    gll16(Bh + boff0 + k0, &sBh[ld0]);                                       \
    gll16(Bh + boff1 + k0, &sBh[ld1]);                                       \
    gll16(Bl + boff0 + k0, &sBl[ld0]);                                       \
    gll16(Bl + boff1 + k0, &sBl[ld1]);                                       \
    __syncthreads();                                                         \
    bf16x8 fah[4], fal[4], fbh[4], fbl[4];                                   \
    _Pragma("unroll") for (int t4 = 0; t4 < 4; t4++) {                       \
      fah[t4] = *(const bf16x8*)&sAh[fca[t4]];                               \
      fal[t4] = *(const bf16x8*)&sAl[fca[t4]];                               \
      fbh[t4] = *(const bf16x8*)&sBh[fcb[t4]];                               \
      fbl[t4] = *(const bf16x8*)&sBl[fcb[t4]];                               \
    }                                                                        \
    _Pragma("unroll") for (int mt = 0; mt < 4; mt++)                         \
      _Pragma("unroll") for (int nt = 0; nt < 4; nt++) {                     \
        acc[mt][nt] = __builtin_amdgcn_mfma_f32_16x16x32_bf16(               \
            fah[mt], fbh[nt], acc[mt][nt], 0, 0, 0);                         \
        acc[mt][nt] = __builtin_amdgcn_mfma_f32_16x16x32_bf16(               \
            fah[mt], fbl[nt], acc[mt][nt], 0, 0, 0);                         \
        acc[mt][nt] = __builtin_amdgcn_mfma_f32_16x16x32_bf16(               \
            fal[mt], fbh[nt], acc[mt][nt], 0, 0, 0);                         \
      }                                                                      \
    __syncthreads();                                                         \
  }

// ---------------- split-bf16 MFMA GEMM: C = act(A@W^T + bias)(+R) ----------------
template <int GELU_FLAG, int RES_FLAG, int HILO_OUT>
__global__ __launch_bounds__(256, 4) void mgemm(
    const u16* __restrict__ Ah, const u16* __restrict__ Al,
    const u16* __restrict__ Bh, const u16* __restrict__ Bl,
    const float* __restrict__ bias, const float* __restrict__ R,
    float* __restrict__ C, u16* __restrict__ Oh, u16* __restrict__ Ol, int N) {
  __shared__ __align__(16) u16 sAh[4096], sAl[4096], sBh[4096], sBl[4096];
  MG_PROLOGUE()
  MG_KLOOP(Ah, Al, Bh, Bl)
#pragma unroll
  for (int mt = 0; mt < 4; mt++)
#pragma unroll
    for (int reg = 0; reg < 4; reg++) {
      int row = m0 + wm * 64 + mt * 16 + qd * 4 + reg;
#pragma unroll
      for (int nt = 0; nt < 4; nt++) {
        int col = n0 + wn * 64 + nt * 16 + fr;
        float v = acc[mt][nt][reg] + bias[col];
        if (GELU_FLAG) v = gelu_f(v);
        if (RES_FLAG) v += R[(size_t)row * N + col];
        if (HILO_OUT) {
          u16 h = bf16_rne(v);
          Oh[(size_t)row * N + col] = h;
          Ol[(size_t)row * N + col] = bf16_rne(v - bf16_f(h));
        } else {
          C[(size_t)row * N + col] = v;
        }
      }
    }
}

// ---------------- distance GEMM + packed-u64 argmin ----------------
__global__ __launch_bounds__(256, 4) void dist_mfma(
    const u16* __restrict__ Ah, const u16* __restrict__ Al,
    const u16* __restrict__ Bh, const u16* __restrict__ Bl,
    const float* __restrict__ cnorm, u64* __restrict__ packed) {
  __shared__ __align__(16) u16 sAh[4096], sAl[4096], sBh[4096], sBl[4096];
  MG_PROLOGUE()
  MG_KLOOP(Ah, Al, Bh, Bl)
#pragma unroll
  for (int mt = 0; mt < 4; mt++)
#pragma unroll
    for (int reg = 0; reg < 4; reg++) {
      u64 best = ~0ull;
#pragma unroll
      for (int nt = 0; nt < 4; nt++) {
        int c = n0 + wn * 64 + nt * 16 + fr;
        float d = cnorm[c] - 2.0f * acc[mt][nt][reg];
        u32 ub = __float_as_uint(d);
        ub = (ub & 0x80000000u) ? ~ub : (ub | 0x80000000u);
        u64 p = ((u64)ub << 32) | (u32)c;
        best = (p < best) ? p : best;
      }
#pragma unroll
      for (int mm = 1; mm <= 8; mm <<= 1) {
        u32 h2 = __shfl_xor((u32)(best >> 32), mm);
        u32 l2 = __shfl_xor((u32)best, mm);
        u64 o = ((u64)h2 << 32) | l2;
        best = (o < best) ? o : best;
      }
      if (fr == 0) {
        int row = m0 + wm * 64 + mt * 16 + qd * 4 + reg;
        atomicMin(&packed[row], best);
      }
    }
}

// ---------------- idx output + skew-oblivious count (fused) ----------------
__global__ __launch_bounds__(256) void idxcount_kernel(
    const u64* __restrict__ packed, float* __restrict__ o_idx,
    int* __restrict__ cnt) {
  __shared__ int h[2048];
  for (int i = threadIdx.x; i < 2048; i += 256) h[i] = 0;
  __syncthreads();
  int r = blockIdx.x * 256 + threadIdx.x;
  u32 k = (u32)packed[r];
  o_idx[r] = (float)k;
  atomicAdd(&h[k], 1);
  __syncthreads();
  for (int i = threadIdx.x; i < 2048; i += 256) {
    int v = h[i];
    if (v) atomicAdd(&cnt[i], v);
  }
}

__global__ __launch_bounds__(256) void scan_kernel(
    const int* __restrict__ cnt, int* __restrict__ base,
    int* __restrict__ cursor, const float* __restrict__ ema_cs,
    float* __restrict__ nbuf) {
  __shared__ int part[256];
  __shared__ float esum[256];
  int t = threadIdx.x;
  int local[8];
  int s = 0;
  float es = 0.0f;
#pragma unroll
  for (int i = 0; i < 8; i++) {
    local[i] = cnt[t * 8 + i];
    s += local[i];
    es += ema_cs[t * 8 + i];
  }
  part[t] = s;
  esum[t] = es;
  __syncthreads();
  for (int off = 1; off < 256; off <<= 1) {
    int v = (t >= off) ? part[t - off] : 0;
    __syncthreads();
    part[t] += v;
    __syncthreads();
  }
  int run = part[t] - s;
#pragma unroll
  for (int i = 0; i < 8; i++) {
    base[t * 8 + i] = run;
    cursor[t * 8 + i] = run;
    run += local[i];
  }
  for (int o = 128; o; o >>= 1) {
    if (t < o) esum[t] += esum[t + o];
    __syncthreads();
  }
  if (t == 0) nbuf[0] = 0.9f * esum[0] + 0.1f * (float)RM;
}

__global__ __launch_bounds__(256) void scatter_kernel(
    const u64* __restrict__ packed, int* __restrict__ cursor,
    u32* __restrict__ bucket) {
  __shared__ int h[2048];
  __shared__ int gb[2048];
  for (int i = threadIdx.x; i < 2048; i += 256) h[i] = 0;
  __syncthreads();
  int r = blockIdx.x * 256 + threadIdx.x;
  int k = (int)(u32)packed[r];
  int lrank = atomicAdd(&h[k], 1);
  __syncthreads();
  for (int i = threadIdx.x; i < 2048; i += 256) {
    int v = h[i];
    gb[i] = v ? atomicAdd(&cursor[i], v) : 0;
  }
  __syncthreads();
  bucket[gb[k] + lrank] = ((u32)k << 17) | (u32)r;
}

// ---------------- quant gather + loss partials; f = fh+fl ----------------
__global__ __launch_bounds__(256) void quant_out_kernel(
    const u16* __restrict__ fh, const u16* __restrict__ fl,
    const float* __restrict__ CBm, const u64* __restrict__ packed,
    float* __restrict__ ptf_out, float* __restrict__ lpart) {
  __shared__ float wred[4];
  int row = blockIdx.x * 2 + (threadIdx.x >> 7);
  int t = threadIdx.x & 127;
  int k = (int)(u32)packed[row];
  uint2 hb = ((const uint2*)(fh + (size_t)row * 512))[t];
  uint2 lb = ((const uint2*)(fl + (size_t)row * 512))[t];
  float f0 = bf16_f((u16)hb.x) + bf16_f((u16)lb.x);
  float f1 = bf16_f((u16)(hb.x >> 16)) + bf16_f((u16)(lb.x >> 16));
  float f2 = bf16_f((u16)hb.y) + bf16_f((u16)lb.y);
  float f3 = bf16_f((u16)(hb.y >> 16)) + bf16_f((u16)(lb.y >> 16));
  float4 c = ((const float4*)(CBm + (size_t)k * 512))[t];
  float* po = ptf_out + (size_t)row * 512 + 4 * t;
  po[0] = c.x; po[1] = c.y; po[2] = c.z; po[3] = c.w;
  float dx = c.x - f0, dy = c.y - f1, dz = c.z - f2, dwv = c.w - f3;
  float ls = dx * dx + dy * dy + dz * dz + dwv * dwv;
#pragma unroll
  for (int m = 32; m; m >>= 1) ls += __shfl_xor(ls, m);
  if ((threadIdx.x & 63) == 0) wred[threadIdx.x >> 6] = ls;
  __syncthreads();
  if (threadIdx.x == 0)
    lpart[blockIdx.x] = wred[0] + wred[1] + wred[2] + wred[3];
}

__global__ __launch_bounds__(256) void loss_final_kernel(
    const float* __restrict__ lpart, float* __restrict__ loss_out) {
  __shared__ float red[256];
  float s = 0.0f;
  for (int i = threadIdx.x; i < RM / 2; i += 256) s += lpart[i];
  red[threadIdx.x] = s;
  __syncthreads();
  for (int o = 128; o; o >>= 1) {
    if (threadIdx.x < o) red[threadIdx.x] += red[threadIdx.x + o];
    __syncthreads();
  }
  if (threadIdx.x == 0)
    loss_out[0] = red[0] / (float)((size_t)RM * 512);
}

// ---------------- skew-oblivious dw from bucket chunks ----------------
__global__ __launch_bounds__(256) void dwsum_chunk_kernel(
    const u16* __restrict__ fh, const u16* __restrict__ fl,
    const u32* __restrict__ bucket, float* __restrict__ dw) {
  __shared__ u32 sp[64];
  const int t = threadIdx.x;
  if (t < 64) sp[t] = bucket[blockIdx.x * 64 + t];
  __syncthreads();
  float ax = 0.0f, ay = 0.0f;
  int curk = (int)(sp[0] >> 17);
  u32 hb = *(const u32*)(fh + (size_t)(sp[0] & 0x1FFFF) * 512 + 2 * t);
  u32 lb = *(const u32*)(fl + (size_t)(sp[0] & 0x1FFFF) * 512 + 2 * t);
  for (int i = 0; i < 64; i++) {
    u32 hn = 0, ln2 = 0;
    if (i + 1 < 64) {
      hn = *(const u32*)(fh + (size_t)(sp[i + 1] & 0x1FFFF) * 512 + 2 * t);
      ln2 = *(const u32*)(fl + (size_t)(sp[i + 1] & 0x1FFFF) * 512 + 2 * t);
    }
    int k = (int)(sp[i] >> 17);
    if (k != curk) {
      atomicAdd(&dw[(size_t)curk * 512 + 2 * t], ax);
      atomicAdd(&dw[(size_t)curk * 512 + 2 * t + 1], ay);
      ax = 0.0f; ay = 0.0f; curk = k;
    }
    ax += bf16_f((u16)hb) + bf16_f((u16)lb);
    ay += bf16_f((u16)(hb >> 16)) + bf16_f((u16)(lb >> 16));
    hb = hn; lb = ln2;
  }
  atomicAdd(&dw[(size_t)curk * 512 + 2 * t], ax);
  atomicAdd(&dw[(size_t)curk * 512 + 2 * t + 1], ay);
}

// ---------------- codebook_new finalize ----------------
__global__ __launch_bounds__(256) void cbnew_kernel(
    const float* __restrict__ ema_w, const float* __restrict__ dw,
    const float* __restrict__ ema_cs, const int* __restrict__ cnt,
    const float* __restrict__ nbuf, float* __restrict__ outp) {
  int tid = blockIdx.x * 256 + threadIdx.x;
  int k = tid >> 9;
  float n = nbuf[0];
  float cs = ema_cs[k] * 0.9f + 0.1f * (float)cnt[k];
  cs = (cs + 1e-5f) / (n + 0.02048f) * n;
  outp[tid] = (ema_w[tid] * 0.9f + 0.1f * dw[tid]) / cs;
}

// ---------------- fully fused decoder: one block per pose ----------------
// 544 (joint,dim) pairs covered by three segments: tid, tid+256, tid+512(<544 => tid<32)
__global__ __launch_bounds__(256) void decoder_fused(
    const float* __restrict__ ptf,
    const float* __restrict__ dtokw, const float* __restrict__ dtokb,
    const float* __restrict__ dsw, const float* __restrict__ dsb,
    const float* __restrict__ ln1g, const float* __restrict__ ln1b,
    const float* __restrict__ tw1, const float* __restrict__ tb1,
    const float* __restrict__ tw2, const float* __restrict__ tb2,
    const float* __restrict__ ln2g, const float* __restrict__ ln2b,
    const float* __restrict__ cw1, const float* __restrict__ cb1,
    const float* __restrict__ cw2, const float* __restrict__ cb2,
    const float* __restrict__ lng, const float* __restrict__ lnb,
    const float* __restrict__ recw, const float* __restrict__ recb,
    float* __restrict__ o_rec) {
  __shared__ float buf[34 * 257];   // ptf chunk [34][257]; reused as W chunk [256][33]
  __shared__ float yS[17][257];
  __shared__ float zS[17][33];
  __shared__ float t2S[17][33];
  __shared__ float hS[17][65];
  __shared__ float sdw[34 * 17];
  __shared__ float stw1[17 * 64], stw2[64 * 17];
  const int tid = threadIdx.x;
  const int b = blockIdx.x;
  for (int i = tid; i < 34 * 17; i += 256) sdw[i] = dtokw[i];
  for (int i = tid; i < 17 * 64; i += 256) { stw1[i] = tw1[i]; stw2[i] = tw2[i]; }
  float zacc0 = 0.0f, zacc1 = 0.0f, zacc2 = 0.0f;
  const int j0 = tid >> 5, dd0 = tid & 31;          // pairs 0..255
  const int p1 = tid + 256;
  const int j1 = p1 >> 5, dd1 = p1 & 31;            // pairs 256..511 (always valid)
  const int p2 = tid + 512;
  const int j2 = p2 >> 5, dd2 = p2 & 31;            // pairs 512..543, valid iff tid<32
  for (int ch = 0; ch < 2; ch++) {
    // load ptf chunk [34][256]
    for (int m = 0; m < 34; m++)
      buf[m * 257 + tid] = ptf[((size_t)b * 34 + m) * 512 + ch * 256 + tid];
    __syncthreads();
    // y[j][d] = sum_m ptf[m][d]*dtokw[m][j] + dtokb[j]
#pragma unroll 1
    for (int j = 0; j < 17; j++) {
      float s = dtokb[j];
#pragma unroll
      for (int m = 0; m < 34; m++) s = fmaf(buf[m * 257 + tid], sdw[m * 17 + j], s);
      yS[j][tid] = s;
    }
    __syncthreads();
    // reuse buf for dstart_w chunk [256][33-strided]
    for (int i = tid; i < 256 * 32; i += 256) {
      int d = i >> 5, dd = i & 31;
      buf[d * 33 + dd] = dsw[(size_t)(ch * 256 + d) * 32 + dd];
    }
    __syncthreads();
    // z partials (all three segments)
    {
      float s = 0.0f;
      for (int d = 0; d < 256; d++) s = fmaf(yS[j0][d], buf[d * 33 + dd0], s);
      zacc0 += s;
      float s1 = 0.0f;
      for (int d = 0; d < 256; d++) s1 = fmaf(yS[j1][d], buf[d * 33 + dd1], s1);
      zacc1 += s1;
      if (tid < 32) {
        float s2 = 0.0f;
        for (int d = 0; d < 256; d++) s2 = fmaf(yS[j2][d], buf[d * 33 + dd2], s2);
        zacc2 += s2;
      }
    }
    __syncthreads();
  }
  zS[j0][dd0] = zacc0 + dsb[dd0];
  zS[j1][dd1] = zacc1 + dsb[dd1];
  if (tid < 32) zS[j2][dd2] = zacc2 + dsb[dd2];
  __syncthreads();
  // mixer LN1 (serial per row, threads 0..16)
  if (tid < 17) {
    float m = 0.0f;
#pragma unroll
    for (int d = 0; d < 32; d++) m += zS[tid][d];
    m *= (1.0f / 32.0f);
    float v = 0.0f;
#pragma unroll
    for (int d = 0; d < 32; d++) { float t = zS[tid][d] - m; v += t * t; }
    float rs = 1.0f / sqrtf(v * (1.0f / 32.0f) + 1e-5f);
#pragma unroll
    for (int d = 0; d < 32; d++)
      t2S[tid][d] = (zS[tid][d] - m) * rs * ln1g[d] + ln1b[d];
  }
  __syncthreads();
  // tokenmix over joints (threads 0..31 = column d)
  if (tid < 32) {
    float t[17], acc[17];
#pragma unroll
    for (int j = 0; j < 17; j++) { t[j] = t2S[j][tid]; acc[j] = 0.0f; }
    for (int k = 0; k < 64; k++) {
      float h = tb1[k];
#pragma unroll
      for (int j = 0; j < 17; j++) h = fmaf(t[j], stw1[j * 64 + k], h);
      h = gelu_f(h);
#pragma unroll
      for (int j = 0; j < 17; j++) acc[j] = fmaf(h, stw2[k * 17 + j], acc[j]);
    }
#pragma unroll
    for (int j = 0; j < 17; j++) zS[j][tid] = zS[j][tid] + acc[j] + tb2[j];
  }
  __syncthreads();
  // LN2
  if (tid < 17) {
    float m = 0.0f;
#pragma unroll
    for (int d = 0; d < 32; d++) m += zS[tid][d];
    m *= (1.0f / 32.0f);
    float v = 0.0f;
#pragma unroll
    for (int d = 0; d < 32; d++) { float t = zS[tid][d] - m; v += t * t; }
    float rs = 1.0f / sqrtf(v * (1.0f / 32.0f) + 1e-5f);
#pragma unroll
    for (int d = 0; d < 32; d++)
      t2S[tid][d] = (zS[tid][d] - m) * rs * ln2g[d] + ln2b[d];
  }
  __syncthreads();
  // channel MLP hidden (17*64 outputs)
  for (int p = tid; p < 17 * 64; p += 256) {
    int j = p >> 6, k = p & 63;
    float s = cb1[k];
#pragma unroll
    for (int d = 0; d < 32; d++) s = fmaf(t2S[j][d], cw1[d * 64 + k], s);
    hS[j][k] = gelu_f(s);
  }
  __syncthreads();
  // channel MLP out + residual (all three segments)
  {
    float s = cb2[dd0];
#pragma unroll
    for (int k = 0; k < 64; k++) s = fmaf(hS[j0][k], cw2[k * 32 + dd0], s);
    zS[j0][dd0] += s;
    float s1 = cb2[dd1];
#pragma unroll
    for (int k = 0; k < 64; k++) s1 = fmaf(hS[j1][k], cw2[k * 32 + dd1], s1);
    zS[j1][dd1] += s1;
    if (tid < 32) {
      float s2 = cb2[dd2];
#pragma unroll
      for (int k = 0; k < 64; k++) s2 = fmaf(hS[j2][k], cw2[k * 32 + dd2], s2);
      zS[j2][dd2] += s2;
    }
  }
  __syncthreads();
  // final LN
  if (tid < 17) {
    float m = 0.0f;
#pragma unroll
    for (int d = 0; d < 32; d++) m += zS[tid][d];
    m *= (1.0f / 32.0f);
    float v = 0.0f;
#pragma unroll
    for (int d = 0; d < 32; d++) { float t = zS[tid][d] - m; v += t * t; }
    float rs = 1.0f / sqrtf(v * (1.0f / 32.0f) + 1e-5f);
#pragma unroll
    for (int d = 0; d < 32; d++)
      t2S[tid][d] = (zS[tid][d] - m) * rs * lng[d] + lnb[d];
  }
  __syncthreads();
  // rec: 34 outputs
  if (tid < 34) {
    int j = tid >> 1, c = tid & 1;
    float s = recb[c];
#pragma unroll
    for (int d = 0; d < 32; d++) s = fmaf(t2S[j][d], recw[d * 2 + c], s);
    o_rec[((size_t)b * 17 + j) * 2 + c] = s;
  }
}

// ================================================================
extern "C" void kernel_launch(void* const* d_in, const int* in_sizes, int n_in,
                              void* d_out, int out_size, void* d_ws, size_t ws_size,
                              hipStream_t stream) {
  const float* joints   = (const float*)d_in[0];
  const float* inv_tok  = (const float*)d_in[3];
  const float* start_w  = (const float*)d_in[4];
  const float* start_b  = (const float*)d_in[5];
  const float* e_ln1g = (const float*)d_in[6];
  const float* e_ln1b = (const float*)d_in[7];
  const float* e_tw1  = (const float*)d_in[8];
  const float* e_tb1  = (const float*)d_in[9];
  const float* e_tw2  = (const float*)d_in[10];
  const float* e_tb2  = (const float*)d_in[11];
  const float* e_ln2g = (const float*)d_in[12];
  const float* e_ln2b = (const float*)d_in[13];
  const float* e_cw1  = (const float*)d_in[14];
  const float* e_cb1  = (const float*)d_in[15];
  const float* e_cw2  = (const float*)d_in[16];
  const float* e_cb2  = (const float*)d_in[17];
  const float* d_ln1g = (const float*)d_in[18];
  const float* d_ln1b = (const float*)d_in[19];
  const float* d_tw1  = (const float*)d_in[20];
  const float* d_tb1  = (const float*)d_in[21];
  const float* d_tw2  = (const float*)d_in[22];
  const float* d_tb2  = (const float*)d_in[23];
  const float* d_ln2g = (const float*)d_in[24];
  const float* d_ln2b = (const float*)d_in[25];
  const float* d_cw1  = (const float*)d_in[26];
  const float* d_cb1  = (const float*)d_in[27];
  const float* d_cw2  = (const float*)d_in[28];
  const float* d_cb2  = (const float*)d_in[29];
  const float* enc_lng = (const float*)d_in[30];
  const float* enc_lnb = (const float*)d_in[31];
  const float* tok_w   = (const float*)d_in[32];
  const float* tok_b   = (const float*)d_in[33];
  const float* feat_w  = (const float*)d_in[34];
  const float* feat_b  = (const float*)d_in[35];
  const float* codebook = (const float*)d_in[36];
  const float* ema_cs   = (const float*)d_in[37];
  const float* ema_w    = (const float*)d_in[38];
  const float* dtok_w   = (const float*)d_in[39];
  const float* dtok_b   = (const float*)d_in[40];
  const float* dstart_w = (const float*)d_in[41];
  const float* dstart_b = (const float*)d_in[42];
  const float* dec_lng  = (const float*)d_in[43];
  const float* dec_lnb  = (const float*)d_in[44];
  const float* rec_w    = (const float*)d_in[45];
  const float* rec_b    = (const float*)d_in[46];

  // -------- workspace layout (same proven footprint) --------
  float* ws = (float*)d_ws;
  float* Ab  = ws;                  // [RJ,512] fp32 residual
  float* Bb  = ws + SZX;            // [RJ,512] fp32 (x+y residual)
  float* Cc  = ws + 2 * SZX;        // scratch
  float* P1e = ws + 3 * SZX;        // RJ bf16 hi+lo (ln2 out)
  float* P2e = ws + 4 * SZX;        // RJ bf16 hi+lo (mgemm1 out)
  float* cbs = ws + 5 * SZX;        // codebook split hi+lo
  float* cnorm = cbs + 1048576;                      // 2048
  u64*  packed = (u64*)(cnorm + 2048);               // RM u64
  int*  cnt    = (int*)(cnorm + 2048 + 69632);       // 2048
  int*  basebuf = cnt + 2048;
  int*  cursor  = basebuf + 2048;
  u32*  bucket  = (u32*)(cursor + 2048);             // RM
  float* lpart  = (float*)(bucket + RM);             // RM/2
  float* nbuf   = lpart + RM / 2;                    // 1 (padded)
  float* dw     = nbuf + 2048;                       // 2048*512
  u16* WTh1 = (u16*)dw;
  u16* WTl1 = (u16*)(dw + 131072);
  u16* WTh2 = (u16*)(dw + 262144);
  u16* WTl2 = (u16*)(dw + 393216);
  u16* P1eh = (u16*)P1e;  u16* P1el = (u16*)(P1e + SZX / 2);
  u16* P2eh = (u16*)P2e;  u16* P2el = (u16*)(P2e + SZX / 2);
  u16* P1mh = (u16*)Ab;   u16* P1ml = (u16*)Bb;
  u16* P2mh = (u16*)Cc;   u16* P2ml = (u16*)P1e;
  u16* chh = (u16*)cbs;   u16* cll = (u16*)(cbs + 524288);

  // -------- outputs --------
  float* outp = (float*)d_out;
  float* o_rec = outp;
  float* o_idx = outp + (size_t)RJ * 2;
  float* o_loss = o_idx + RM;
  float* o_ptf = o_loss + 1;
  float* o_cb = o_ptf + SZM;

  // -------- encoder --------
  embed_kernel<<<(RJ * 512) / 256, 256, 0, stream>>>(joints, inv_tok, start_w, start_b, Ab);
  for (int i = 0; i < 4; i++) {
    prep2_wT<<<2048, 256, 0, stream>>>(
        e_cw1 + (size_t)i * 512 * 512, e_cw2 + (size_t)i * 512 * 512,
        WTh1, WTl1, WTh2, WTl2);
    mixer_fused<<<Bn, 256, 0, stream>>>(
        Ab, Bb, P1eh, P1el,
        e_ln1g + i * 512, e_ln1b + i * 512,
        e_tw1 + i * 17 * 64, e_tb1 + i * 64, e_tw2 + i * 64 * 17, e_tb2 + i * 17,
        e_ln2g + i * 512, e_ln2b + i * 512);
    mgemm<1, 0, 1><<<dim3(RJ / 128, 4), 256, 0, stream>>>(
        P1eh, P1el, WTh1, WTl1, e_cb1 + i * 512, nullptr, nullptr, P2eh, P2el, 512);
    mgemm<0, 1, 0><<<dim3(RJ / 128, 4), 256, 0, stream>>>(
        P2eh, P2el, WTh2, WTl2, e_cb2 + i * 512, Bb, Ab, nullptr, nullptr, 512);
  }
  lnmix_fused<<<Bn, 256, 0, stream>>>(Ab, P1mh, P1ml, enc_lng, enc_lnb, tok_w, tok_b);
  prep_wT<<<1024, 256, 0, stream>>>(feat_w, WTh1, WTl1);
  mgemm<0, 0, 1><<<dim3(RM / 128, 4), 256, 0, stream>>>(
      P1mh, P1ml, WTh1, WTl1, feat_b, nullptr, nullptr, P2mh, P2ml, 512);

  // -------- VQ: distances + argmin --------
  splitnorm_kernel<<<2048 / 4, 256, 0, stream>>>(codebook, chh, cll, cnorm);
  hipMemsetAsync(packed, 0xFF, (size_t)RM * 8, stream);
  dist_mfma<<<dim3(RM / 128, 2048 / 128), 256, 0, stream>>>(P2mh, P2ml, chh, cll, cnorm, packed);

  // -------- skew-oblivious bucketed EMA update --------
  hipMemsetAsync(cnt, 0, 2048 * sizeof(int), stream);
  idxcount_kernel<<<RM / 256, 256, 0, stream>>>(packed, o_idx, cnt);
  scan_kernel<<<1, 256, 0, stream>>>(cnt, basebuf, cursor, ema_cs, nbuf);
  scatter_kernel<<<RM / 256, 256, 0, stream>>>(packed, cursor, bucket);
  quant_out_kernel<<<RM / 2, 256, 0, stream>>>(P2mh, P2ml, codebook, packed, o_ptf, lpart);
  loss_final_kernel<<<1, 256, 0, stream>>>(lpart, o_loss);
  hipMemsetAsync(dw, 0, (size_t)2048 * 512 * sizeof(float), stream);  // WT dead now
  dwsum_chunk_kernel<<<RM / 64, 256, 0, stream>>>(P2mh, P2ml, bucket, dw);
  cbnew_kernel<<<(2048 * 512) / 256, 256, 0, stream>>>(ema_w, dw, ema_cs, cnt, nbuf, o_cb);

  // -------- decoder (single fused kernel) --------
  decoder_fused<<<Bn, 256, 0, stream>>>(
      o_ptf, dtok_w, dtok_b, dstart_w, dstart_b,
      d_ln1g, d_ln1b, d_tw1, d_tb1, d_tw2, d_tb2, d_ln2g, d_ln2b,
      d_cw1, d_cb1, d_cw2, d_cb2, dec_lng, dec_lnb, rec_w, rec_b, o_rec);
}

// Round 9
// 1616.158 us; speedup vs baseline: 3.5102x; 1.0070x over previous
//
#include <hip/hip_runtime.h>
#include <math.h>

// ---------------- problem constants ----------------
constexpr int Bn = 1024, Jn = 17, Mn = 34;
constexpr int RJ = Bn * Jn;                 // 17408
constexpr int RM = Bn * Mn;                 // 34816
constexpr size_t SZX = (size_t)RJ * 512;    // floats
constexpr size_t SZM = (size_t)RM * 512;    // floats

typedef __attribute__((ext_vector_type(8))) short bf16x8;
typedef __attribute__((ext_vector_type(4))) float f32x4;
typedef unsigned long long u64;
typedef unsigned short u16;
typedef unsigned int u32;

__device__ __forceinline__ float gelu_f(float x) {
  return 0.5f * x * (1.0f + erff(x * 0.7071067811865475f));
}
__device__ __forceinline__ u16 bf16_rne(float x) {
  u32 u = __float_as_uint(x);
  u += 0x7fffu + ((u >> 16) & 1u);
  return (u16)(u >> 16);
}
__device__ __forceinline__ float bf16_f(u16 h) {
  return __uint_as_float((u32)h << 16);
}

// async global->LDS, 16B per lane; LDS dest = wave-uniform base + lane*16
typedef __attribute__((address_space(1))) const void gas_t;
typedef __attribute__((address_space(3))) void las_t;
__device__ __forceinline__ void gll16(const void* g, void* l) {
  __builtin_amdgcn_global_load_lds((gas_t*)g, (las_t*)l, 16, 0, 0);
}

// ---------------- embed ----------------
__global__ __launch_bounds__(256) void embed_kernel(
    const float* __restrict__ joints, const float* __restrict__ inv,
    const float* __restrict__ sw, const float* __restrict__ sb,
    float* __restrict__ out) {
  int tid = blockIdx.x * 256 + threadIdx.x;
  int row = tid >> 9, d = tid & 511;
  float j0 = joints[row * 3 + 0];
  float j1 = joints[row * 3 + 1];
  float j2 = joints[row * 3 + 2];
  float x = fmaf(j0, sw[d], fmaf(j1, sw[512 + d], sb[d]));
  float v = (j2 != 0.0f) ? 1.0f : 0.0f;
  out[tid] = x * v + inv[d] * (1.0f - v);
}

// ---------------- fused mixer prefix + weight transpose/split for this layer ----------------
__global__ __launch_bounds__(256) void mixer_fused(
    const float* __restrict__ x_in, float* __restrict__ res_out,
    u16* __restrict__ oh, u16* __restrict__ ol,
    const float* __restrict__ g1, const float* __restrict__ b1,
    const float* __restrict__ tw1, const float* __restrict__ tb1,
    const float* __restrict__ tw2, const float* __restrict__ tb2,
    const float* __restrict__ g2, const float* __restrict__ b2,
    const float* __restrict__ W1, const float* __restrict__ W2,
    u16* __restrict__ Th1, u16* __restrict__ Tl1,
    u16* __restrict__ Th2, u16* __restrict__ Tl2) {
  __shared__ float xs[17][512];
  __shared__ float sw1[17 * 64], sw2[64 * 17], sb1v[64], sb2v[17];
  __shared__ float stats[17][2];
  const int tid = threadIdx.x;
  const int b = blockIdx.x;
  // weight prep: exactly one element of each weight per thread (1024*256 = 262144)
  {
    int gid = b * 256 + tid;
    int k = gid >> 9, n = gid & 511;
    float v = W1[gid];
    u16 h = bf16_rne(v);
    Th1[(size_t)n * 512 + k] = h;
    Tl1[(size_t)n * 512 + k] = bf16_rne(v - bf16_f(h));
    v = W2[gid];
    h = bf16_rne(v);
    Th2[(size_t)n * 512 + k] = h;
    Tl2[(size_t)n * 512 + k] = bf16_rne(v - bf16_f(h));
  }
  for (int i = tid; i < 17 * 64; i += 256) { sw1[i] = tw1[i]; sw2[i] = tw2[i]; }
  if (tid < 64) sb1v[tid] = tb1[tid];
  if (tid < 17) sb2v[tid] = tb2[tid];
  const float* px = x_in + (size_t)b * 17 * 512;
  for (int i = tid; i < 17 * 512; i += 256) xs[i >> 9][i & 511] = px[i];
  __syncthreads();
  const int wv = tid >> 6, ln_ = tid & 63;
  // phase A: LN1 stats only
  for (int j = wv; j < 17; j += 4) {
    float v[8];
    float s = 0.0f;
#pragma unroll
    for (int i = 0; i < 8; i++) { v[i] = xs[j][ln_ + 64 * i]; s += v[i]; }
#pragma unroll
    for (int m = 32; m; m >>= 1) s += __shfl_xor(s, m);
    float mean = s * (1.0f / 512.0f);
    float s2 = 0.0f;
#pragma unroll
    for (int i = 0; i < 8; i++) { float t = v[i] - mean; s2 += t * t; }
#pragma unroll
    for (int m = 32; m; m >>= 1) s2 += __shfl_xor(s2, m);
    float rs = 1.0f / sqrtf(s2 * (1.0f / 512.0f) + 1e-5f);
    if (ln_ == 0) { stats[j][0] = mean; stats[j][1] = rs; }
  }
  __syncthreads();
  // phase B: column threads apply LN1 inline, tokenmix, residual in place
  for (int cc = 0; cc < 2; cc++) {
    int d = tid + cc * 256;
    float gd = g1[d], bd = b1[d];
    float t[17], acc[17];
#pragma unroll
    for (int j = 0; j < 17; j++) {
      t[j] = (xs[j][d] - stats[j][0]) * stats[j][1] * gd + bd;
      acc[j] = 0.0f;
    }
    for (int k = 0; k < 64; k++) {
      float h = sb1v[k];
#pragma unroll
      for (int j = 0; j < 17; j++) h = fmaf(t[j], sw1[j * 64 + k], h);
      h = gelu_f(h);
#pragma unroll
      for (int j = 0; j < 17; j++) acc[j] = fmaf(h, sw2[k * 17 + j], acc[j]);
    }
#pragma unroll
    for (int j = 0; j < 17; j++) {
      float r = xs[j][d] + acc[j] + sb2v[j];
      xs[j][d] = r;
      res_out[((size_t)b * 17 + j) * 512 + d] = r;
    }
  }
  __syncthreads();
  // phase C: LN2 rows -> hi/lo
  for (int j = wv; j < 17; j += 4) {
    float v[8];
    float s = 0.0f;
#pragma unroll
    for (int i = 0; i < 8; i++) { v[i] = xs[j][ln_ + 64 * i]; s += v[i]; }
#pragma unroll
    for (int m = 32; m; m >>= 1) s += __shfl_xor(s, m);
    float mean = s * (1.0f / 512.0f);
    float s2 = 0.0f;
#pragma unroll
    for (int i = 0; i < 8; i++) { float t = v[i] - mean; s2 += t * t; }
#pragma unroll
    for (int m = 32; m; m >>= 1) s2 += __shfl_xor(s2, m);
    float rs = 1.0f / sqrtf(s2 * (1.0f / 512.0f) + 1e-5f);
#pragma unroll
    for (int i = 0; i < 8; i++) {
      int d = ln_ + 64 * i;
      float o = (v[i] - mean) * rs * g2[d] + b2[d];
      u16 h = bf16_rne(o);
      size_t off = ((size_t)b * 17 + j) * 512 + d;
      oh[off] = h;
      ol[off] = bf16_rne(o - bf16_f(h));
    }
  }
}

// ---------------- fused enc_ln + token linmix (17->34) + feat_w prep ----------------
__global__ __launch_bounds__(256) void lnmix_fused(
    const float* __restrict__ x_in, u16* __restrict__ oh, u16* __restrict__ ol,
    const float* __restrict__ g, const float* __restrict__ bb,
    const float* __restrict__ w, const float* __restrict__ bias,
    const float* __restrict__ Wf, u16* __restrict__ Thf, u16* __restrict__ Tlf) {
  __shared__ float xs[17][513];
  __shared__ float sw[17 * 34], sb[34];
  const int tid = threadIdx.x;
  const int b = blockIdx.x;
  {
    int gid = b * 256 + tid;
    int k = gid >> 9, n = gid & 511;
    float v = Wf[gid];
    u16 h = bf16_rne(v);
    Thf[(size_t)n * 512 + k] = h;
    Tlf[(size_t)n * 512 + k] = bf16_rne(v - bf16_f(h));
  }
  for (int i = tid; i < 17 * 34; i += 256) sw[i] = w[i];
  if (tid < 34) sb[tid] = bias[tid];
  const float* px = x_in + (size_t)b * 17 * 512;
  for (int i = tid; i < 17 * 512; i += 256) xs[i >> 9][i & 511] = px[i];
  __syncthreads();
  const int wv = tid >> 6, ln_ = tid & 63;
  for (int j = wv; j < 17; j += 4) {
    float v[8];
    float s = 0.0f;
#pragma unroll
    for (int i = 0; i < 8; i++) { v[i] = xs[j][ln_ + 64 * i]; s += v[i]; }
#pragma unroll
    for (int m = 32; m; m >>= 1) s += __shfl_xor(s, m);
    float mean = s * (1.0f / 512.0f);
    float s2 = 0.0f;
#pragma unroll
    for (int i = 0; i < 8; i++) { float t = v[i] - mean; s2 += t * t; }
#pragma unroll
    for (int m = 32; m; m >>= 1) s2 += __shfl_xor(s2, m);
    float rs = 1.0f / sqrtf(s2 * (1.0f / 512.0f) + 1e-5f);
#pragma unroll
    for (int i = 0; i < 8; i++) {
      int d = ln_ + 64 * i;
      xs[j][d] = (v[i] - mean) * rs * g[d] + bb[d];
    }
  }
  __syncthreads();
  for (int cc = 0; cc < 2; cc++) {
    int d = tid + cc * 256;
    float t[17];
#pragma unroll
    for (int j = 0; j < 17; j++) t[j] = xs[j][d];
#pragma unroll
    for (int m = 0; m < 34; m++) {
      float s = sb[m];
#pragma unroll
      for (int j = 0; j < 17; j++) s = fmaf(t[j], sw[j * 34 + m], s);
      size_t o = ((size_t)b * 34 + m) * 512 + d;
      u16 h = bf16_rne(s);
      oh[o] = h;
      ol[o] = bf16_rne(s - bf16_f(h));
    }
  }
}

// ---------------- fused codebook split + L2 norms + packed/cnt init ----------------
__global__ __launch_bounds__(256) void splitnorm_kernel(
    const float* __restrict__ CBm, u16* __restrict__ hi, u16* __restrict__ lo,
    float* __restrict__ cnorm, u64* __restrict__ packed, int* __restrict__ cnt) {
  int gid = blockIdx.x * 256 + threadIdx.x;   // 512*256 = 131072 threads
  for (int i = gid; i < RM; i += 131072) packed[i] = ~0ull;
  if (gid < 2048) cnt[gid] = 0;
  int wave = threadIdx.x >> 6, lane = threadIdx.x & 63;
  int k = blockIdx.x * 4 + wave;
  const float4* p4 = (const float4*)(CBm + (size_t)k * 512);
  ushort4* h4 = (ushort4*)(hi + (size_t)k * 512);
  ushort4* l4 = (ushort4*)(lo + (size_t)k * 512);
  float s = 0.0f;
#pragma unroll
  for (int i = 0; i < 2; i++) {
    float4 x = p4[lane + 64 * i];
    ushort4 h, l;
    h.x = bf16_rne(x.x); l.x = bf16_rne(x.x - bf16_f(h.x));
    h.y = bf16_rne(x.y); l.y = bf16_rne(x.y - bf16_f(h.y));
    h.z = bf16_rne(x.z); l.z = bf16_rne(x.z - bf16_f(h.z));
    h.w = bf16_rne(x.w); l.w = bf16_rne(x.w - bf16_f(h.w));
    h4[lane + 64 * i] = h;
    l4[lane + 64 * i] = l;
    s = fmaf(x.x, x.x, s); s = fmaf(x.y, x.y, s);
    s = fmaf(x.z, x.z, s); s = fmaf(x.w, x.w, s);
  }
#pragma unroll
  for (int m = 32; m; m >>= 1) s += __shfl_xor(s, m);
  if (lane == 0) cnorm[k] = s;
}

// ---------------- split-bf16 MFMA GEMM, 64x128 tile (4 waves of 32x64) ----------------
// Block tile: M=64, N=128. wave(wm=wave>>1 in M, wn=wave&1 in N): 32x64 = 2x4 16x16 tiles.
template <int GELU_FLAG, int RES_FLAG, int HILO_OUT>
__global__ __launch_bounds__(256, 4) void mgemm64(
    const u16* __restrict__ Ah, const u16* __restrict__ Al,
    const u16* __restrict__ Bh, const u16* __restrict__ Bl,
    const float* __restrict__ bias, const float* __restrict__ R,
    float* __restrict__ C, u16* __restrict__ Oh, u16* __restrict__ Ol, int N) {
  __shared__ __align__(16) u16 sAh[2048], sAl[2048], sBh[4096], sBl[4096];
  const int tid = threadIdx.x;
  const int m0 = blockIdx.x * 64, n0 = blockIdx.y * 128;
  const int lane = tid & 63, wave = tid >> 6;
  const int wm = wave >> 1, wn = wave & 1;
  const int fr = lane & 15, q = lane >> 4;
  // A staging: 256 chunks (64 rows x 4), one per thread: chunk = tid
  const int ra = tid >> 2, ca = (tid & 3) ^ ((ra >> 1) & 3);
  const size_t aoff = (size_t)(m0 + ra) * 512 + ca * 8;
  // B staging: 512 chunks (128 rows x 4), two per thread: tid and tid+256
  const int rb0 = tid >> 2, cb0 = (tid & 3) ^ ((rb0 >> 1) & 3);
  const int ci1 = tid + 256;
  const int rb1 = ci1 >> 2, cb1 = (ci1 & 3) ^ ((rb1 >> 1) & 3);
  const size_t boff0 = (size_t)(n0 + rb0) * 512 + cb0 * 8;
  const size_t boff1 = (size_t)(n0 + rb1) * 512 + cb1 * 8;
  const int ldA = wave * 512;            // u16 index (chunk wave*64 + lane)
  const int ldB0 = wave * 512, ldB1 = 2048 + wave * 512;
  // fragment chunk offsets (u16 index)
  int fca[2], fcb[4];
#pragma unroll
  for (int mt = 0; mt < 2; mt++) {
    int rra = wm * 32 + mt * 16 + fr;
    fca[mt] = (rra * 4 + (q ^ ((rra >> 1) & 3))) * 8;
  }
#pragma unroll
  for (int nt = 0; nt < 4; nt++) {
    int rrb = wn * 64 + nt * 16 + fr;
    fcb[nt] = (rrb * 4 + (q ^ ((rrb >> 1) & 3))) * 8;
  }
  f32x4 acc[2][4];
#pragma unroll
  for (int i = 0; i < 2; i++)
#pragma unroll
    for (int j = 0; j < 4; j++) {
      acc[i][j][0] = 0.0f; acc[i][j][1] = 0.0f;
      acc[i][j][2] = 0.0f; acc[i][j][3] = 0.0f;
    }
  for (int k0 = 0; k0 < 512; k0 += 32) {
    gll16(Ah + aoff + k0, &sAh[ldA]);
    gll16(Al + aoff + k0, &sAl[ldA]);
    gll16(Bh + boff0 + k0, &sBh[ldB0]);
    gll16(Bh + boff1 + k0, &sBh[ldB1]);
    gll16(Bl + boff0 + k0, &sBl[ldB0]);
    gll16(Bl + boff1 + k0, &sBl[ldB1]);
    __syncthreads();
    bf16x8 fah[2], fal[2], fbh[4], fbl[4];
#pragma unroll
    for (int mt = 0; mt < 2; mt++) {
      fah[mt] = *(const bf16x8*)&sAh[fca[mt]];
      fal[mt] = *(const bf16x8*)&sAl[fca[mt]];
    }
#pragma unroll
    for (int nt = 0; nt < 4; nt++) {
      fbh[nt] = *(const bf16x8*)&sBh[fcb[nt]];
      fbl[nt] = *(const bf16x8*)&sBl[fcb[nt]];
    }
#pragma unroll
    for (int mt = 0; mt < 2; mt++)
#pragma unroll
      for (int nt = 0; nt < 4; nt++) {
        acc[mt][nt] = __builtin_amdgcn_mfma_f32_16x16x32_bf16(
            fah[mt], fbh[nt], acc[mt][nt], 0, 0, 0);
        acc[mt][nt] = __builtin_amdgcn_mfma_f32_16x16x32_bf16(
            fah[mt], fbl[nt], acc[mt][nt], 0, 0, 0);
        acc[mt][nt] = __builtin_amdgcn_mfma_f32_16x16x32_bf16(
            fal[mt], fbh[nt], acc[mt][nt], 0, 0, 0);
      }
    __syncthreads();
  }
#pragma unroll
  for (int mt = 0; mt < 2; mt++)
#pragma unroll
    for (int reg = 0; reg < 4; reg++) {
      int row = m0 + wm * 32 + mt * 16 + q * 4 + reg;
#pragma unroll
      for (int nt = 0; nt < 4; nt++) {
        int col = n0 + wn * 64 + nt * 16 + fr;
        float v = acc[mt][nt][reg] + bias[col];
        if (GELU_FLAG) v = gelu_f(v);
        if (RES_FLAG) v += R[(size_t)row * N + col];
        if (HILO_OUT) {
          u16 h = bf16_rne(v);
          Oh[(size_t)row * N + col] = h;
          Ol[(size_t)row * N + col] = bf16_rne(v - bf16_f(h));
        } else {
          C[(size_t)row * N + col] = v;
        }
      }
    }
}

// ======== M=128 staging/compute macros (dist kernel, validated) ========
#define MG_PROLOGUE()                                                        \
  const int tid = threadIdx.x;                                               \
  const int m0 = blockIdx.x * 128, n0 = blockIdx.y * 128;                    \
  const int lane = tid & 63, wave = tid >> 6;                                \
  const int wm = wave >> 1, wn = wave & 1;                                   \
  const int fr = lane & 15, q = lane >> 4, qd = q;                           \
  const int ci0 = wave * 128 + lane, ci1 = ci0 + 64;                         \
  const int r0 = ci0 >> 2, c0x = (ci0 & 3) ^ ((r0 >> 1) & 3);                \
  const int r1 = ci1 >> 2, c1x = (ci1 & 3) ^ ((r1 >> 1) & 3);                \
  const size_t aoff0 = (size_t)(m0 + r0) * 512 + c0x * 8;                    \
  const size_t aoff1 = (size_t)(m0 + r1) * 512 + c1x * 8;                    \
  const size_t boff0 = (size_t)(n0 + r0) * 512 + c0x * 8;                    \
  const size_t boff1 = (size_t)(n0 + r1) * 512 + c1x * 8;                    \
  const int ld0 = wave * 1024, ld1 = ld0 + 512; /* u16 index of dest */      \
  int fca[4], fcb[4];                                                        \
  _Pragma("unroll") for (int t4 = 0; t4 < 4; t4++) {                         \
    int rra = wm * 64 + t4 * 16 + fr;                                        \
    int rrb = wn * 64 + t4 * 16 + fr;                                        \
    int sz = q ^ ((fr >> 1) & 3);                                            \
    fca[t4] = (rra * 4 + sz) * 8;                                            \
    fcb[t4] = (rrb * 4 + sz) * 8;                                            \
  }                                                                          \
  f32x4 acc[4][4];                                                           \
  _Pragma("unroll") for (int i = 0; i < 4; i++)                              \
    _Pragma("unroll") for (int j = 0; j < 4; j++) {                          \
      acc[i][j][0] = 0.0f; acc[i][j][1] = 0.0f;                              \
      acc[i][j][2] = 0.0f; acc[i][j][3] = 0.0f;                              \
    }

#define MG_KLOOP(Ah, Al, Bh, Bl)                                             \
  for (int k0 = 0; k0 < 512; k0 += 32) {                                     \
    gll16(Ah + aoff0 + k0, &sAh[ld0]);                                       \
    gll16(Ah + aoff1 + k0, &sAh[ld1]);                                       \
    gll16(Al + aoff0 + k0, &sAl[ld0]);                                       \
    gll16(Al + aoff1 + k0, &sAl[ld1]);                                       \
    gll16(Bh + boff0 + k0, &sBh[ld0]);                                       \
    gll16(Bh + boff1 + k0, &sBh[ld1]);                                       \
    gll16(Bl + boff0 + k0, &sBl[ld0]);                                       \
    gll16(Bl + boff1 + k0, &sBl[ld1]);                                       \
    __syncthreads();                                                         \
    bf16x8 fah[4], fal[4], fbh[4], fbl[4];                                   \
    _Pragma("unroll") for (int t4 = 0; t4 < 4; t4++) {                       \
      fah[t4] = *(const bf16x8*)&sAh[fca[t4]];                               \
      fal[t4] = *(const bf16x8*)&sAl[fca[t4]];                               \
      fbh[t4] = *(const bf16x8*)&sBh[fcb[t4]];                               \
      fbl[t4] = *(const bf16x8*)&sBl[fcb[t4]];                               \
    }                                                                        \
    _Pragma("unroll") for (int mt = 0; mt < 4; mt++)                         \
      _Pragma("unroll") for (int nt = 0; nt < 4; nt++) {                     \
        acc[mt][nt] = __builtin_amdgcn_mfma_f32_16x16x32_bf16(               \
            fah[mt], fbh[nt], acc[mt][nt], 0, 0, 0);                         \
        acc[mt][nt] = __builtin_amdgcn_mfma_f32_16x16x32_bf16(               \
            fah[mt], fbl[nt], acc[mt][nt], 0, 0, 0);                         \
        acc[mt][nt] = __builtin_amdgcn_mfma_f32_16x16x32_bf16(               \
            fal[mt], fbh[nt], acc[mt][nt], 0, 0, 0);                         \
      }                                                                      \
    __syncthreads();                                                         \
  }

// ---------------- distance GEMM + packed-u64 argmin ----------------
__global__ __launch_bounds__(256, 4) void dist_mfma(
    const u16* __restrict__ Ah, const u16* __restrict__ Al,
    const u16* __restrict__ Bh, const u16* __restrict__ Bl,
    const float* __restrict__ cnorm, u64* __restrict__ packed) {
  __shared__ __align__(16) u16 sAh[4096], sAl[4096], sBh[4096], sBl[4096];
  MG_PROLOGUE()
  MG_KLOOP(Ah, Al, Bh, Bl)
#pragma unroll
  for (int mt = 0; mt < 4; mt++)
#pragma unroll
    for (int reg = 0; reg < 4; reg++) {
      u64 best = ~0ull;
#pragma unroll
      for (int nt = 0; nt < 4; nt++) {
        int c = n0 + wn * 64 + nt * 16 + fr;
        float d = cnorm[c] - 2.0f * acc[mt][nt][reg];
        u32 ub = __float_as_uint(d);
        ub = (ub & 0x80000000u) ? ~ub : (ub | 0x80000000u);
        u64 p = ((u64)ub << 32) | (u32)c;
        best = (p < best) ? p : best;
      }
#pragma unroll
      for (int mm = 1; mm <= 8; mm <<= 1) {
        u32 h2 = __shfl_xor((u32)(best >> 32), mm);
        u32 l2 = __shfl_xor((u32)best, mm);
        u64 o = ((u64)h2 << 32) | l2;
        best = (o < best) ? o : best;
      }
      if (fr == 0) {
        int row = m0 + wm * 64 + mt * 16 + qd * 4 + reg;
        atomicMin(&packed[row], best);
      }
    }
}

// ---------------- idx output + skew-oblivious count (fused) ----------------
__global__ __launch_bounds__(256) void idxcount_kernel(
    const u64* __restrict__ packed, float* __restrict__ o_idx,
    int* __restrict__ cnt) {
  __shared__ int h[2048];
  for (int i = threadIdx.x; i < 2048; i += 256) h[i] = 0;
  __syncthreads();
  int r = blockIdx.x * 256 + threadIdx.x;
  u32 k = (u32)packed[r];
  o_idx[r] = (float)k;
  atomicAdd(&h[k], 1);
  __syncthreads();
  for (int i = threadIdx.x; i < 2048; i += 256) {
    int v = h[i];
    if (v) atomicAdd(&cnt[i], v);
  }
}

__global__ __launch_bounds__(256) void scan_kernel(
    const int* __restrict__ cnt, int* __restrict__ base,
    int* __restrict__ cursor, const float* __restrict__ ema_cs,
    float* __restrict__ nbuf) {
  __shared__ int part[256];
  __shared__ float esum[256];
  int t = threadIdx.x;
  int local[8];
  int s = 0;
  float es = 0.0f;
#pragma unroll
  for (int i = 0; i < 8; i++) {
    local[i] = cnt[t * 8 + i];
    s += local[i];
    es += ema_cs[t * 8 + i];
  }
  part[t] = s;
  esum[t] = es;
  __syncthreads();
  for (int off = 1; off < 256; off <<= 1) {
    int v = (t >= off) ? part[t - off] : 0;
    __syncthreads();
    part[t] += v;
    __syncthreads();
  }
  int run = part[t] - s;
#pragma unroll
  for (int i = 0; i < 8; i++) {
    base[t * 8 + i] = run;
    cursor[t * 8 + i] = run;
    run += local[i];
  }
  for (int o = 128; o; o >>= 1) {
    if (t < o) esum[t] += esum[t + o];
    __syncthreads();
  }
  if (t == 0) nbuf[0] = 0.9f * esum[0] + 0.1f * (float)RM;
}

// ---------------- scatter (+ fused dw zeroing; WT dead by now) ----------------
__global__ __launch_bounds__(256) void scatter_kernel(
    const u64* __restrict__ packed, int* __restrict__ cursor,
    u32* __restrict__ bucket, float* __restrict__ dw) {
  __shared__ int h[2048];
  __shared__ int gb[2048];
  int gid = blockIdx.x * 256 + threadIdx.x;   // 34816 threads
  for (int i = gid; i < 2048 * 512; i += RM) dw[i] = 0.0f;
  for (int i = threadIdx.x; i < 2048; i += 256) h[i] = 0;
  __syncthreads();
  int k = (int)(u32)packed[gid];
  int lrank = atomicAdd(&h[k], 1);
  __syncthreads();
  for (int i = threadIdx.x; i < 2048; i += 256) {
    int v = h[i];
    gb[i] = v ? atomicAdd(&cursor[i], v) : 0;
  }
  __syncthreads();
  bucket[gb[k] + lrank] = ((u32)k << 17) | (u32)gid;
}

// ---------------- quant gather + loss partials; f = fh+fl ----------------
__global__ __launch_bounds__(256) void quant_out_kernel(
    const u16* __restrict__ fh, const u16* __restrict__ fl,
    const float* __restrict__ CBm, const u64* __restrict__ packed,
    float* __restrict__ ptf_out, float* __restrict__ lpart) {
  __shared__ float wred[4];
  int row = blockIdx.x * 2 + (threadIdx.x >> 7);
  int t = threadIdx.x & 127;
  int k = (int)(u32)packed[row];
  uint2 hb = ((const uint2*)(fh + (size_t)row * 512))[t];
  uint2 lb = ((const uint2*)(fl + (size_t)row * 512))[t];
  float f0 = bf16_f((u16)hb.x) + bf16_f((u16)lb.x);
  float f1 = bf16_f((u16)(hb.x >> 16)) + bf16_f((u16)(lb.x >> 16));
  float f2 = bf16_f((u16)hb.y) + bf16_f((u16)lb.y);
  float f3 = bf16_f((u16)(hb.y >> 16)) + bf16_f((u16)(lb.y >> 16));
  float4 c = ((const float4*)(CBm + (size_t)k * 512))[t];
  float* po = ptf_out + (size_t)row * 512 + 4 * t;
  po[0] = c.x; po[1] = c.y; po[2] = c.z; po[3] = c.w;
  float dx = c.x - f0, dy = c.y - f1, dz = c.z - f2, dwv = c.w - f3;
  float ls = dx * dx + dy * dy + dz * dz + dwv * dwv;
#pragma unroll
  for (int m = 32; m; m >>= 1) ls += __shfl_xor(ls, m);
  if ((threadIdx.x & 63) == 0) wred[threadIdx.x >> 6] = ls;
  __syncthreads();
  if (threadIdx.x == 0)
    lpart[blockIdx.x] = wred[0] + wred[1] + wred[2] + wred[3];
}

// ---------------- skew-oblivious dw from bucket chunks ----------------
__global__ __launch_bounds__(256) void dwsum_chunk_kernel(
    const u16* __restrict__ fh, const u16* __restrict__ fl,
    const u32* __restrict__ bucket, float* __restrict__ dw) {
  __shared__ u32 sp[64];
  const int t = threadIdx.x;
  if (t < 64) sp[t] = bucket[blockIdx.x * 64 + t];
  __syncthreads();
  float ax = 0.0f, ay = 0.0f;
  int curk = (int)(sp[0] >> 17);
  u32 hb = *(const u32*)(fh + (size_t)(sp[0] & 0x1FFFF) * 512 + 2 * t);
  u32 lb = *(const u32*)(fl + (size_t)(sp[0] & 0x1FFFF) * 512 + 2 * t);
  for (int i = 0; i < 64; i++) {
    u32 hn = 0, ln2 = 0;
    if (i + 1 < 64) {
      hn = *(const u32*)(fh + (size_t)(sp[i + 1] & 0x1FFFF) * 512 + 2 * t);
      ln2 = *(const u32*)(fl + (size_t)(sp[i + 1] & 0x1FFFF) * 512 + 2 * t);
    }
    int k = (int)(sp[i] >> 17);
    if (k != curk) {
      atomicAdd(&dw[(size_t)curk * 512 + 2 * t], ax);
      atomicAdd(&dw[(size_t)curk * 512 + 2 * t + 1], ay);
      ax = 0.0f; ay = 0.0f; curk = k;
    }
    ax += bf16_f((u16)hb) + bf16_f((u16)lb);
    ay += bf16_f((u16)(hb >> 16)) + bf16_f((u16)(lb >> 16));
    hb = hn; lb = ln2;
  }
  atomicAdd(&dw[(size_t)curk * 512 + 2 * t], ax);
  atomicAdd(&dw[(size_t)curk * 512 + 2 * t + 1], ay);
}

// ---------------- codebook_new finalize (+ fused loss reduction in block 0) ----------------
__global__ __launch_bounds__(256) void cbnew_kernel(
    const float* __restrict__ ema_w, const float* __restrict__ dw,
    const float* __restrict__ ema_cs, const int* __restrict__ cnt,
    const float* __restrict__ nbuf, float* __restrict__ outp,
    const float* __restrict__ lpart, float* __restrict__ loss_out) {
  int tid = blockIdx.x * 256 + threadIdx.x;
  int k = tid >> 9;
  float n = nbuf[0];
  float cs = ema_cs[k] * 0.9f + 0.1f * (float)cnt[k];
  cs = (cs + 1e-5f) / (n + 0.02048f) * n;
  outp[tid] = (ema_w[tid] * 0.9f + 0.1f * dw[tid]) / cs;
  if (blockIdx.x == 0) {
    __shared__ float red[256];
    float s = 0.0f;
    for (int i = threadIdx.x; i < RM / 2; i += 256) s += lpart[i];
    red[threadIdx.x] = s;
    __syncthreads();
    for (int o = 128; o; o >>= 1) {
      if (threadIdx.x < o) red[threadIdx.x] += red[threadIdx.x + o];
      __syncthreads();
    }
    if (threadIdx.x == 0)
      loss_out[0] = red[0] / (float)((size_t)RM * 512);
  }
}

// ---------------- fully fused decoder: one block per pose ----------------
__global__ __launch_bounds__(256) void decoder_fused(
    const float* __restrict__ ptf,
    const float* __restrict__ dtokw, const float* __restrict__ dtokb,
    const float* __restrict__ dsw, const float* __restrict__ dsb,
    const float* __restrict__ ln1g, const float* __restrict__ ln1b,
    const float* __restrict__ tw1, const float* __restrict__ tb1,
    const float* __restrict__ tw2, const float* __restrict__ tb2,
    const float* __restrict__ ln2g, const float* __restrict__ ln2b,
    const float* __restrict__ cw1, const float* __restrict__ cb1,
    const float* __restrict__ cw2, const float* __restrict__ cb2,
    const float* __restrict__ lng, const float* __restrict__ lnb,
    const float* __restrict__ recw, const float* __restrict__ recb,
    float* __restrict__ o_rec) {
  __shared__ float buf[34 * 257];
  __shared__ float yS[17][257];
  __shared__ float zS[17][33];
  __shared__ float t2S[17][33];
  __shared__ float hS[17][65];
  __shared__ float sdw[34 * 17];
  __shared__ float stw1[17 * 64], stw2[64 * 17];
  const int tid = threadIdx.x;
  const int b = blockIdx.x;
  for (int i = tid; i < 34 * 17; i += 256) sdw[i] = dtokw[i];
  for (int i = tid; i < 17 * 64; i += 256) { stw1[i] = tw1[i]; stw2[i] = tw2[i]; }
  float zacc0 = 0.0f, zacc1 = 0.0f, zacc2 = 0.0f;
  const int j0 = tid >> 5, dd0 = tid & 31;
  const int p1 = tid + 256;
  const int j1 = p1 >> 5, dd1 = p1 & 31;
  const int p2 = tid + 512;
  const int j2 = p2 >> 5, dd2 = p2 & 31;   // valid iff tid < 32
  for (int ch = 0; ch < 2; ch++) {
    for (int m = 0; m < 34; m++)
      buf[m * 257 + tid] = ptf[((size_t)b * 34 + m) * 512 + ch * 256 + tid];
    __syncthreads();
#pragma unroll 1
    for (int j = 0; j < 17; j++) {
      float s = dtokb[j];
#pragma unroll
      for (int m = 0; m < 34; m++) s = fmaf(buf[m * 257 + tid], sdw[m * 17 + j], s);
      yS[j][tid] = s;
    }
    __syncthreads();
    for (int i = tid; i < 256 * 32; i += 256) {
      int d = i >> 5, dd = i & 31;
      buf[d * 33 + dd] = dsw[(size_t)(ch * 256 + d) * 32 + dd];
    }
    __syncthreads();
    {
      float s = 0.0f;
      for (int d = 0; d < 256; d++) s = fmaf(yS[j0][d], buf[d * 33 + dd0], s);
      zacc0 += s;
      float s1 = 0.0f;
      for (int d = 0; d < 256; d++) s1 = fmaf(yS[j1][d], buf[d * 33 + dd1], s1);
      zacc1 += s1;
      if (tid < 32) {
        float s2 = 0.0f;
        for (int d = 0; d < 256; d++) s2 = fmaf(yS[j2][d], buf[d * 33 + dd2], s2);
        zacc2 += s2;
      }
    }
    __syncthreads();
  }
  zS[j0][dd0] = zacc0 + dsb[dd0];
  zS[j1][dd1] = zacc1 + dsb[dd1];
  if (tid < 32) zS[j2][dd2] = zacc2 + dsb[dd2];
  __syncthreads();
  if (tid < 17) {
    float m = 0.0f;
#pragma unroll
    for (int d = 0; d < 32; d++) m += zS[tid][d];
    m *= (1.0f / 32.0f);
    float v = 0.0f;
#pragma unroll
    for (int d = 0; d < 32; d++) { float t = zS[tid][d] - m; v += t * t; }
    float rs = 1.0f / sqrtf(v * (1.0f / 32.0f) + 1e-5f);
#pragma unroll
    for (int d = 0; d < 32; d++)
      t2S[tid][d] = (zS[tid][d] - m) * rs * ln1g[d] + ln1b[d];
  }
  __syncthreads();
  if (tid < 32) {
    float t[17], acc[17];
#pragma unroll
    for (int j = 0; j < 17; j++) { t[j] = t2S[j][tid]; acc[j] = 0.0f; }
    for (int k = 0; k < 64; k++) {
      float h = tb1[k];
#pragma unroll
      for (int j = 0; j < 17; j++) h = fmaf(t[j], stw1[j * 64 + k], h);
      h = gelu_f(h);
#pragma unroll
      for (int j = 0; j < 17; j++) acc[j] = fmaf(h, stw2[k * 17 + j], acc[j]);
    }
#pragma unroll
    for (int j = 0; j < 17; j++) zS[j][tid] = zS[j][tid] + acc[j] + tb2[j];
  }
  __syncthreads();
  if (tid < 17) {
    float m = 0.0f;
#pragma unroll
    for (int d = 0; d < 32; d++) m += zS[tid][d];
    m *= (1.0f / 32.0f);
    float v = 0.0f;
#pragma unroll
    for (int d = 0; d < 32; d++) { float t = zS[tid][d] - m; v += t * t; }
    float rs = 1.0f / sqrtf(v * (1.0f / 32.0f) + 1e-5f);
#pragma unroll
    for (int d = 0; d < 32; d++)
      t2S[tid][d] = (zS[tid][d] - m) * rs * ln2g[d] + ln2b[d];
  }
  __syncthreads();
  for (int p = tid; p < 17 * 64; p += 256) {
    int j = p >> 6, k = p & 63;
    float s = cb1[k];
#pragma unroll
    for (int d = 0; d < 32; d++) s = fmaf(t2S[j][d], cw1[d * 64 + k], s);
    hS[j][k] = gelu_f(s);
  }
  __syncthreads();
  {
    float s = cb2[dd0];
#pragma unroll
    for (int k = 0; k < 64; k++) s = fmaf(hS[j0][k], cw2[k * 32 + dd0], s);
    zS[j0][dd0] += s;
    float s1 = cb2[dd1];
#pragma unroll
    for (int k = 0; k < 64; k++) s1 = fmaf(hS[j1][k], cw2[k * 32 + dd1], s1);
    zS[j1][dd1] += s1;
    if (tid < 32) {
      float s2 = cb2[dd2];
#pragma unroll
      for (int k = 0; k < 64; k++) s2 = fmaf(hS[j2][k], cw2[k * 32 + dd2], s2);
      zS[j2][dd2] += s2;
    }
  }
  __syncthreads();
  if (tid < 17) {
    float m = 0.0f;
#pragma unroll
    for (int d = 0; d < 32; d++) m += zS[tid][d];
    m *= (1.0f / 32.0f);
    float v = 0.0f;
#pragma unroll
    for (int d = 0; d < 32; d++) { float t = zS[tid][d] - m; v += t * t; }
    float rs = 1.0f / sqrtf(v * (1.0f / 32.0f) + 1e-5f);
#pragma unroll
    for (int d = 0; d < 32; d++)
      t2S[tid][d] = (zS[tid][d] - m) * rs * lng[d] + lnb[d];
  }
  __syncthreads();
  if (tid < 34) {
    int j = tid >> 1, c = tid & 1;
    float s = recb[c];
#pragma unroll
    for (int d = 0; d < 32; d++) s = fmaf(t2S[j][d], recw[d * 2 + c], s);
    o_rec[((size_t)b * 17 + j) * 2 + c] = s;
  }
}

// ================================================================
extern "C" void kernel_launch(void* const* d_in, const int* in_sizes, int n_in,
                              void* d_out, int out_size, void* d_ws, size_t ws_size,
                              hipStream_t stream) {
  const float* joints   = (const float*)d_in[0];
  const float* inv_tok  = (const float*)d_in[3];
  const float* start_w  = (const float*)d_in[4];
  const float* start_b  = (const float*)d_in[5];
  const float* e_ln1g = (const float*)d_in[6];
  const float* e_ln1b = (const float*)d_in[7];
  const float* e_tw1  = (const float*)d_in[8];
  const float* e_tb1  = (const float*)d_in[9];
  const float* e_tw2  = (const float*)d_in[10];
  const float* e_tb2  = (const float*)d_in[11];
  const float* e_ln2g = (const float*)d_in[12];
  const float* e_ln2b = (const float*)d_in[13];
  const float* e_cw1  = (const float*)d_in[14];
  const float* e_cb1  = (const float*)d_in[15];
  const float* e_cw2  = (const float*)d_in[16];
  const float* e_cb2  = (const float*)d_in[17];
  const float* d_ln1g = (const float*)d_in[18];
  const float* d_ln1b = (const float*)d_in[19];
  const float* d_tw1  = (const float*)d_in[20];
  const float* d_tb1  = (const float*)d_in[21];
  const float* d_tw2  = (const float*)d_in[22];
  const float* d_tb2  = (const float*)d_in[23];
  const float* d_ln2g = (const float*)d_in[24];
  const float* d_ln2b = (const float*)d_in[25];
  const float* d_cw1  = (const float*)d_in[26];
  const float* d_cb1  = (const float*)d_in[27];
  const float* d_cw2  = (const float*)d_in[28];
  const float* d_cb2  = (const float*)d_in[29];
  const float* enc_lng = (const float*)d_in[30];
  const float* enc_lnb = (const float*)d_in[31];
  const float* tok_w   = (const float*)d_in[32];
  const float* tok_b   = (const float*)d_in[33];
  const float* feat_w  = (const float*)d_in[34];
  const float* feat_b  = (const float*)d_in[35];
  const float* codebook = (const float*)d_in[36];
  const float* ema_cs   = (const float*)d_in[37];
  const float* ema_w    = (const float*)d_in[38];
  const float* dtok_w   = (const float*)d_in[39];
  const float* dtok_b   = (const float*)d_in[40];
  const float* dstart_w = (const float*)d_in[41];
  const float* dstart_b = (const float*)d_in[42];
  const float* dec_lng  = (const float*)d_in[43];
  const float* dec_lnb  = (const float*)d_in[44];
  const float* rec_w    = (const float*)d_in[45];
  const float* rec_b    = (const float*)d_in[46];

  // -------- workspace layout (same proven footprint) --------
  float* ws = (float*)d_ws;
  float* Ab  = ws;                  // [RJ,512] fp32 residual
  float* Bb  = ws + SZX;            // [RJ,512] fp32 (x+y residual)
  float* Cc  = ws + 2 * SZX;        // scratch
  float* P1e = ws + 3 * SZX;        // RJ bf16 hi+lo (ln2 out)
  float* P2e = ws + 4 * SZX;        // RJ bf16 hi+lo (mgemm1 out)
  float* cbs = ws + 5 * SZX;        // codebook split hi+lo
  float* cnorm = cbs + 1048576;                      // 2048
  u64*  packed = (u64*)(cnorm + 2048);               // RM u64
  int*  cnt    = (int*)(cnorm + 2048 + 69632);       // 2048
  int*  basebuf = cnt + 2048;
  int*  cursor  = basebuf + 2048;
  u32*  bucket  = (u32*)(cursor + 2048);             // RM
  float* lpart  = (float*)(bucket + RM);             // RM/2
  float* nbuf   = lpart + RM / 2;                    // 1 (padded)
  float* dw     = nbuf + 2048;                       // 2048*512
  u16* WTh1 = (u16*)dw;
  u16* WTl1 = (u16*)(dw + 131072);
  u16* WTh2 = (u16*)(dw + 262144);
  u16* WTl2 = (u16*)(dw + 393216);
  u16* P1eh = (u16*)P1e;  u16* P1el = (u16*)(P1e + SZX / 2);
  u16* P2eh = (u16*)P2e;  u16* P2el = (u16*)(P2e + SZX / 2);
  u16* P1mh = (u16*)Ab;   u16* P1ml = (u16*)Bb;
  u16* P2mh = (u16*)Cc;   u16* P2ml = (u16*)P1e;
  u16* chh = (u16*)cbs;   u16* cll = (u16*)(cbs + 524288);

  // -------- outputs --------
  float* outp = (float*)d_out;
  float* o_rec = outp;
  float* o_idx = outp + (size_t)RJ * 2;
  float* o_loss = o_idx + RM;
  float* o_ptf = o_loss + 1;
  float* o_cb = o_ptf + SZM;

  // -------- encoder --------
  embed_kernel<<<(RJ * 512) / 256, 256, 0, stream>>>(joints, inv_tok, start_w, start_b, Ab);
  for (int i = 0; i < 4; i++) {
    mixer_fused<<<Bn, 256, 0, stream>>>(
        Ab, Bb, P1eh, P1el,
        e_ln1g + i * 512, e_ln1b + i * 512,
        e_tw1 + i * 17 * 64, e_tb1 + i * 64, e_tw2 + i * 64 * 17, e_tb2 + i * 17,
        e_ln2g + i * 512, e_ln2b + i * 512,
        e_cw1 + (size_t)i * 512 * 512, e_cw2 + (size_t)i * 512 * 512,
        WTh1, WTl1, WTh2, WTl2);
    mgemm64<1, 0, 1><<<dim3(RJ / 64, 4), 256, 0, stream>>>(
        P1eh, P1el, WTh1, WTl1, e_cb1 + i * 512, nullptr, nullptr, P2eh, P2el, 512);
    mgemm64<0, 1, 0><<<dim3(RJ / 64, 4), 256, 0, stream>>>(
        P2eh, P2el, WTh2, WTl2, e_cb2 + i * 512, Bb, Ab, nullptr, nullptr, 512);
  }
  lnmix_fused<<<Bn, 256, 0, stream>>>(Ab, P1mh, P1ml, enc_lng, enc_lnb, tok_w, tok_b,
                                      feat_w, WTh1, WTl1);
  mgemm64<0, 0, 1><<<dim3(RM / 64, 4), 256, 0, stream>>>(
      P1mh, P1ml, WTh1, WTl1, feat_b, nullptr, nullptr, P2mh, P2ml, 512);

  // -------- VQ: distances + argmin --------
  splitnorm_kernel<<<2048 / 4, 256, 0, stream>>>(codebook, chh, cll, cnorm, packed, cnt);
  dist_mfma<<<dim3(RM / 128, 2048 / 128), 256, 0, stream>>>(P2mh, P2ml, chh, cll, cnorm, packed);

  // -------- skew-oblivious bucketed EMA update --------
  idxcount_kernel<<<RM / 256, 256, 0, stream>>>(packed, o_idx, cnt);
  scan_kernel<<<1, 256, 0, stream>>>(cnt, basebuf, cursor, ema_cs, nbuf);
  scatter_kernel<<<RM / 256, 256, 0, stream>>>(packed, cursor, bucket, dw);
  quant_out_kernel<<<RM / 2, 256, 0, stream>>>(P2mh, P2ml, codebook, packed, o_ptf, lpart);
  dwsum_chunk_kernel<<<RM / 64, 256, 0, stream>>>(P2mh, P2ml, bucket, dw);
  cbnew_kernel<<<(2048 * 512) / 256, 256, 0, stream>>>(
      ema_w, dw, ema_cs, cnt, nbuf, o_cb, lpart, o_loss);

  // -------- decoder (single fused kernel) --------
  decoder_fused<<<Bn, 256, 0, stream>>>(
      o_ptf, dtok_w, dtok_b, dstart_w, dstart_b,
      d_ln1g, d_ln1b, d_tw1, d_tb1, d_tw2, d_tb2, d_ln2g, d_ln2b,
      d_cw1, d_cb1, d_cw2, d_cb2, dec_lng, dec_lnb, rec_w, rec_b, o_rec);
}

// Round 10
// 1361.050 us; speedup vs baseline: 4.1681x; 1.1874x over previous
//
#include <hip/hip_runtime.h>
#include <math.h>

// ---------------- problem constants ----------------
constexpr int Bn = 1024, Jn = 17, Mn = 34;
constexpr int RJ = Bn * Jn;                 // 17408
constexpr int RM = Bn * Mn;                 // 34816
constexpr size_t SZX = (size_t)RJ * 512;    // floats
constexpr size_t SZM = (size_t)RM * 512;    // floats

typedef __attribute__((ext_vector_type(8))) short bf16x8;
typedef __attribute__((ext_vector_type(4))) float f32x4;
typedef unsigned long long u64;
typedef unsigned short u16;
typedef unsigned int u32;

__device__ __forceinline__ float gelu_f(float x) {
  return 0.5f * x * (1.0f + erff(x * 0.7071067811865475f));
}
__device__ __forceinline__ u16 bf16_rne(float x) {
  u32 u = __float_as_uint(x);
  u += 0x7fffu + ((u >> 16) & 1u);
  return (u16)(u >> 16);
}
__device__ __forceinline__ float bf16_f(u16 h) {
  return __uint_as_float((u32)h << 16);
}

// async global->LDS, 16B per lane; LDS dest = wave-uniform base + lane*16
typedef __attribute__((address_space(1))) const void gas_t;
typedef __attribute__((address_space(3))) void las_t;
__device__ __forceinline__ void gll16(const void* g, void* l) {
  __builtin_amdgcn_global_load_lds((gas_t*)g, (las_t*)l, 16, 0, 0);
}

// ---------------- embed ----------------
__global__ __launch_bounds__(256) void embed_kernel(
    const float* __restrict__ joints, const float* __restrict__ inv,
    const float* __restrict__ sw, const float* __restrict__ sb,
    float* __restrict__ out) {
  int tid = blockIdx.x * 256 + threadIdx.x;
  int row = tid >> 9, d = tid & 511;
  float j0 = joints[row * 3 + 0];
  float j1 = joints[row * 3 + 1];
  float j2 = joints[row * 3 + 2];
  float x = fmaf(j0, sw[d], fmaf(j1, sw[512 + d], sb[d]));
  float v = (j2 != 0.0f) ? 1.0f : 0.0f;
  out[tid] = x * v + inv[d] * (1.0f - v);
}

// ---------------- fused mixer prefix + weight transpose/split for this layer ----------------
// Weights for tokenmix are read via wave-uniform GLOBAL loads (scalar path), not LDS.
__global__ __launch_bounds__(256) void mixer_fused(
    const float* __restrict__ x_in, float* __restrict__ res_out,
    u16* __restrict__ oh, u16* __restrict__ ol,
    const float* __restrict__ g1, const float* __restrict__ b1,
    const float* __restrict__ tw1, const float* __restrict__ tb1,
    const float* __restrict__ tw2, const float* __restrict__ tb2,
    const float* __restrict__ g2, const float* __restrict__ b2,
    const float* __restrict__ W1, const float* __restrict__ W2,
    u16* __restrict__ Th1, u16* __restrict__ Tl1,
    u16* __restrict__ Th2, u16* __restrict__ Tl2) {
  __shared__ float xs[17][512];
  __shared__ float stats[17][2];
  const int tid = threadIdx.x;
  const int b = blockIdx.x;
  // weight prep: exactly one element of each weight per thread (1024*256 = 262144)
  {
    int gid = b * 256 + tid;
    int k = gid >> 9, n = gid & 511;
    float v = W1[gid];
    u16 h = bf16_rne(v);
    Th1[(size_t)n * 512 + k] = h;
    Tl1[(size_t)n * 512 + k] = bf16_rne(v - bf16_f(h));
    v = W2[gid];
    h = bf16_rne(v);
    Th2[(size_t)n * 512 + k] = h;
    Tl2[(size_t)n * 512 + k] = bf16_rne(v - bf16_f(h));
  }
  const float* px = x_in + (size_t)b * 17 * 512;
  for (int i = tid; i < 17 * 512; i += 256) xs[i >> 9][i & 511] = px[i];
  __syncthreads();
  const int wv = tid >> 6, ln_ = tid & 63;
  // phase A: LN1 stats only
  for (int j = wv; j < 17; j += 4) {
    float v[8];
    float s = 0.0f;
#pragma unroll
    for (int i = 0; i < 8; i++) { v[i] = xs[j][ln_ + 64 * i]; s += v[i]; }
#pragma unroll
    for (int m = 32; m; m >>= 1) s += __shfl_xor(s, m);
    float mean = s * (1.0f / 512.0f);
    float s2 = 0.0f;
#pragma unroll
    for (int i = 0; i < 8; i++) { float t = v[i] - mean; s2 += t * t; }
#pragma unroll
    for (int m = 32; m; m >>= 1) s2 += __shfl_xor(s2, m);
    float rs = 1.0f / sqrtf(s2 * (1.0f / 512.0f) + 1e-5f);
    if (ln_ == 0) { stats[j][0] = mean; stats[j][1] = rs; }
  }
  __syncthreads();
  // phase B: single pass, 2 columns/thread; weights via uniform global loads
  {
    const int d0 = tid, d1 = tid + 256;
    float ga = g1[d0], ba = b1[d0];
    float gb = g1[d1], bb2 = b1[d1];
    float t0[17], t1[17], a0[17], a1[17];
#pragma unroll
    for (int j = 0; j < 17; j++) {
      float mj = stats[j][0], rj = stats[j][1];
      t0[j] = (xs[j][d0] - mj) * rj * ga + ba;
      t1[j] = (xs[j][d1] - mj) * rj * gb + bb2;
      a0[j] = 0.0f; a1[j] = 0.0f;
    }
#pragma unroll 1
    for (int k = 0; k < 64; k++) {
      float h0 = tb1[k], h1 = h0;
#pragma unroll
      for (int j = 0; j < 17; j++) {
        float w = tw1[j * 64 + k];
        h0 = fmaf(t0[j], w, h0);
        h1 = fmaf(t1[j], w, h1);
      }
      h0 = gelu_f(h0);
      h1 = gelu_f(h1);
#pragma unroll
      for (int j = 0; j < 17; j++) {
        float w = tw2[k * 17 + j];
        a0[j] = fmaf(h0, w, a0[j]);
        a1[j] = fmaf(h1, w, a1[j]);
      }
    }
#pragma unroll
    for (int j = 0; j < 17; j++) {
      float tb = tb2[j];
      float r0 = xs[j][d0] + a0[j] + tb;
      float r1 = xs[j][d1] + a1[j] + tb;
      xs[j][d0] = r0;
      xs[j][d1] = r1;
      res_out[((size_t)b * 17 + j) * 512 + d0] = r0;
      res_out[((size_t)b * 17 + j) * 512 + d1] = r1;
    }
  }
  __syncthreads();
  // phase C: LN2 rows -> hi/lo
  for (int j = wv; j < 17; j += 4) {
    float v[8];
    float s = 0.0f;
#pragma unroll
    for (int i = 0; i < 8; i++) { v[i] = xs[j][ln_ + 64 * i]; s += v[i]; }
#pragma unroll
    for (int m = 32; m; m >>= 1) s += __shfl_xor(s, m);
    float mean = s * (1.0f / 512.0f);
    float s2 = 0.0f;
#pragma unroll
    for (int i = 0; i < 8; i++) { float t = v[i] - mean; s2 += t * t; }
#pragma unroll
    for (int m = 32; m; m >>= 1) s2 += __shfl_xor(s2, m);
    float rs = 1.0f / sqrtf(s2 * (1.0f / 512.0f) + 1e-5f);
#pragma unroll
    for (int i = 0; i < 8; i++) {
      int d = ln_ + 64 * i;
      float o = (v[i] - mean) * rs * g2[d] + b2[d];
      u16 h = bf16_rne(o);
      size_t off = ((size_t)b * 17 + j) * 512 + d;
      oh[off] = h;
      ol[off] = bf16_rne(o - bf16_f(h));
    }
  }
}

// ---------------- fused enc_ln + token linmix (17->34) + feat_w prep ----------------
__global__ __launch_bounds__(256) void lnmix_fused(
    const float* __restrict__ x_in, u16* __restrict__ oh, u16* __restrict__ ol,
    const float* __restrict__ g, const float* __restrict__ bb,
    const float* __restrict__ w, const float* __restrict__ bias,
    const float* __restrict__ Wf, u16* __restrict__ Thf, u16* __restrict__ Tlf) {
  __shared__ float xs[17][513];
  const int tid = threadIdx.x;
  const int b = blockIdx.x;
  {
    int gid = b * 256 + tid;
    int k = gid >> 9, n = gid & 511;
    float v = Wf[gid];
    u16 h = bf16_rne(v);
    Thf[(size_t)n * 512 + k] = h;
    Tlf[(size_t)n * 512 + k] = bf16_rne(v - bf16_f(h));
  }
  const float* px = x_in + (size_t)b * 17 * 512;
  for (int i = tid; i < 17 * 512; i += 256) xs[i >> 9][i & 511] = px[i];
  __syncthreads();
  const int wv = tid >> 6, ln_ = tid & 63;
  for (int j = wv; j < 17; j += 4) {
    float v[8];
    float s = 0.0f;
#pragma unroll
    for (int i = 0; i < 8; i++) { v[i] = xs[j][ln_ + 64 * i]; s += v[i]; }
#pragma unroll
    for (int m = 32; m; m >>= 1) s += __shfl_xor(s, m);
    float mean = s * (1.0f / 512.0f);
    float s2 = 0.0f;
#pragma unroll
    for (int i = 0; i < 8; i++) { float t = v[i] - mean; s2 += t * t; }
#pragma unroll
    for (int m = 32; m; m >>= 1) s2 += __shfl_xor(s2, m);
    float rs = 1.0f / sqrtf(s2 * (1.0f / 512.0f) + 1e-5f);
#pragma unroll
    for (int i = 0; i < 8; i++) {
      int d = ln_ + 64 * i;
      xs[j][d] = (v[i] - mean) * rs * g[d] + bb[d];
    }
  }
  __syncthreads();
  // single pass, 2 columns/thread; weights via uniform global loads
  {
    const int d0 = tid, d1 = tid + 256;
    float t0[17], t1[17];
#pragma unroll
    for (int j = 0; j < 17; j++) { t0[j] = xs[j][d0]; t1[j] = xs[j][d1]; }
#pragma unroll 1
    for (int m = 0; m < 34; m++) {
      float s0 = bias[m], s1 = s0;
#pragma unroll
      for (int j = 0; j < 17; j++) {
        float wv2 = w[j * 34 + m];
        s0 = fmaf(t0[j], wv2, s0);
        s1 = fmaf(t1[j], wv2, s1);
      }
      size_t o0 = ((size_t)b * 34 + m) * 512 + d0;
      u16 h0 = bf16_rne(s0);
      oh[o0] = h0;
      ol[o0] = bf16_rne(s0 - bf16_f(h0));
      size_t o1 = o0 + 256;
      u16 h1 = bf16_rne(s1);
      oh[o1] = h1;
      ol[o1] = bf16_rne(s1 - bf16_f(h1));
    }
  }
}

// ---------------- fused codebook split + L2 norms + packed/cnt init ----------------
__global__ __launch_bounds__(256) void splitnorm_kernel(
    const float* __restrict__ CBm, u16* __restrict__ hi, u16* __restrict__ lo,
    float* __restrict__ cnorm, u64* __restrict__ packed, int* __restrict__ cnt) {
  int gid = blockIdx.x * 256 + threadIdx.x;   // 512*256 = 131072 threads
  for (int i = gid; i < RM; i += 131072) packed[i] = ~0ull;
  if (gid < 2048) cnt[gid] = 0;
  int wave = threadIdx.x >> 6, lane = threadIdx.x & 63;
  int k = blockIdx.x * 4 + wave;
  const float4* p4 = (const float4*)(CBm + (size_t)k * 512);
  ushort4* h4 = (ushort4*)(hi + (size_t)k * 512);
  ushort4* l4 = (ushort4*)(lo + (size_t)k * 512);
  float s = 0.0f;
#pragma unroll
  for (int i = 0; i < 2; i++) {
    float4 x = p4[lane + 64 * i];
    ushort4 h, l;
    h.x = bf16_rne(x.x); l.x = bf16_rne(x.x - bf16_f(h.x));
    h.y = bf16_rne(x.y); l.y = bf16_rne(x.y - bf16_f(h.y));
    h.z = bf16_rne(x.z); l.z = bf16_rne(x.z - bf16_f(h.z));
    h.w = bf16_rne(x.w); l.w = bf16_rne(x.w - bf16_f(h.w));
    h4[lane + 64 * i] = h;
    l4[lane + 64 * i] = l;
    s = fmaf(x.x, x.x, s); s = fmaf(x.y, x.y, s);
    s = fmaf(x.z, x.z, s); s = fmaf(x.w, x.w, s);
  }
#pragma unroll
  for (int m = 32; m; m >>= 1) s += __shfl_xor(s, m);
  if (lane == 0) cnorm[k] = s;
}

// ---------------- split-bf16 MFMA GEMM, 64x128 tile (4 waves of 32x64) ----------------
template <int GELU_FLAG, int RES_FLAG, int HILO_OUT>
__global__ __launch_bounds__(256, 4) void mgemm64(
    const u16* __restrict__ Ah, const u16* __restrict__ Al,
    const u16* __restrict__ Bh, const u16* __restrict__ Bl,
    const float* __restrict__ bias, const float* __restrict__ R,
    float* __restrict__ C, u16* __restrict__ Oh, u16* __restrict__ Ol, int N) {
  __shared__ __align__(16) u16 sAh[2048], sAl[2048], sBh[4096], sBl[4096];
  const int tid = threadIdx.x;
  const int m0 = blockIdx.x * 64, n0 = blockIdx.y * 128;
  const int lane = tid & 63, wave = tid >> 6;
  const int wm = wave >> 1, wn = wave & 1;
  const int fr = lane & 15, q = lane >> 4;
  const int ra = tid >> 2, ca = (tid & 3) ^ ((ra >> 1) & 3);
  const size_t aoff = (size_t)(m0 + ra) * 512 + ca * 8;
  const int rb0 = tid >> 2, cb0 = (tid & 3) ^ ((rb0 >> 1) & 3);
  const int ci1 = tid + 256;
  const int rb1 = ci1 >> 2, cb1 = (ci1 & 3) ^ ((rb1 >> 1) & 3);
  const size_t boff0 = (size_t)(n0 + rb0) * 512 + cb0 * 8;
  const size_t boff1 = (size_t)(n0 + rb1) * 512 + cb1 * 8;
  const int ldA = wave * 512;
  const int ldB0 = wave * 512, ldB1 = 2048 + wave * 512;
  int fca[2], fcb[4];
#pragma unroll
  for (int mt = 0; mt < 2; mt++) {
    int rra = wm * 32 + mt * 16 + fr;
    fca[mt] = (rra * 4 + (q ^ ((rra >> 1) & 3))) * 8;
  }
#pragma unroll
  for (int nt = 0; nt < 4; nt++) {
    int rrb = wn * 64 + nt * 16 + fr;
    fcb[nt] = (rrb * 4 + (q ^ ((rrb >> 1) & 3))) * 8;
  }
  f32x4 acc[2][4];
#pragma unroll
  for (int i = 0; i < 2; i++)
#pragma unroll
    for (int j = 0; j < 4; j++) {
      acc[i][j][0] = 0.0f; acc[i][j][1] = 0.0f;
      acc[i][j][2] = 0.0f; acc[i][j][3] = 0.0f;
    }
  for (int k0 = 0; k0 < 512; k0 += 32) {
    gll16(Ah + aoff + k0, &sAh[ldA]);
    gll16(Al + aoff + k0, &sAl[ldA]);
    gll16(Bh + boff0 + k0, &sBh[ldB0]);
    gll16(Bh + boff1 + k0, &sBh[ldB1]);
    gll16(Bl + boff0 + k0, &sBl[ldB0]);
    gll16(Bl + boff1 + k0, &sBl[ldB1]);
    __syncthreads();
    bf16x8 fah[2], fal[2], fbh[4], fbl[4];
#pragma unroll
    for (int mt = 0; mt < 2; mt++) {
      fah[mt] = *(const bf16x8*)&sAh[fca[mt]];
      fal[mt] = *(const bf16x8*)&sAl[fca[mt]];
    }
#pragma unroll
    for (int nt = 0; nt < 4; nt++) {
      fbh[nt] = *(const bf16x8*)&sBh[fcb[nt]];
      fbl[nt] = *(const bf16x8*)&sBl[fcb[nt]];
    }
#pragma unroll
    for (int mt = 0; mt < 2; mt++)
#pragma unroll
      for (int nt = 0; nt < 4; nt++) {
        acc[mt][nt] = __builtin_amdgcn_mfma_f32_16x16x32_bf16(
            fah[mt], fbh[nt], acc[mt][nt], 0, 0, 0);
        acc[mt][nt] = __builtin_amdgcn_mfma_f32_16x16x32_bf16(
            fah[mt], fbl[nt], acc[mt][nt], 0, 0, 0);
        acc[mt][nt] = __builtin_amdgcn_mfma_f32_16x16x32_bf16(
            fal[mt], fbh[nt], acc[mt][nt], 0, 0, 0);
      }
    __syncthreads();
  }
#pragma unroll
  for (int mt = 0; mt < 2; mt++)
#pragma unroll
    for (int reg = 0; reg < 4; reg++) {
      int row = m0 + wm * 32 + mt * 16 + q * 4 + reg;
#pragma unroll
      for (int nt = 0; nt < 4; nt++) {
        int col = n0 + wn * 64 + nt * 16 + fr;
        float v = acc[mt][nt][reg] + bias[col];
        if (GELU_FLAG) v = gelu_f(v);
        if (RES_FLAG) v += R[(size_t)row * N + col];
        if (HILO_OUT) {
          u16 h = bf16_rne(v);
          Oh[(size_t)row * N + col] = h;
          Ol[(size_t)row * N + col] = bf16_rne(v - bf16_f(h));
        } else {
          C[(size_t)row * N + col] = v;
        }
      }
    }
}

// ======== M=128 staging/compute macros (dist kernel, validated) ========
#define MG_PROLOGUE()                                                        \
  const int tid = threadIdx.x;                                               \
  const int m0 = blockIdx.x * 128, n0 = blockIdx.y * 128;                    \
  const int lane = tid & 63, wave = tid >> 6;                                \
  const int wm = wave >> 1, wn = wave & 1;                                   \
  const int fr = lane & 15, q = lane >> 4, qd = q;                           \
  const int ci0 = wave * 128 + lane, ci1 = ci0 + 64;                         \
  const int r0 = ci0 >> 2, c0x = (ci0 & 3) ^ ((r0 >> 1) & 3);                \
  const int r1 = ci1 >> 2, c1x = (ci1 & 3) ^ ((r1 >> 1) & 3);                \
  const size_t aoff0 = (size_t)(m0 + r0) * 512 + c0x * 8;                    \
  const size_t aoff1 = (size_t)(m0 + r1) * 512 + c1x * 8;                    \
  const size_t boff0 = (size_t)(n0 + r0) * 512 + c0x * 8;                    \
  const size_t boff1 = (size_t)(n0 + r1) * 512 + c1x * 8;                    \
  const int ld0 = wave * 1024, ld1 = ld0 + 512; /* u16 index of dest */      \
  int fca[4], fcb[4];                                                        \
  _Pragma("unroll") for (int t4 = 0; t4 < 4; t4++) {                         \
    int rra = wm * 64 + t4 * 16 + fr;                                        \
    int rrb = wn * 64 + t4 * 16 + fr;                                        \
    int sz = q ^ ((fr >> 1) & 3);                                            \
    fca[t4] = (rra * 4 + sz) * 8;                                            \
    fcb[t4] = (rrb * 4 + sz) * 8;                                            \
  }                                                                          \
  f32x4 acc[4][4];                                                           \
  _Pragma("unroll") for (int i = 0; i < 4; i++)                              \
    _Pragma("unroll") for (int j = 0; j < 4; j++) {                          \
      acc[i][j][0] = 0.0f; acc[i][j][1] = 0.0f;                              \
      acc[i][j][2] = 0.0f; acc[i][j][3] = 0.0f;                              \
    }

#define MG_KLOOP(Ah, Al, Bh, Bl)                                             \
  for (int k0 = 0; k0 < 512; k0 += 32) {                                     \
    gll16(Ah + aoff0 + k0, &sAh[ld0]);                                       \
    gll16(Ah + aoff1 + k0, &sAh[ld1]);                                       \
    gll16(Al + aoff0 + k0, &sAl[ld0]);                                       \
    gll16(Al + aoff1 + k0, &sAl[ld1]);                                       \
    gll16(Bh + boff0 + k0, &sBh[ld0]);                                       \
    gll16(Bh + boff1 + k0, &sBh[ld1]);                                       \
    gll16(Bl + boff0 + k0, &sBl[ld0]);                                       \
    gll16(Bl + boff1 + k0, &sBl[ld1]);                                       \
    __syncthreads();                                                         \
    bf16x8 fah[4], fal[4], fbh[4], fbl[4];                                   \
    _Pragma("unroll") for (int t4 = 0; t4 < 4; t4++) {                       \
      fah[t4] = *(const bf16x8*)&sAh[fca[t4]];                               \
      fal[t4] = *(const bf16x8*)&sAl[fca[t4]];                               \
      fbh[t4] = *(const bf16x8*)&sBh[fcb[t4]];                               \
      fbl[t4] = *(const bf16x8*)&sBl[fcb[t4]];                               \
    }                                                                        \
    _Pragma("unroll") for (int mt = 0; mt < 4; mt++)                         \
      _Pragma("unroll") for (int nt = 0; nt < 4; nt++) {                     \
        acc[mt][nt] = __builtin_amdgcn_mfma_f32_16x16x32_bf16(               \
            fah[mt], fbh[nt], acc[mt][nt], 0, 0, 0);                         \
        acc[mt][nt] = __builtin_amdgcn_mfma_f32_16x16x32_bf16(               \
            fah[mt], fbl[nt], acc[mt][nt], 0, 0, 0);                         \
        acc[mt][nt] = __builtin_amdgcn_mfma_f32_16x16x32_bf16(               \
            fal[mt], fbh[nt], acc[mt][nt], 0, 0, 0);                         \
      }                                                                      \
    __syncthreads();                                                         \
  }

// ---------------- distance GEMM + packed-u64 argmin ----------------
__global__ __launch_bounds__(256, 4) void dist_mfma(
    const u16* __restrict__ Ah, const u16* __restrict__ Al,
    const u16* __restrict__ Bh, const u16* __restrict__ Bl,
    const float* __restrict__ cnorm, u64* __restrict__ packed) {
  __shared__ __align__(16) u16 sAh[4096], sAl[4096], sBh[4096], sBl[4096];
  MG_PROLOGUE()
  MG_KLOOP(Ah, Al, Bh, Bl)
#pragma unroll
  for (int mt = 0; mt < 4; mt++)
#pragma unroll
    for (int reg = 0; reg < 4; reg++) {
      u64 best = ~0ull;
#pragma unroll
      for (int nt = 0; nt < 4; nt++) {
        int c = n0 + wn * 64 + nt * 16 + fr;
        float d = cnorm[c] - 2.0f * acc[mt][nt][reg];
        u32 ub = __float_as_uint(d);
        ub = (ub & 0x80000000u) ? ~ub : (ub | 0x80000000u);
        u64 p = ((u64)ub << 32) | (u32)c;
        best = (p < best) ? p : best;
      }
#pragma unroll
      for (int mm = 1; mm <= 8; mm <<= 1) {
        u32 h2 = __shfl_xor((u32)(best >> 32), mm);
        u32 l2 = __shfl_xor((u32)best, mm);
        u64 o = ((u64)h2 << 32) | l2;
        best = (o < best) ? o : best;
      }
      if (fr == 0) {
        int row = m0 + wm * 64 + mt * 16 + qd * 4 + reg;
        atomicMin(&packed[row], best);
      }
    }
}

// ---------------- idx output + skew-oblivious count (fused) ----------------
__global__ __launch_bounds__(256) void idxcount_kernel(
    const u64* __restrict__ packed, float* __restrict__ o_idx,
    int* __restrict__ cnt) {
  __shared__ int h[2048];
  for (int i = threadIdx.x; i < 2048; i += 256) h[i] = 0;
  __syncthreads();
  int r = blockIdx.x * 256 + threadIdx.x;
  u32 k = (u32)packed[r];
  o_idx[r] = (float)k;
  atomicAdd(&h[k], 1);
  __syncthreads();
  for (int i = threadIdx.x; i < 2048; i += 256) {
    int v = h[i];
    if (v) atomicAdd(&cnt[i], v);
  }
}

__global__ __launch_bounds__(256) void scan_kernel(
    const int* __restrict__ cnt, int* __restrict__ base,
    int* __restrict__ cursor, const float* __restrict__ ema_cs,
    float* __restrict__ nbuf) {
  __shared__ int part[256];
  __shared__ float esum[256];
  int t = threadIdx.x;
  int local[8];
  int s = 0;
  float es = 0.0f;
#pragma unroll
  for (int i = 0; i < 8; i++) {
    local[i] = cnt[t * 8 + i];
    s += local[i];
    es += ema_cs[t * 8 + i];
  }
  part[t] = s;
  esum[t] = es;
  __syncthreads();
  for (int off = 1; off < 256; off <<= 1) {
    int v = (t >= off) ? part[t - off] : 0;
    __syncthreads();
    part[t] += v;
    __syncthreads();
  }
  int run = part[t] - s;
#pragma unroll
  for (int i = 0; i < 8; i++) {
    base[t * 8 + i] = run;
    cursor[t * 8 + i] = run;
    run += local[i];
  }
  for (int o = 128; o; o >>= 1) {
    if (t < o) esum[t] += esum[t + o];
    __syncthreads();
  }
  if (t == 0) nbuf[0] = 0.9f * esum[0] + 0.1f * (float)RM;
}

// ---------------- scatter (+ fused dw zeroing; WT dead by now) ----------------
__global__ __launch_bounds__(256) void scatter_kernel(
    const u64* __restrict__ packed, int* __restrict__ cursor,
    u32* __restrict__ bucket, float* __restrict__ dw) {
  __shared__ int h[2048];
  __shared__ int gb[2048];
  int gid = blockIdx.x * 256 + threadIdx.x;   // 34816 threads
  for (int i = gid; i < 2048 * 512; i += RM) dw[i] = 0.0f;
  for (int i = threadIdx.x; i < 2048; i += 256) h[i] = 0;
  __syncthreads();
  int k = (int)(u32)packed[gid];
  int lrank = atomicAdd(&h[k], 1);
  __syncthreads();
  for (int i = threadIdx.x; i < 2048; i += 256) {
    int v = h[i];
    gb[i] = v ? atomicAdd(&cursor[i], v) : 0;
  }
  __syncthreads();
  bucket[gb[k] + lrank] = ((u32)k << 17) | (u32)gid;
}

// ---------------- quant gather + loss partials; f = fh+fl ----------------
__global__ __launch_bounds__(256) void quant_out_kernel(
    const u16* __restrict__ fh, const u16* __restrict__ fl,
    const float* __restrict__ CBm, const u64* __restrict__ packed,
    float* __restrict__ ptf_out, float* __restrict__ lpart) {
  __shared__ float wred[4];
  int row = blockIdx.x * 2 + (threadIdx.x >> 7);
  int t = threadIdx.x & 127;
  int k = (int)(u32)packed[row];
  uint2 hb = ((const uint2*)(fh + (size_t)row * 512))[t];
  uint2 lb = ((const uint2*)(fl + (size_t)row * 512))[t];
  float f0 = bf16_f((u16)hb.x) + bf16_f((u16)lb.x);
  float f1 = bf16_f((u16)(hb.x >> 16)) + bf16_f((u16)(lb.x >> 16));
  float f2 = bf16_f((u16)hb.y) + bf16_f((u16)lb.y);
  float f3 = bf16_f((u16)(hb.y >> 16)) + bf16_f((u16)(lb.y >> 16));
  float4 c = ((const float4*)(CBm + (size_t)k * 512))[t];
  float* po = ptf_out + (size_t)row * 512 + 4 * t;
  po[0] = c.x; po[1] = c.y; po[2] = c.z; po[3] = c.w;
  float dx = c.x - f0, dy = c.y - f1, dz = c.z - f2, dwv = c.w - f3;
  float ls = dx * dx + dy * dy + dz * dz + dwv * dwv;
#pragma unroll
  for (int m = 32; m; m >>= 1) ls += __shfl_xor(ls, m);
  if ((threadIdx.x & 63) == 0) wred[threadIdx.x >> 6] = ls;
  __syncthreads();
  if (threadIdx.x == 0)
    lpart[blockIdx.x] = wred[0] + wred[1] + wred[2] + wred[3];
}

// ---------------- skew-oblivious dw from bucket chunks ----------------
__global__ __launch_bounds__(256) void dwsum_chunk_kernel(
    const u16* __restrict__ fh, const u16* __restrict__ fl,
    const u32* __restrict__ bucket, float* __restrict__ dw) {
  __shared__ u32 sp[64];
  const int t = threadIdx.x;
  if (t < 64) sp[t] = bucket[blockIdx.x * 64 + t];
  __syncthreads();
  float ax = 0.0f, ay = 0.0f;
  int curk = (int)(sp[0] >> 17);
  u32 hb = *(const u32*)(fh + (size_t)(sp[0] & 0x1FFFF) * 512 + 2 * t);
  u32 lb = *(const u32*)(fl + (size_t)(sp[0] & 0x1FFFF) * 512 + 2 * t);
  for (int i = 0; i < 64; i++) {
    u32 hn = 0, ln2 = 0;
    if (i + 1 < 64) {
      hn = *(const u32*)(fh + (size_t)(sp[i + 1] & 0x1FFFF) * 512 + 2 * t);
      ln2 = *(const u32*)(fl + (size_t)(sp[i + 1] & 0x1FFFF) * 512 + 2 * t);
    }
    int k = (int)(sp[i] >> 17);
    if (k != curk) {
      atomicAdd(&dw[(size_t)curk * 512 + 2 * t], ax);
      atomicAdd(&dw[(size_t)curk * 512 + 2 * t + 1], ay);
      ax = 0.0f; ay = 0.0f; curk = k;
    }
    ax += bf16_f((u16)hb) + bf16_f((u16)lb);
    ay += bf16_f((u16)(hb >> 16)) + bf16_f((u16)(lb >> 16));
    hb = hn; lb = ln2;
  }
  atomicAdd(&dw[(size_t)curk * 512 + 2 * t], ax);
  atomicAdd(&dw[(size_t)curk * 512 + 2 * t + 1], ay);
}

// ---------------- codebook_new finalize (+ fused loss reduction in block 0) ----------------
__global__ __launch_bounds__(256) void cbnew_kernel(
    const float* __restrict__ ema_w, const float* __restrict__ dw,
    const float* __restrict__ ema_cs, const int* __restrict__ cnt,
    const float* __restrict__ nbuf, float* __restrict__ outp,
    const float* __restrict__ lpart, float* __restrict__ loss_out) {
  int tid = blockIdx.x * 256 + threadIdx.x;
  int k = tid >> 9;
  float n = nbuf[0];
  float cs = ema_cs[k] * 0.9f + 0.1f * (float)cnt[k];
  cs = (cs + 1e-5f) / (n + 0.02048f) * n;
  outp[tid] = (ema_w[tid] * 0.9f + 0.1f * dw[tid]) / cs;
  if (blockIdx.x == 0) {
    __shared__ float red[256];
    float s = 0.0f;
    for (int i = threadIdx.x; i < RM / 2; i += 256) s += lpart[i];
    red[threadIdx.x] = s;
    __syncthreads();
    for (int o = 128; o; o >>= 1) {
      if (threadIdx.x < o) red[threadIdx.x] += red[threadIdx.x + o];
      __syncthreads();
    }
    if (threadIdx.x == 0)
      loss_out[0] = red[0] / (float)((size_t)RM * 512);
  }
}

// ---------------- fully fused decoder: one block per pose ----------------
// 544 (joint,dim) pairs: segments j0 (pairs 0..255), j1 (256..511), j2 (512..543, tid<32).
// Note dd is identical across segments (256 % 32 == 0) -> shared weight loads.
__global__ __launch_bounds__(256) void decoder_fused(
    const float* __restrict__ ptf,
    const float* __restrict__ dtokw, const float* __restrict__ dtokb,
    const float* __restrict__ dsw, const float* __restrict__ dsb,
    const float* __restrict__ ln1g, const float* __restrict__ ln1b,
    const float* __restrict__ tw1, const float* __restrict__ tb1,
    const float* __restrict__ tw2, const float* __restrict__ tb2,
    const float* __restrict__ ln2g, const float* __restrict__ ln2b,
    const float* __restrict__ cw1, const float* __restrict__ cb1,
    const float* __restrict__ cw2, const float* __restrict__ cb2,
    const float* __restrict__ lng, const float* __restrict__ lnb,
    const float* __restrict__ recw, const float* __restrict__ recb,
    float* __restrict__ o_rec) {
  __shared__ float yS[17][260];   // 260: float4-aligned rows (1040 B)
  __shared__ float zS[17][33];
  __shared__ float t2S[17][33];
  __shared__ float hS[17][65];
  const int tid = threadIdx.x;
  const int b = blockIdx.x;
  float zacc0 = 0.0f, zacc1 = 0.0f, zacc2 = 0.0f;
  const int j0 = tid >> 5, dd0 = tid & 31;
  const int j1 = (tid + 256) >> 5;
  const int j2 = (tid + 512) >> 5;           // valid iff tid < 32
  for (int ch = 0; ch < 2; ch++) {
    // y phase: ptf in registers, dtokw via uniform global loads
    float p[34];
#pragma unroll
    for (int m = 0; m < 34; m++)
      p[m] = ptf[((size_t)b * 34 + m) * 512 + ch * 256 + tid];
#pragma unroll 1
    for (int j = 0; j < 17; j++) {
      float s = dtokb[j];
#pragma unroll
      for (int m = 0; m < 34; m++) s = fmaf(p[m], dtokw[m * 17 + j], s);
      yS[j][tid] = s;
    }
    __syncthreads();
    // z partials: vectorized yS reads + W direct from global (coalesced 128B lines)
    {
      const float4* y0 = (const float4*)&yS[j0][0];
      const float4* y1 = (const float4*)&yS[j1][0];
      const float* wg = dsw + (size_t)ch * 256 * 32 + dd0;
#pragma unroll 1
      for (int d4 = 0; d4 < 64; d4++) {
        float4 va = y0[d4];
        float4 vb = y1[d4];
        float w0 = wg[(4 * d4 + 0) * 32];
        float w1 = wg[(4 * d4 + 1) * 32];
        float w2 = wg[(4 * d4 + 2) * 32];
        float w3 = wg[(4 * d4 + 3) * 32];
        zacc0 = fmaf(va.x, w0, zacc0); zacc0 = fmaf(va.y, w1, zacc0);
        zacc0 = fmaf(va.z, w2, zacc0); zacc0 = fmaf(va.w, w3, zacc0);
        zacc1 = fmaf(vb.x, w0, zacc1); zacc1 = fmaf(vb.y, w1, zacc1);
        zacc1 = fmaf(vb.z, w2, zacc1); zacc1 = fmaf(vb.w, w3, zacc1);
      }
      if (tid < 32) {
        const float4* y2 = (const float4*)&yS[j2][0];
#pragma unroll 1
        for (int d4 = 0; d4 < 64; d4++) {
          float4 vc = y2[d4];
          float w0 = wg[(4 * d4 + 0) * 32];
          float w1 = wg[(4 * d4 + 1) * 32];
          float w2 = wg[(4 * d4 + 2) * 32];
          float w3 = wg[(4 * d4 + 3) * 32];
          zacc2 = fmaf(vc.x, w0, zacc2); zacc2 = fmaf(vc.y, w1, zacc2);
          zacc2 = fmaf(vc.z, w2, zacc2); zacc2 = fmaf(vc.w, w3, zacc2);
        }
      }
    }
    __syncthreads();
  }
  zS[j0][dd0] = zacc0 + dsb[dd0];
  zS[j1][dd0] = zacc1 + dsb[dd0];
  if (tid < 32) zS[j2][dd0] = zacc2 + dsb[dd0];
  __syncthreads();
  // mixer LN1 (threads 0..16)
  if (tid < 17) {
    float m = 0.0f;
#pragma unroll
    for (int d = 0; d < 32; d++) m += zS[tid][d];
    m *= (1.0f / 32.0f);
    float v = 0.0f;
#pragma unroll
    for (int d = 0; d < 32; d++) { float t = zS[tid][d] - m; v += t * t; }
    float rs = 1.0f / sqrtf(v * (1.0f / 32.0f) + 1e-5f);
#pragma unroll
    for (int d = 0; d < 32; d++)
      t2S[tid][d] = (zS[tid][d] - m) * rs * ln1g[d] + ln1b[d];
  }
  __syncthreads();
  // tokenmix over joints (threads 0..31), weights via uniform global loads
  if (tid < 32) {
    float t[17], acc[17];
#pragma unroll
    for (int j = 0; j < 17; j++) { t[j] = t2S[j][tid]; acc[j] = 0.0f; }
    for (int k = 0; k < 64; k++) {
      float h = tb1[k];
#pragma unroll
      for (int j = 0; j < 17; j++) h = fmaf(t[j], tw1[j * 64 + k], h);
      h = gelu_f(h);
#pragma unroll
      for (int j = 0; j < 17; j++) acc[j] = fmaf(h, tw2[k * 17 + j], acc[j]);
    }
#pragma unroll
    for (int j = 0; j < 17; j++) zS[j][tid] = zS[j][tid] + acc[j] + tb2[j];
  }
  __syncthreads();
  // LN2
  if (tid < 17) {
    float m = 0.0f;
#pragma unroll
    for (int d = 0; d < 32; d++) m += zS[tid][d];
    m *= (1.0f / 32.0f);
    float v = 0.0f;
#pragma unroll
    for (int d = 0; d < 32; d++) { float t = zS[tid][d] - m; v += t * t; }
    float rs = 1.0f / sqrtf(v * (1.0f / 32.0f) + 1e-5f);
#pragma unroll
    for (int d = 0; d < 32; d++)
      t2S[tid][d] = (zS[tid][d] - m) * rs * ln2g[d] + ln2b[d];
  }
  __syncthreads();
  // channel MLP hidden (17*64 outputs)
  for (int p = tid; p < 17 * 64; p += 256) {
    int j = p >> 6, k = p & 63;
    float s = cb1[k];
#pragma unroll
    for (int d = 0; d < 32; d++) s = fmaf(t2S[j][d], cw1[d * 64 + k], s);
    hS[j][k] = gelu_f(s);
  }
  __syncthreads();
  // channel MLP out + residual (3 segments, shared dd0/cb2)
  {
    float cb = cb2[dd0];
    float s0 = cb, s1 = cb;
#pragma unroll
    for (int k = 0; k < 64; k++) {
      float w = cw2[k * 32 + dd0];
      s0 = fmaf(hS[j0][k], w, s0);
      s1 = fmaf(hS[j1][k], w, s1);
    }
    zS[j0][dd0] += s0;
    zS[j1][dd0] += s1;
    if (tid < 32) {
      float s2 = cb;
#pragma unroll
      for (int k = 0; k < 64; k++) s2 = fmaf(hS[j2][k], cw2[k * 32 + dd0], s2);
      zS[j2][dd0] += s2;
    }
  }
  __syncthreads();
  // final LN
  if (tid < 17) {
    float m = 0.0f;
#pragma unroll
    for (int d = 0; d < 32; d++) m += zS[tid][d];
    m *= (1.0f / 32.0f);
    float v = 0.0f;
#pragma unroll
    for (int d = 0; d < 32; d++) { float t = zS[tid][d] - m; v += t * t; }
    float rs = 1.0f / sqrtf(v * (1.0f / 32.0f) + 1e-5f);
#pragma unroll
    for (int d = 0; d < 32; d++)
      t2S[tid][d] = (zS[tid][d] - m) * rs * lng[d] + lnb[d];
  }
  __syncthreads();
  // rec: 34 outputs
  if (tid < 34) {
    int j = tid >> 1, c = tid & 1;
    float s = recb[c];
#pragma unroll
    for (int d = 0; d < 32; d++) s = fmaf(t2S[j][d], recw[d * 2 + c], s);
    o_rec[((size_t)b * 17 + j) * 2 + c] = s;
  }
}

// ================================================================
extern "C" void kernel_launch(void* const* d_in, const int* in_sizes, int n_in,
                              void* d_out, int out_size, void* d_ws, size_t ws_size,
                              hipStream_t stream) {
  const float* joints   = (const float*)d_in[0];
  const float* inv_tok  = (const float*)d_in[3];
  const float* start_w  = (const float*)d_in[4];
  const float* start_b  = (const float*)d_in[5];
  const float* e_ln1g = (const float*)d_in[6];
  const float* e_ln1b = (const float*)d_in[7];
  const float* e_tw1  = (const float*)d_in[8];
  const float* e_tb1  = (const float*)d_in[9];
  const float* e_tw2  = (const float*)d_in[10];
  const float* e_tb2  = (const float*)d_in[11];
  const float* e_ln2g = (const float*)d_in[12];
  const float* e_ln2b = (const float*)d_in[13];
  const float* e_cw1  = (const float*)d_in[14];
  const float* e_cb1  = (const float*)d_in[15];
  const float* e_cw2  = (const float*)d_in[16];
  const float* e_cb2  = (const float*)d_in[17];
  const float* d_ln1g = (const float*)d_in[18];
  const float* d_ln1b = (const float*)d_in[19];
  const float* d_tw1  = (const float*)d_in[20];
  const float* d_tb1  = (const float*)d_in[21];
  const float* d_tw2  = (const float*)d_in[22];
  const float* d_tb2  = (const float*)d_in[23];
  const float* d_ln2g = (const float*)d_in[24];
  const float* d_ln2b = (const float*)d_in[25];
  const float* d_cw1  = (const float*)d_in[26];
  const float* d_cb1  = (const float*)d_in[27];
  const float* d_cw2  = (const float*)d_in[28];
  const float* d_cb2  = (const float*)d_in[29];
  const float* enc_lng = (const float*)d_in[30];
  const float* enc_lnb = (const float*)d_in[31];
  const float* tok_w   = (const float*)d_in[32];
  const float* tok_b   = (const float*)d_in[33];
  const float* feat_w  = (const float*)d_in[34];
  const float* feat_b  = (const float*)d_in[35];
  const float* codebook = (const float*)d_in[36];
  const float* ema_cs   = (const float*)d_in[37];
  const float* ema_w    = (const float*)d_in[38];
  const float* dtok_w   = (const float*)d_in[39];
  const float* dtok_b   = (const float*)d_in[40];
  const float* dstart_w = (const float*)d_in[41];
  const float* dstart_b = (const float*)d_in[42];
  const float* dec_lng  = (const float*)d_in[43];
  const float* dec_lnb  = (const float*)d_in[44];
  const float* rec_w    = (const float*)d_in[45];
  const float* rec_b    = (const float*)d_in[46];

  // -------- workspace layout (same proven footprint) --------
  float* ws = (float*)d_ws;
  float* Ab  = ws;                  // [RJ,512] fp32 residual
  float* Bb  = ws + SZX;            // [RJ,512] fp32 (x+y residual)
  float* Cc  = ws + 2 * SZX;        // scratch
  float* P1e = ws + 3 * SZX;        // RJ bf16 hi+lo (ln2 out)
  float* P2e = ws + 4 * SZX;        // RJ bf16 hi+lo (mgemm1 out)
  float* cbs = ws + 5 * SZX;        // codebook split hi+lo
  float* cnorm = cbs + 1048576;                      // 2048
  u64*  packed = (u64*)(cnorm + 2048);               // RM u64
  int*  cnt    = (int*)(cnorm + 2048 + 69632);       // 2048
  int*  basebuf = cnt + 2048;
  int*  cursor  = basebuf + 2048;
  u32*  bucket  = (u32*)(cursor + 2048);             // RM
  float* lpart  = (float*)(bucket + RM);             // RM/2
  float* nbuf   = lpart + RM / 2;                    // 1 (padded)
  float* dw     = nbuf + 2048;                       // 2048*512
  u16* WTh1 = (u16*)dw;
  u16* WTl1 = (u16*)(dw + 131072);
  u16* WTh2 = (u16*)(dw + 262144);
  u16* WTl2 = (u16*)(dw + 393216);
  u16* P1eh = (u16*)P1e;  u16* P1el = (u16*)(P1e + SZX / 2);
  u16* P2eh = (u16*)P2e;  u16* P2el = (u16*)(P2e + SZX / 2);
  u16* P1mh = (u16*)Ab;   u16* P1ml = (u16*)Bb;
  u16* P2mh = (u16*)Cc;   u16* P2ml = (u16*)P1e;
  u16* chh = (u16*)cbs;   u16* cll = (u16*)(cbs + 524288);

  // -------- outputs --------
  float* outp = (float*)d_out;
  float* o_rec = outp;
  float* o_idx = outp + (size_t)RJ * 2;
  float* o_loss = o_idx + RM;
  float* o_ptf = o_loss + 1;
  float* o_cb = o_ptf + SZM;

  // -------- encoder --------
  embed_kernel<<<(RJ * 512) / 256, 256, 0, stream>>>(joints, inv_tok, start_w, start_b, Ab);
  for (int i = 0; i < 4; i++) {
    mixer_fused<<<Bn, 256, 0, stream>>>(
        Ab, Bb, P1eh, P1el,
        e_ln1g + i * 512, e_ln1b + i * 512,
        e_tw1 + i * 17 * 64, e_tb1 + i * 64, e_tw2 + i * 64 * 17, e_tb2 + i * 17,
        e_ln2g + i * 512, e_ln2b + i * 512,
        e_cw1 + (size_t)i * 512 * 512, e_cw2 + (size_t)i * 512 * 512,
        WTh1, WTl1, WTh2, WTl2);
    mgemm64<1, 0, 1><<<dim3(RJ / 64, 4), 256, 0, stream>>>(
        P1eh, P1el, WTh1, WTl1, e_cb1 + i * 512, nullptr, nullptr, P2eh, P2el, 512);
    mgemm64<0, 1, 0><<<dim3(RJ / 64, 4), 256, 0, stream>>>(
        P2eh, P2el, WTh2, WTl2, e_cb2 + i * 512, Bb, Ab, nullptr, nullptr, 512);
  }
  lnmix_fused<<<Bn, 256, 0, stream>>>(Ab, P1mh, P1ml, enc_lng, enc_lnb, tok_w, tok_b,
                                      feat_w, WTh1, WTl1);
  mgemm64<0, 0, 1><<<dim3(RM / 64, 4), 256, 0, stream>>>(
      P1mh, P1ml, WTh1, WTl1, feat_b, nullptr, nullptr, P2mh, P2ml, 512);

  // -------- VQ: distances + argmin --------
  splitnorm_kernel<<<2048 / 4, 256, 0, stream>>>(codebook, chh, cll, cnorm, packed, cnt);
  dist_mfma<<<dim3(RM / 128, 2048 / 128), 256, 0, stream>>>(P2mh, P2ml, chh, cll, cnorm, packed);

  // -------- skew-oblivious bucketed EMA update --------
  idxcount_kernel<<<RM / 256, 256, 0, stream>>>(packed, o_idx, cnt);
  scan_kernel<<<1, 256, 0, stream>>>(cnt, basebuf, cursor, ema_cs, nbuf);
  scatter_kernel<<<RM / 256, 256, 0, stream>>>(packed, cursor, bucket, dw);
  quant_out_kernel<<<RM / 2, 256, 0, stream>>>(P2mh, P2ml, codebook, packed, o_ptf, lpart);
  dwsum_chunk_kernel<<<RM / 64, 256, 0, stream>>>(P2mh, P2ml, bucket, dw);
  cbnew_kernel<<<(2048 * 512) / 256, 256, 0, stream>>>(
      ema_w, dw, ema_cs, cnt, nbuf, o_cb, lpart, o_loss);

  // -------- decoder (single fused kernel) --------
  decoder_fused<<<Bn, 256, 0, stream>>>(
      o_ptf, dtok_w, dtok_b, dstart_w, dstart_b,
      d_ln1g, d_ln1b, d_tw1, d_tb1, d_tw2, d_tb2, d_ln2g, d_ln2b,
      d_cw1, d_cb1, d_cw2, d_cb2, dec_lng, dec_lnb, rec_w, rec_b, o_rec);
}